// Round 7
// baseline (3494.918 us; speedup 1.0000x reference)
//
#include <hip/hip_runtime.h>
#include <hip/hip_bf16.h>

typedef __hip_bfloat16 bf16;

constexpr int B  = 64, T = 120, N = 24, M = 3, D = 32;
constexpr int NH = 2, FD = 16, FF = 64, L = 3;
constexpr float SCALE = 0.25f;   // 1/sqrt(FD)
constexpr int ST   = 33;         // padded LDS stride (spatial kernel, f32)
constexpr int STE  = 34;         // Es/Os bf16 row stride (68 B)
constexpr int STK2 = 40;         // Ks/Vs bf16 row stride (80 B, 16B-aligned)

__device__ __forceinline__ float b2f(bf16 x) { return __bfloat162float(x); }
__device__ __forceinline__ float blo(unsigned u) { return __uint_as_float(u << 16); }
__device__ __forceinline__ float bhi(unsigned u) { return __uint_as_float(u & 0xffff0000u); }

// ---------------------------------------------------------------------------
// Compose q/k/v chained linears in one launch: grid = 3*U blocks.
// ---------------------------------------------------------------------------
__global__ __launch_bounds__(256) void compose3_kernel(
    const float* __restrict__ W1q, const float* __restrict__ b1q,
    const float* __restrict__ W2q, const float* __restrict__ b2q,
    const float* __restrict__ W1k, const float* __restrict__ b1k,
    const float* __restrict__ W2k, const float* __restrict__ b2k,
    const float* __restrict__ W1v, const float* __restrict__ b1v,
    const float* __restrict__ W2v, const float* __restrict__ b2v,
    float* __restrict__ Wc, float* __restrict__ bc, int U) {
  int fam = blockIdx.x / U;
  int n   = blockIdx.x % U;
  const float* W1 = (fam == 0) ? W1q : (fam == 1) ? W1k : W1v;
  const float* b1 = (fam == 0) ? b1q : (fam == 1) ? b1k : b1v;
  const float* W2 = (fam == 0) ? W2q : (fam == 1) ? W2k : W2v;
  const float* b2 = (fam == 0) ? b2q : (fam == 1) ? b2k : b2v;
  const float* w1 = W1 + n * D * D;
  const float* w2 = W2 + n * D * D;
  float* wc = Wc + (size_t)(fam * U + n) * D * D;
  float* bcp = bc + (fam * U + n) * D;
  __shared__ float s1[D * D], s2[D * D];
  for (int i = threadIdx.x; i < D * D; i += 256) {
    s1[i] = w1[i];
    s2[i] = w2[i];
  }
  __syncthreads();
  for (int i = threadIdx.x; i < D * D; i += 256) {
    int d = i >> 5, f = i & 31;
    float acc = 0.f;
#pragma unroll
    for (int e = 0; e < D; ++e) acc += s1[d * D + e] * s2[e * D + f];
    wc[i] = acc;
  }
  if (threadIdx.x < D) {
    int f = threadIdx.x;
    float acc = b2[n * D + f];
#pragma unroll
    for (int e = 0; e < D; ++e) acc += b1[n * D + e] * s2[e * D + f];
    bcp[f] = acc;
  }
}

// ---------------------------------------------------------------------------
// E[b,t,n,d] = sum_m X[b,t,n*M+m]*E_W[n,m,d] + E_b[n,d] + pe[t,d]   (bf16 out)
// ---------------------------------------------------------------------------
__global__ __launch_bounds__(256) void embed_kernel(
    const float* __restrict__ X, const float* __restrict__ pe,
    const float* __restrict__ E_W, const float* __restrict__ E_b,
    bf16* __restrict__ E) {
  int idx = blockIdx.x * 256 + threadIdx.x;
  if (idx >= B * T * N * D) return;
  int d = idx & 31;
  int n = (idx >> 5) % N;
  int bt = idx / (D * N);
  int t = bt % T;
  const float* x = X + bt * (N * M) + n * M;
  float acc = E_b[n * D + d] + pe[t * D + d];
#pragma unroll
  for (int m = 0; m < M; ++m) acc += x[m] * E_W[(n * M + m) * D + d];
  E[idx] = __float2bfloat16(acc);
}

// ---------------------------------------------------------------------------
// Temporal attention v4, fused per (b, n).  Occupancy push:
//  - launch_bounds(256,4) + phase-split Q/K/V weight loads -> VGPR <= 128
//    (was 172 -> only 2 waves/SIMD; m69 cliff at 128)
//  - K/V stored bf16 stride 40 (16B-aligned rows) -> LDS 34.7 KB -> 4 blk/CU
//  => 16 waves/CU (was 8) to hide the softmax dependent chain.
// ---------------------------------------------------------------------------
__global__ __launch_bounds__(256, 4) void temporal_kernel(
    const bf16* __restrict__ E, const float* __restrict__ WtC,
    const float* __restrict__ btC, const float* __restrict__ tm_Wo,
    const float* __restrict__ tm_bo, const float* __restrict__ ln_g,
    const float* __restrict__ ln_b, bf16* __restrict__ Tn) {
  int b = blockIdx.x / N;
  int n = blockIdx.x % N;
  __shared__ __align__(16) bf16 Es[T * STE];    // staged E
  __shared__ __align__(16) bf16 Os[T * STE];    // Q, then O
  __shared__ __align__(16) bf16 Ks[T * STK2];   // K, later pre-LN rows
  __shared__ __align__(16) bf16 Vs[T * STK2];
  int tid = threadIdx.x;
  int e = tid & 31;
  const bf16* Eg = E + ((size_t)b * T * N + n) * D;

  // --- stage Es ---
  for (int i = tid; i < T * D; i += 256) {
    int t = i >> 5, d = i & 31;
    Es[t * STE + d] = Eg[(size_t)t * N * D + d];
  }
  __syncthreads();

  // --- Q projection (one weight-column array live at a time) ---
  {
    const float* wg = WtC + (0 * N + n) * D * D;
    float w[D];
#pragma unroll
    for (int d = 0; d < D; ++d) w[d] = wg[d * D + e];
    float bb = btC[(0 * N + n) * D + e];
#pragma unroll
    for (int k = 0; k < T * D / 256; ++k) {
      int t = (tid + k * 256) >> 5;
      float a = bb;
#pragma unroll
      for (int d = 0; d < D; ++d) a += b2f(Es[t * STE + d]) * w[d];
      Os[t * STE + e] = __float2bfloat16(a);
    }
  }
  // --- K projection ---
  {
    const float* wg = WtC + (1 * N + n) * D * D;
    float w[D];
#pragma unroll
    for (int d = 0; d < D; ++d) w[d] = wg[d * D + e];
    float bb = btC[(1 * N + n) * D + e];
#pragma unroll
    for (int k = 0; k < T * D / 256; ++k) {
      int t = (tid + k * 256) >> 5;
      float a = bb;
#pragma unroll
      for (int d = 0; d < D; ++d) a += b2f(Es[t * STE + d]) * w[d];
      Ks[t * STK2 + e] = __float2bfloat16(a);
    }
  }
  // --- V projection ---
  {
    const float* wg = WtC + (2 * N + n) * D * D;
    float w[D];
#pragma unroll
    for (int d = 0; d < D; ++d) w[d] = wg[d * D + e];
    float bb = btC[(2 * N + n) * D + e];
#pragma unroll
    for (int k = 0; k < T * D / 256; ++k) {
      int t = (tid + k * 256) >> 5;
      float a = bb;
#pragma unroll
      for (int d = 0; d < D; ++d) a += b2f(Es[t * STE + d]) * w[d];
      Vs[t * STK2 + e] = __float2bfloat16(a);
    }
  }
  __syncthreads();

  // --- balanced split online softmax (rows tq and 119-tq, key parity) ---
  if (tid < 240) {
    int par = tid & 1;
    int h   = (tid >> 1) & 1;
    int tq  = tid >> 2;
    int ho  = h * FD;
#pragma unroll 1
    for (int half = 0; half < 2; ++half) {
      int r = half ? (T - 1 - tq) : tq;
      float q[FD];
#pragma unroll
      for (int f = 0; f < FD; ++f) q[f] = b2f(Os[r * STE + ho + f]);
      float m = -3e38f, l = 0.f;
      float acc[FD];
#pragma unroll
      for (int f = 0; f < FD; ++f) acc[f] = 0.f;
#pragma unroll 1
      for (int k = par; k <= r; k += 2) {
        const uint4* kp = (const uint4*)&Ks[k * STK2 + ho];
        uint4 ka = kp[0], kb = kp[1];
        float s = q[0]*blo(ka.x) + q[1]*bhi(ka.x) + q[2]*blo(ka.y) + q[3]*bhi(ka.y)
                + q[4]*blo(ka.z) + q[5]*bhi(ka.z) + q[6]*blo(ka.w) + q[7]*bhi(ka.w)
                + q[8]*blo(kb.x) + q[9]*bhi(kb.x) + q[10]*blo(kb.y) + q[11]*bhi(kb.y)
                + q[12]*blo(kb.z) + q[13]*bhi(kb.z) + q[14]*blo(kb.w) + q[15]*bhi(kb.w);
        s *= SCALE;
        float nm = fmaxf(m, s);
        float cf = __expf(m - nm);
        float p  = __expf(s - nm);
        l = l * cf + p;
        const uint4* vp = (const uint4*)&Vs[k * STK2 + ho];
        uint4 va = vp[0], vb = vp[1];
        acc[0]  = acc[0]*cf  + p*blo(va.x); acc[1]  = acc[1]*cf  + p*bhi(va.x);
        acc[2]  = acc[2]*cf  + p*blo(va.y); acc[3]  = acc[3]*cf  + p*bhi(va.y);
        acc[4]  = acc[4]*cf  + p*blo(va.z); acc[5]  = acc[5]*cf  + p*bhi(va.z);
        acc[6]  = acc[6]*cf  + p*blo(va.w); acc[7]  = acc[7]*cf  + p*bhi(va.w);
        acc[8]  = acc[8]*cf  + p*blo(vb.x); acc[9]  = acc[9]*cf  + p*bhi(vb.x);
        acc[10] = acc[10]*cf + p*blo(vb.y); acc[11] = acc[11]*cf + p*bhi(vb.y);
        acc[12] = acc[12]*cf + p*blo(vb.z); acc[13] = acc[13]*cf + p*bhi(vb.z);
        acc[14] = acc[14]*cf + p*blo(vb.w); acc[15] = acc[15]*cf + p*bhi(vb.w);
        m = nm;
      }
      // merge parity-partial states (lanes tid, tid^1)
      float m2 = __shfl_xor(m, 1, 64);
      float mm = fmaxf(m, m2);
      float cs = __expf(m - mm);
      float l2 = __shfl_xor(l, 1, 64);
      float c2 = __expf(m2 - mm);
      float rl = 1.f / (l * cs + l2 * c2);
#pragma unroll
      for (int f = 0; f < FD; ++f) {
        float a = acc[f] * cs;
        a += __shfl_xor(a, 1, 64);
        if ((f >> 3) == par)   // par0 writes f0..7, par1 writes f8..15
          Os[r * STE + ho + f] = __float2bfloat16(a * rl);
      }
    }
  }
  __syncthreads();

  // --- output projection + residual into Ks (bf16 pre-LN rows) ---
  {
    const float* wg = tm_Wo + n * D * D;
    float w[D];
#pragma unroll
    for (int d = 0; d < D; ++d) w[d] = wg[d * D + e];
    float bb = tm_bo[n * D + e];
#pragma unroll
    for (int k = 0; k < T * D / 256; ++k) {
      int t = (tid + k * 256) >> 5;
      float a = bb;
#pragma unroll
      for (int d = 0; d < D; ++d) a += b2f(Os[t * STE + d]) * w[d];
      Ks[t * STK2 + e] = __float2bfloat16(a + b2f(Es[t * STE + e]));
    }
  }
  __syncthreads();

  // --- LayerNorm, one thread per row ---
  if (tid < T) {
    int t = tid;
    float x[D];
    float mu = 0.f;
#pragma unroll
    for (int d = 0; d < D; ++d) { x[d] = b2f(Ks[t * STK2 + d]); mu += x[d]; }
    mu *= (1.f / D);
    float var = 0.f;
#pragma unroll
    for (int d = 0; d < D; ++d) { float c = x[d] - mu; var += c * c; }
    var *= (1.f / D);
    float r = rsqrtf(var + 1e-5f);
#pragma unroll
    for (int d = 0; d < D; ++d)
      Tn[((size_t)(b * T + t) * N + n) * D + d] =
          __float2bfloat16((x[d] - mu) * r * ln_g[d] + ln_b[d]);
  }
}

// ---------------------------------------------------------------------------
// Spatial attention, fused per (b, t).  Phase-split weight loads + lb(64,4)
// for VGPR <= 128 -> 16 waves/CU.
// ---------------------------------------------------------------------------
__global__ __launch_bounds__(64, 4) void spatial_kernel(
    const bf16* __restrict__ E, const float* __restrict__ WsC,
    const float* __restrict__ bsC, const float* __restrict__ sm_Wo,
    const float* __restrict__ sm_bo, const float* __restrict__ ln_g,
    const float* __restrict__ ln_b, bf16* __restrict__ Sn) {
  int b = blockIdx.x / T;
  int t = blockIdx.x % T;
  __shared__ float Es[N * ST], Ks[N * ST], Vs[N * ST], Os[N * ST];
  int tid = threadIdx.x;
  int e = tid & 31;

  for (int i = tid; i < N * D; i += 64) {
    int nn = i >> 5, d = i & 31;
    Es[nn * ST + d] = b2f(E[((size_t)(b * T + t) * N + nn) * D + d]);
  }
  __syncthreads();

  {
    const float* wg = WsC + (0 * T + t) * D * D;
    float w[D];
#pragma unroll
    for (int d = 0; d < D; ++d) w[d] = wg[d * D + e];
    float bb = bsC[(0 * T + t) * D + e];
#pragma unroll
    for (int k = 0; k < N * D / 64; ++k) {
      int nn = (tid + k * 64) >> 5;
      float a = bb;
#pragma unroll
      for (int d = 0; d < D; ++d) a += Es[nn * ST + d] * w[d];
      Os[nn * ST + e] = a;
    }
  }
  {
    const float* wg = WsC + (1 * T + t) * D * D;
    float w[D];
#pragma unroll
    for (int d = 0; d < D; ++d) w[d] = wg[d * D + e];
    float bb = bsC[(1 * T + t) * D + e];
#pragma unroll
    for (int k = 0; k < N * D / 64; ++k) {
      int nn = (tid + k * 64) >> 5;
      float a = bb;
#pragma unroll
      for (int d = 0; d < D; ++d) a += Es[nn * ST + d] * w[d];
      Ks[nn * ST + e] = a;
    }
  }
  {
    const float* wg = WsC + (2 * T + t) * D * D;
    float w[D];
#pragma unroll
    for (int d = 0; d < D; ++d) w[d] = wg[d * D + e];
    float bb = bsC[(2 * T + t) * D + e];
#pragma unroll
    for (int k = 0; k < N * D / 64; ++k) {
      int nn = (tid + k * 64) >> 5;
      float a = bb;
#pragma unroll
      for (int d = 0; d < D; ++d) a += Es[nn * ST + d] * w[d];
      Vs[nn * ST + e] = a;
    }
  }
  __syncthreads();

  if (tid < N * NH) {
    int nn = tid >> 1, h = tid & 1;
    int ho = h * FD;
    float q[FD];
#pragma unroll
    for (int f = 0; f < FD; ++f) q[f] = Os[nn * ST + ho + f];
    float sc[N];
    float m = -1e30f;
#pragma unroll
    for (int k = 0; k < N; ++k) {
      float s = 0.f;
#pragma unroll
      for (int f = 0; f < FD; ++f) s += q[f] * Ks[k * ST + ho + f];
      s *= SCALE;
      sc[k] = s;
      m = fmaxf(m, s);
    }
    float l = 0.f;
#pragma unroll
    for (int k = 0; k < N; ++k) { sc[k] = __expf(sc[k] - m); l += sc[k]; }
    float rl = 1.f / l;
#pragma unroll
    for (int f = 0; f < FD; ++f) {
      float a = 0.f;
#pragma unroll
      for (int k = 0; k < N; ++k) a += sc[k] * Vs[k * ST + ho + f];
      Os[nn * ST + ho + f] = a * rl;
    }
  }
  __syncthreads();

  {
    const float* wg = sm_Wo + t * D * D;
    float w[D];
#pragma unroll
    for (int d = 0; d < D; ++d) w[d] = wg[d * D + e];
    float bb = sm_bo[t * D + e];
#pragma unroll
    for (int k = 0; k < N * D / 64; ++k) {
      int nn = (tid + k * 64) >> 5;
      float a = bb;
#pragma unroll
      for (int d = 0; d < D; ++d) a += Os[nn * ST + d] * w[d];
      Ks[nn * ST + e] = a + Es[nn * ST + e];
    }
  }
  __syncthreads();

  if (tid < N) {
    int nn = tid;
    float mu = 0.f;
#pragma unroll
    for (int d = 0; d < D; ++d) mu += Ks[nn * ST + d];
    mu *= (1.f / D);
    float var = 0.f;
#pragma unroll
    for (int d = 0; d < D; ++d) { float c = Ks[nn * ST + d] - mu; var += c * c; }
    var *= (1.f / D);
    float r = rsqrtf(var + 1e-5f);
#pragma unroll
    for (int d = 0; d < D; ++d)
      Sn[((size_t)(b * T + t) * N + nn) * D + d] =
          __float2bfloat16((Ks[nn * ST + d] - mu) * r * ln_g[d] + ln_b[d]);
  }
}

// ---------------------------------------------------------------------------
// ts = Tn + Sn; ff = relu(ts@W1+b1)@W2+b2; E = LN(ff + ts).  Row per thread,
// hidden layer processed in 2 chunks of 32 so live set fits 128 VGPR.
// ---------------------------------------------------------------------------
__global__ __launch_bounds__(256, 4) void ff_kernel(
    const bf16* __restrict__ Tn, const bf16* __restrict__ Sn,
    const float* __restrict__ W1, const float* __restrict__ b1,
    const float* __restrict__ W2, const float* __restrict__ b2,
    const float* __restrict__ ln_g, const float* __restrict__ ln_b,
    bf16* __restrict__ E) {
  __shared__ float w1[D * FF], w2[FF * D], bb1[FF], bb2[D], g[D], bbn[D];
  int tid = threadIdx.x;
  for (int i = tid; i < D * FF; i += 256) {
    w1[i] = W1[i];
    w2[i] = W2[i];
  }
  if (tid < FF) bb1[tid] = b1[tid];
  if (tid < D) {
    bb2[tid] = b2[tid];
    g[tid]   = ln_g[tid];
    bbn[tid] = ln_b[tid];
  }
  __syncthreads();
  int row = blockIdx.x * 256 + tid;
  if (row >= B * T * N) return;
  float ts[D];
#pragma unroll
  for (int d = 0; d < D; ++d)
    ts[d] = b2f(Tn[(size_t)row * D + d]) + b2f(Sn[(size_t)row * D + d]);
  float x[D];
#pragma unroll
  for (int d = 0; d < D; ++d) x[d] = bb2[d] + ts[d];
#pragma unroll 1
  for (int c = 0; c < 2; ++c) {
    float hh[32];
#pragma unroll
    for (int j = 0; j < 32; ++j) {
      int jj = c * 32 + j;
      float a = bb1[jj];
#pragma unroll
      for (int d = 0; d < D; ++d) a += ts[d] * w1[d * FF + jj];
      hh[j] = fmaxf(a, 0.f);
    }
#pragma unroll
    for (int e2 = 0; e2 < D; ++e2) {
      float a = 0.f;
#pragma unroll
      for (int j = 0; j < 32; ++j) a += hh[j] * w2[(c * 32 + j) * D + e2];
      x[e2] += a;
    }
  }
  float mu = 0.f;
#pragma unroll
  for (int e2 = 0; e2 < D; ++e2) mu += x[e2];
  mu *= (1.f / D);
  float var = 0.f;
#pragma unroll
  for (int e2 = 0; e2 < D; ++e2) { float c = x[e2] - mu; var += c * c; }
  var *= (1.f / D);
  float r = rsqrtf(var + 1e-5f);
#pragma unroll
  for (int e2 = 0; e2 < D; ++e2)
    E[(size_t)row * D + e2] = __float2bfloat16((x[e2] - mu) * r * g[e2] + bbn[e2]);
}

// ---------------------------------------------------------------------------
// out[b,t,n,m] = E[b,t,n,:]@op_W[n,:,m] + op_b[n,m] + X[b,t,n*M+m]  (f32 out)
// ---------------------------------------------------------------------------
__global__ __launch_bounds__(256) void out_kernel(
    const bf16* __restrict__ E, const float* __restrict__ op_W,
    const float* __restrict__ op_b, const float* __restrict__ X,
    float* __restrict__ out) {
  int idx = blockIdx.x * 256 + threadIdx.x;
  if (idx >= B * T * N * M) return;
  int m  = idx % M;
  int n  = (idx / M) % N;
  int bt = idx / (M * N);
  float acc = op_b[n * M + m];
  const bf16* e = E + ((size_t)bt * N + n) * D;
#pragma unroll
  for (int d = 0; d < D; ++d) acc += b2f(e[d]) * op_W[(n * D + d) * M + m];
  acc += X[idx];
  out[idx] = acc;
}

// ---------------------------------------------------------------------------
extern "C" void kernel_launch(void* const* d_in, const int* in_sizes, int n_in,
                              void* d_out, int out_size, void* d_ws, size_t ws_size,
                              hipStream_t stream) {
  const float* X     = (const float*)d_in[0];
  const float* pe    = (const float*)d_in[1];
  const float* E_W   = (const float*)d_in[2];
  const float* E_b   = (const float*)d_in[3];
  const float* tq_W  = (const float*)d_in[4];
  const float* tq_b  = (const float*)d_in[5];
  const float* tk_W  = (const float*)d_in[6];
  const float* tk_b  = (const float*)d_in[7];
  const float* tv_W  = (const float*)d_in[8];
  const float* tv_b  = (const float*)d_in[9];
  const float* tm_Wq = (const float*)d_in[10];
  const float* tm_bq = (const float*)d_in[11];
  const float* tm_Wk = (const float*)d_in[12];
  const float* tm_bk = (const float*)d_in[13];
  const float* tm_Wv = (const float*)d_in[14];
  const float* tm_bv = (const float*)d_in[15];
  const float* tm_Wo = (const float*)d_in[16];
  const float* tm_bo = (const float*)d_in[17];
  const float* sq_W  = (const float*)d_in[18];
  const float* sq_b  = (const float*)d_in[19];
  const float* sk_W  = (const float*)d_in[20];
  const float* sk_b  = (const float*)d_in[21];
  const float* sv_W  = (const float*)d_in[22];
  const float* sv_b  = (const float*)d_in[23];
  const float* sm_Wq = (const float*)d_in[24];
  const float* sm_bq = (const float*)d_in[25];
  const float* sm_Wk = (const float*)d_in[26];
  const float* sm_bk = (const float*)d_in[27];
  const float* sm_Wv = (const float*)d_in[28];
  const float* sm_bv = (const float*)d_in[29];
  const float* sm_Wo = (const float*)d_in[30];
  const float* sm_bo = (const float*)d_in[31];
  const float* ff1_W = (const float*)d_in[32];
  const float* ff1_b = (const float*)d_in[33];
  const float* ff2_W = (const float*)d_in[34];
  const float* ff2_b = (const float*)d_in[35];
  const float* ln_g  = (const float*)d_in[36];
  const float* ln_b  = (const float*)d_in[37];
  const float* op_W  = (const float*)d_in[38];
  const float* op_b  = (const float*)d_in[39];
  float* out = (float*)d_out;

  // workspace: f32 composed weights first, then bf16 activations (~37.2 MB)
  float* WtC = (float*)d_ws;                         // 3*N*D*D
  float* btC = WtC + 3 * N * D * D;                  // 3*N*D
  float* WsC = btC + 3 * N * D;                      // 3*T*D*D
  float* bsC = WsC + 3 * T * D * D;                  // 3*T*D
  size_t act = (size_t)B * T * N * D;
  bf16* Ebuf = (bf16*)(bsC + 3 * T * D);
  bf16* Tn   = Ebuf + act;
  bf16* Sn   = Tn + act;

  compose3_kernel<<<3 * N, 256, 0, stream>>>(
      tq_W, tq_b, tm_Wq, tm_bq, tk_W, tk_b, tm_Wk, tm_bk,
      tv_W, tv_b, tm_Wv, tm_bv, WtC, btC, N);
  compose3_kernel<<<3 * T, 256, 0, stream>>>(
      sq_W, sq_b, sm_Wq, sm_bq, sk_W, sk_b, sm_Wk, sm_bk,
      sv_W, sv_b, sm_Wv, sm_bv, WsC, bsC, T);

  embed_kernel<<<(B * T * N * D) / 256, 256, 0, stream>>>(X, pe, E_W, E_b, Ebuf);

  for (int l = 0; l < L; ++l) {
    temporal_kernel<<<B * N, 256, 0, stream>>>(Ebuf, WtC, btC, tm_Wo, tm_bo, ln_g, ln_b, Tn);
    spatial_kernel<<<B * T, 64, 0, stream>>>(Ebuf, WsC, bsC, sm_Wo, sm_bo, ln_g, ln_b, Sn);
    ff_kernel<<<(B * T * N + 255) / 256, 256, 0, stream>>>(Tn, Sn, ff1_W, ff1_b, ff2_W, ff2_b, ln_g, ln_b, Ebuf);
  }

  out_kernel<<<(B * T * N * M) / 256, 256, 0, stream>>>(Ebuf, op_W, op_b, X, out);
}

// Round 8
// 2495.969 us; speedup vs baseline: 1.4002x; 1.4002x over previous
//
#include <hip/hip_runtime.h>
#include <hip/hip_bf16.h>

typedef __hip_bfloat16 bf16;

constexpr int B  = 64, T = 120, N = 24, M = 3, D = 32;
constexpr int NH = 2, FD = 16, FF = 64, L = 3;
constexpr float SCALE = 0.25f;   // 1/sqrt(FD)
constexpr int ST  = 33;          // padded LDS stride (spatial kernel, f32)
constexpr int STE = 34;          // Es bf16 row stride (68 B, scalar access only)
constexpr int STO = 40;          // Os/Ks/Vs bf16 row stride (80 B, 16B-aligned)

__device__ __forceinline__ float b2f(bf16 x) { return __bfloat162float(x); }
__device__ __forceinline__ float blo(unsigned u) { return __uint_as_float(u << 16); }
__device__ __forceinline__ float bhi(unsigned u) { return __uint_as_float(u & 0xffff0000u); }

// ---------------------------------------------------------------------------
// Compose q/k/v chained linears in one launch: grid = 3*U blocks.
// ---------------------------------------------------------------------------
__global__ __launch_bounds__(256) void compose3_kernel(
    const float* __restrict__ W1q, const float* __restrict__ b1q,
    const float* __restrict__ W2q, const float* __restrict__ b2q,
    const float* __restrict__ W1k, const float* __restrict__ b1k,
    const float* __restrict__ W2k, const float* __restrict__ b2k,
    const float* __restrict__ W1v, const float* __restrict__ b1v,
    const float* __restrict__ W2v, const float* __restrict__ b2v,
    float* __restrict__ Wc, float* __restrict__ bc, int U) {
  int fam = blockIdx.x / U;
  int n   = blockIdx.x % U;
  const float* W1 = (fam == 0) ? W1q : (fam == 1) ? W1k : W1v;
  const float* b1 = (fam == 0) ? b1q : (fam == 1) ? b1k : b1v;
  const float* W2 = (fam == 0) ? W2q : (fam == 1) ? W2k : W2v;
  const float* b2 = (fam == 0) ? b2q : (fam == 1) ? b2k : b2v;
  const float* w1 = W1 + n * D * D;
  const float* w2 = W2 + n * D * D;
  float* wc = Wc + (size_t)(fam * U + n) * D * D;
  float* bcp = bc + (fam * U + n) * D;
  __shared__ float s1[D * D], s2[D * D];
  for (int i = threadIdx.x; i < D * D; i += 256) {
    s1[i] = w1[i];
    s2[i] = w2[i];
  }
  __syncthreads();
  for (int i = threadIdx.x; i < D * D; i += 256) {
    int d = i >> 5, f = i & 31;
    float acc = 0.f;
#pragma unroll
    for (int e = 0; e < D; ++e) acc += s1[d * D + e] * s2[e * D + f];
    wc[i] = acc;
  }
  if (threadIdx.x < D) {
    int f = threadIdx.x;
    float acc = b2[n * D + f];
#pragma unroll
    for (int e = 0; e < D; ++e) acc += b1[n * D + e] * s2[e * D + f];
    bcp[f] = acc;
  }
}

// ---------------------------------------------------------------------------
// E[b,t,n,d] = sum_m X[b,t,n*M+m]*E_W[n,m,d] + E_b[n,d] + pe[t,d]   (bf16 out)
// ---------------------------------------------------------------------------
__global__ __launch_bounds__(256) void embed_kernel(
    const float* __restrict__ X, const float* __restrict__ pe,
    const float* __restrict__ E_W, const float* __restrict__ E_b,
    bf16* __restrict__ E) {
  int idx = blockIdx.x * 256 + threadIdx.x;
  if (idx >= B * T * N * D) return;
  int d = idx & 31;
  int n = (idx >> 5) % N;
  int bt = idx / (D * N);
  int t = bt % T;
  const float* x = X + bt * (N * M) + n * M;
  float acc = E_b[n * D + d] + pe[t * D + d];
#pragma unroll
  for (int m = 0; m < M; ++m) acc += x[m] * E_W[(n * M + m) * D + d];
  E[idx] = __float2bfloat16(acc);
}

// ---------------------------------------------------------------------------
// Temporal attention v5, fused per (b, n).
// Pressure fix WITHOUT launch_bounds force (R7 lesson: (256,4) -> 64 VGPR ->
// 585 MB scratch spill, 30 ms).  f-split softmax: thread = (row-pair, head,
// f-half); score computed by both fh threads (cheap), acc[8] each (halves the
// dominant register array), no cross-lane merges.  All K/V/O bf16 in LDS at
// stride 40 (16B-aligned) -> LDS ~37 KB -> 4 blocks/CU if VGPR <= 128.
// ---------------------------------------------------------------------------
__global__ __launch_bounds__(256) void temporal_kernel(
    const bf16* __restrict__ E, const float* __restrict__ WtC,
    const float* __restrict__ btC, const float* __restrict__ tm_Wo,
    const float* __restrict__ tm_bo, const float* __restrict__ ln_g,
    const float* __restrict__ ln_b, bf16* __restrict__ Tn) {
  int b = blockIdx.x / N;
  int n = blockIdx.x % N;
  __shared__ __align__(16) bf16 Es[T * STE];   // staged E (scalar access)
  __shared__ __align__(16) bf16 Os[T * STO];   // Q, then O
  __shared__ __align__(16) bf16 Ks[T * STO];   // K, later pre-LN rows
  __shared__ __align__(16) bf16 Vs[T * STO];
  int tid = threadIdx.x;
  int e = tid & 31;
  const bf16* Eg = E + ((size_t)b * T * N + n) * D;

  // --- stage Es ---
  for (int i = tid; i < T * D; i += 256) {
    int t = i >> 5, d = i & 31;
    Es[t * STE + d] = Eg[(size_t)t * N * D + d];
  }
  __syncthreads();

  // --- Q projection (one weight-column array live at a time) ---
  {
    const float* wg = WtC + (0 * N + n) * D * D;
    float w[D];
#pragma unroll
    for (int d = 0; d < D; ++d) w[d] = wg[d * D + e];
    float bb = btC[(0 * N + n) * D + e];
#pragma unroll
    for (int k = 0; k < T * D / 256; ++k) {
      int t = (tid + k * 256) >> 5;
      float a = bb;
#pragma unroll
      for (int d = 0; d < D; ++d) a += b2f(Es[t * STE + d]) * w[d];
      Os[t * STO + e] = __float2bfloat16(a);
    }
  }
  // --- K projection ---
  {
    const float* wg = WtC + (1 * N + n) * D * D;
    float w[D];
#pragma unroll
    for (int d = 0; d < D; ++d) w[d] = wg[d * D + e];
    float bb = btC[(1 * N + n) * D + e];
#pragma unroll
    for (int k = 0; k < T * D / 256; ++k) {
      int t = (tid + k * 256) >> 5;
      float a = bb;
#pragma unroll
      for (int d = 0; d < D; ++d) a += b2f(Es[t * STE + d]) * w[d];
      Ks[t * STO + e] = __float2bfloat16(a);
    }
  }
  // --- V projection ---
  {
    const float* wg = WtC + (2 * N + n) * D * D;
    float w[D];
#pragma unroll
    for (int d = 0; d < D; ++d) w[d] = wg[d * D + e];
    float bb = btC[(2 * N + n) * D + e];
#pragma unroll
    for (int k = 0; k < T * D / 256; ++k) {
      int t = (tid + k * 256) >> 5;
      float a = bb;
#pragma unroll
      for (int d = 0; d < D; ++d) a += b2f(Es[t * STE + d]) * w[d];
      Vs[t * STO + e] = __float2bfloat16(a);
    }
  }
  __syncthreads();

  // --- f-split online softmax: rows tq and 119-tq per thread quad ---
  if (tid < 240) {
    int fh = tid & 1;            // f-half: acc covers [ho+fh*8, ho+fh*8+8)
    int h  = (tid >> 1) & 1;
    int tq = tid >> 2;
    int ho = h * FD;
    int fo = ho + fh * 8;
#pragma unroll 1
    for (int half = 0; half < 2; ++half) {
      int r = half ? (T - 1 - tq) : tq;
      uint4 q0 = *(const uint4*)&Os[r * STO + ho];
      uint4 q1 = *(const uint4*)&Os[r * STO + ho + 8];
      float qf[16];
      qf[0]  = blo(q0.x); qf[1]  = bhi(q0.x); qf[2]  = blo(q0.y); qf[3]  = bhi(q0.y);
      qf[4]  = blo(q0.z); qf[5]  = bhi(q0.z); qf[6]  = blo(q0.w); qf[7]  = bhi(q0.w);
      qf[8]  = blo(q1.x); qf[9]  = bhi(q1.x); qf[10] = blo(q1.y); qf[11] = bhi(q1.y);
      qf[12] = blo(q1.z); qf[13] = bhi(q1.z); qf[14] = blo(q1.w); qf[15] = bhi(q1.w);
      float m = -3e38f, l = 0.f;
      float acc[8];
#pragma unroll
      for (int j = 0; j < 8; ++j) acc[j] = 0.f;
#pragma unroll 1
      for (int k = 0; k <= r; ++k) {
        uint4 ka = *(const uint4*)&Ks[k * STO + ho];
        uint4 kb = *(const uint4*)&Ks[k * STO + ho + 8];
        float s = qf[0]*blo(ka.x)  + qf[1]*bhi(ka.x)  + qf[2]*blo(ka.y)  + qf[3]*bhi(ka.y)
                + qf[4]*blo(ka.z)  + qf[5]*bhi(ka.z)  + qf[6]*blo(ka.w)  + qf[7]*bhi(ka.w)
                + qf[8]*blo(kb.x)  + qf[9]*bhi(kb.x)  + qf[10]*blo(kb.y) + qf[11]*bhi(kb.y)
                + qf[12]*blo(kb.z) + qf[13]*bhi(kb.z) + qf[14]*blo(kb.w) + qf[15]*bhi(kb.w);
        s *= SCALE;
        float nm = fmaxf(m, s);
        float cf = __expf(m - nm);
        float p  = __expf(s - nm);
        l = l * cf + p;
        uint4 va = *(const uint4*)&Vs[k * STO + fo];
        acc[0] = acc[0]*cf + p*blo(va.x); acc[1] = acc[1]*cf + p*bhi(va.x);
        acc[2] = acc[2]*cf + p*blo(va.y); acc[3] = acc[3]*cf + p*bhi(va.y);
        acc[4] = acc[4]*cf + p*blo(va.z); acc[5] = acc[5]*cf + p*bhi(va.z);
        acc[6] = acc[6]*cf + p*blo(va.w); acc[7] = acc[7]*cf + p*bhi(va.w);
        m = nm;
      }
      float rl = 1.f / l;
#pragma unroll
      for (int j = 0; j < 8; ++j)
        Os[r * STO + fo + j] = __float2bfloat16(acc[j] * rl);
    }
  }
  __syncthreads();

  // --- output projection + residual into Ks (bf16 pre-LN rows) ---
  {
    const float* wg = tm_Wo + n * D * D;
    float w[D];
#pragma unroll
    for (int d = 0; d < D; ++d) w[d] = wg[d * D + e];
    float bb = tm_bo[n * D + e];
#pragma unroll
    for (int k = 0; k < T * D / 256; ++k) {
      int t = (tid + k * 256) >> 5;
      float a = bb;
#pragma unroll
      for (int d = 0; d < D; ++d) a += b2f(Os[t * STO + d]) * w[d];
      Ks[t * STO + e] = __float2bfloat16(a + b2f(Es[t * STE + e]));
    }
  }
  __syncthreads();

  // --- LayerNorm, one thread per row ---
  if (tid < T) {
    int t = tid;
    float x[D];
    float mu = 0.f;
#pragma unroll
    for (int d = 0; d < D; ++d) { x[d] = b2f(Ks[t * STO + d]); mu += x[d]; }
    mu *= (1.f / D);
    float var = 0.f;
#pragma unroll
    for (int d = 0; d < D; ++d) { float c = x[d] - mu; var += c * c; }
    var *= (1.f / D);
    float r = rsqrtf(var + 1e-5f);
#pragma unroll
    for (int d = 0; d < D; ++d)
      Tn[((size_t)(b * T + t) * N + n) * D + d] =
          __float2bfloat16((x[d] - mu) * r * ln_g[d] + ln_b[d]);
  }
}

// ---------------------------------------------------------------------------
// Spatial attention, fused per (b, t).  N=24 rows, 12.7 KB LDS.
// Phase-split weight loads (one w[32] live at a time), NO launch-bounds min.
// ---------------------------------------------------------------------------
__global__ __launch_bounds__(64) void spatial_kernel(
    const bf16* __restrict__ E, const float* __restrict__ WsC,
    const float* __restrict__ bsC, const float* __restrict__ sm_Wo,
    const float* __restrict__ sm_bo, const float* __restrict__ ln_g,
    const float* __restrict__ ln_b, bf16* __restrict__ Sn) {
  int b = blockIdx.x / T;
  int t = blockIdx.x % T;
  __shared__ float Es[N * ST], Ks[N * ST], Vs[N * ST], Os[N * ST];
  int tid = threadIdx.x;
  int e = tid & 31;

  for (int i = tid; i < N * D; i += 64) {
    int nn = i >> 5, d = i & 31;
    Es[nn * ST + d] = b2f(E[((size_t)(b * T + t) * N + nn) * D + d]);
  }
  __syncthreads();

  {
    const float* wg = WsC + (0 * T + t) * D * D;
    float w[D];
#pragma unroll
    for (int d = 0; d < D; ++d) w[d] = wg[d * D + e];
    float bb = bsC[(0 * T + t) * D + e];
#pragma unroll
    for (int k = 0; k < N * D / 64; ++k) {
      int nn = (tid + k * 64) >> 5;
      float a = bb;
#pragma unroll
      for (int d = 0; d < D; ++d) a += Es[nn * ST + d] * w[d];
      Os[nn * ST + e] = a;
    }
  }
  {
    const float* wg = WsC + (1 * T + t) * D * D;
    float w[D];
#pragma unroll
    for (int d = 0; d < D; ++d) w[d] = wg[d * D + e];
    float bb = bsC[(1 * T + t) * D + e];
#pragma unroll
    for (int k = 0; k < N * D / 64; ++k) {
      int nn = (tid + k * 64) >> 5;
      float a = bb;
#pragma unroll
      for (int d = 0; d < D; ++d) a += Es[nn * ST + d] * w[d];
      Ks[nn * ST + e] = a;
    }
  }
  {
    const float* wg = WsC + (2 * T + t) * D * D;
    float w[D];
#pragma unroll
    for (int d = 0; d < D; ++d) w[d] = wg[d * D + e];
    float bb = bsC[(2 * T + t) * D + e];
#pragma unroll
    for (int k = 0; k < N * D / 64; ++k) {
      int nn = (tid + k * 64) >> 5;
      float a = bb;
#pragma unroll
      for (int d = 0; d < D; ++d) a += Es[nn * ST + d] * w[d];
      Vs[nn * ST + e] = a;
    }
  }
  __syncthreads();

  if (tid < N * NH) {
    int nn = tid >> 1, h = tid & 1;
    int ho = h * FD;
    float q[FD];
#pragma unroll
    for (int f = 0; f < FD; ++f) q[f] = Os[nn * ST + ho + f];
    float sc[N];
    float m = -1e30f;
#pragma unroll
    for (int k = 0; k < N; ++k) {
      float s = 0.f;
#pragma unroll
      for (int f = 0; f < FD; ++f) s += q[f] * Ks[k * ST + ho + f];
      s *= SCALE;
      sc[k] = s;
      m = fmaxf(m, s);
    }
    float l = 0.f;
#pragma unroll
    for (int k = 0; k < N; ++k) { sc[k] = __expf(sc[k] - m); l += sc[k]; }
    float rl = 1.f / l;
#pragma unroll
    for (int f = 0; f < FD; ++f) {
      float a = 0.f;
#pragma unroll
      for (int k = 0; k < N; ++k) a += sc[k] * Vs[k * ST + ho + f];
      Os[nn * ST + ho + f] = a * rl;
    }
  }
  __syncthreads();

  {
    const float* wg = sm_Wo + t * D * D;
    float w[D];
#pragma unroll
    for (int d = 0; d < D; ++d) w[d] = wg[d * D + e];
    float bb = sm_bo[t * D + e];
#pragma unroll
    for (int k = 0; k < N * D / 64; ++k) {
      int nn = (tid + k * 64) >> 5;
      float a = bb;
#pragma unroll
      for (int d = 0; d < D; ++d) a += Os[nn * ST + d] * w[d];
      Ks[nn * ST + e] = a + Es[nn * ST + e];
    }
  }
  __syncthreads();

  if (tid < N) {
    int nn = tid;
    float mu = 0.f;
#pragma unroll
    for (int d = 0; d < D; ++d) mu += Ks[nn * ST + d];
    mu *= (1.f / D);
    float var = 0.f;
#pragma unroll
    for (int d = 0; d < D; ++d) { float c = Ks[nn * ST + d] - mu; var += c * c; }
    var *= (1.f / D);
    float r = rsqrtf(var + 1e-5f);
#pragma unroll
    for (int d = 0; d < D; ++d)
      Sn[((size_t)(b * T + t) * N + nn) * D + d] =
          __float2bfloat16((Ks[nn * ST + d] - mu) * r * ln_g[d] + ln_b[d]);
  }
}

// ---------------------------------------------------------------------------
// ts = Tn + Sn; ff = relu(ts@W1+b1)@W2+b2; E = LN(ff + ts).  Row per thread,
// hidden processed in 2 chunks of 32 (hh[32] live, not h[64]).  NO lb min.
// ---------------------------------------------------------------------------
__global__ __launch_bounds__(256) void ff_kernel(
    const bf16* __restrict__ Tn, const bf16* __restrict__ Sn,
    const float* __restrict__ W1, const float* __restrict__ b1,
    const float* __restrict__ W2, const float* __restrict__ b2,
    const float* __restrict__ ln_g, const float* __restrict__ ln_b,
    bf16* __restrict__ E) {
  __shared__ float w1[D * FF], w2[FF * D], bb1[FF], bb2[D], g[D], bbn[D];
  int tid = threadIdx.x;
  for (int i = tid; i < D * FF; i += 256) {
    w1[i] = W1[i];
    w2[i] = W2[i];
  }
  if (tid < FF) bb1[tid] = b1[tid];
  if (tid < D) {
    bb2[tid] = b2[tid];
    g[tid]   = ln_g[tid];
    bbn[tid] = ln_b[tid];
  }
  __syncthreads();
  int row = blockIdx.x * 256 + tid;
  if (row >= B * T * N) return;
  float ts[D];
#pragma unroll
  for (int d = 0; d < D; ++d)
    ts[d] = b2f(Tn[(size_t)row * D + d]) + b2f(Sn[(size_t)row * D + d]);
  float x[D];
#pragma unroll
  for (int d = 0; d < D; ++d) x[d] = bb2[d] + ts[d];
#pragma unroll 1
  for (int c = 0; c < 2; ++c) {
    float hh[32];
#pragma unroll
    for (int j = 0; j < 32; ++j) {
      int jj = c * 32 + j;
      float a = bb1[jj];
#pragma unroll
      for (int d = 0; d < D; ++d) a += ts[d] * w1[d * FF + jj];
      hh[j] = fmaxf(a, 0.f);
    }
#pragma unroll
    for (int e2 = 0; e2 < D; ++e2) {
      float a = 0.f;
#pragma unroll
      for (int j = 0; j < 32; ++j) a += hh[j] * w2[(c * 32 + j) * D + e2];
      x[e2] += a;
    }
  }
  float mu = 0.f;
#pragma unroll
  for (int e2 = 0; e2 < D; ++e2) mu += x[e2];
  mu *= (1.f / D);
  float var = 0.f;
#pragma unroll
  for (int e2 = 0; e2 < D; ++e2) { float c = x[e2] - mu; var += c * c; }
  var *= (1.f / D);
  float r = rsqrtf(var + 1e-5f);
#pragma unroll
  for (int e2 = 0; e2 < D; ++e2)
    E[(size_t)row * D + e2] = __float2bfloat16((x[e2] - mu) * r * g[e2] + bbn[e2]);
}

// ---------------------------------------------------------------------------
// out[b,t,n,m] = E[b,t,n,:]@op_W[n,:,m] + op_b[n,m] + X[b,t,n*M+m]  (f32 out)
// ---------------------------------------------------------------------------
__global__ __launch_bounds__(256) void out_kernel(
    const bf16* __restrict__ E, const float* __restrict__ op_W,
    const float* __restrict__ op_b, const float* __restrict__ X,
    float* __restrict__ out) {
  int idx = blockIdx.x * 256 + threadIdx.x;
  if (idx >= B * T * N * M) return;
  int m  = idx % M;
  int n  = (idx / M) % N;
  int bt = idx / (M * N);
  float acc = op_b[n * M + m];
  const bf16* e = E + ((size_t)bt * N + n) * D;
#pragma unroll
  for (int d = 0; d < D; ++d) acc += b2f(e[d]) * op_W[(n * D + d) * M + m];
  acc += X[idx];
  out[idx] = acc;
}

// ---------------------------------------------------------------------------
extern "C" void kernel_launch(void* const* d_in, const int* in_sizes, int n_in,
                              void* d_out, int out_size, void* d_ws, size_t ws_size,
                              hipStream_t stream) {
  const float* X     = (const float*)d_in[0];
  const float* pe    = (const float*)d_in[1];
  const float* E_W   = (const float*)d_in[2];
  const float* E_b   = (const float*)d_in[3];
  const float* tq_W  = (const float*)d_in[4];
  const float* tq_b  = (const float*)d_in[5];
  const float* tk_W  = (const float*)d_in[6];
  const float* tk_b  = (const float*)d_in[7];
  const float* tv_W  = (const float*)d_in[8];
  const float* tv_b  = (const float*)d_in[9];
  const float* tm_Wq = (const float*)d_in[10];
  const float* tm_bq = (const float*)d_in[11];
  const float* tm_Wk = (const float*)d_in[12];
  const float* tm_bk = (const float*)d_in[13];
  const float* tm_Wv = (const float*)d_in[14];
  const float* tm_bv = (const float*)d_in[15];
  const float* tm_Wo = (const float*)d_in[16];
  const float* tm_bo = (const float*)d_in[17];
  const float* sq_W  = (const float*)d_in[18];
  const float* sq_b  = (const float*)d_in[19];
  const float* sk_W  = (const float*)d_in[20];
  const float* sk_b  = (const float*)d_in[21];
  const float* sv_W  = (const float*)d_in[22];
  const float* sv_b  = (const float*)d_in[23];
  const float* sm_Wq = (const float*)d_in[24];
  const float* sm_bq = (const float*)d_in[25];
  const float* sm_Wk = (const float*)d_in[26];
  const float* sm_bk = (const float*)d_in[27];
  const float* sm_Wv = (const float*)d_in[28];
  const float* sm_bv = (const float*)d_in[29];
  const float* sm_Wo = (const float*)d_in[30];
  const float* sm_bo = (const float*)d_in[31];
  const float* ff1_W = (const float*)d_in[32];
  const float* ff1_b = (const float*)d_in[33];
  const float* ff2_W = (const float*)d_in[34];
  const float* ff2_b = (const float*)d_in[35];
  const float* ln_g  = (const float*)d_in[36];
  const float* ln_b  = (const float*)d_in[37];
  const float* op_W  = (const float*)d_in[38];
  const float* op_b  = (const float*)d_in[39];
  float* out = (float*)d_out;

  // workspace: f32 composed weights first, then bf16 activations (~37.2 MB)
  float* WtC = (float*)d_ws;                         // 3*N*D*D
  float* btC = WtC + 3 * N * D * D;                  // 3*N*D
  float* WsC = btC + 3 * N * D;                      // 3*T*D*D
  float* bsC = WsC + 3 * T * D * D;                  // 3*T*D
  size_t act = (size_t)B * T * N * D;
  bf16* Ebuf = (bf16*)(bsC + 3 * T * D);
  bf16* Tn   = Ebuf + act;
  bf16* Sn   = Tn + act;

  compose3_kernel<<<3 * N, 256, 0, stream>>>(
      tq_W, tq_b, tm_Wq, tm_bq, tk_W, tk_b, tm_Wk, tm_bk,
      tv_W, tv_b, tm_Wv, tm_bv, WtC, btC, N);
  compose3_kernel<<<3 * T, 256, 0, stream>>>(
      sq_W, sq_b, sm_Wq, sm_bq, sk_W, sk_b, sm_Wk, sm_bk,
      sv_W, sv_b, sm_Wv, sm_bv, WsC, bsC, T);

  embed_kernel<<<(B * T * N * D) / 256, 256, 0, stream>>>(X, pe, E_W, E_b, Ebuf);

  for (int l = 0; l < L; ++l) {
    temporal_kernel<<<B * N, 256, 0, stream>>>(Ebuf, WtC, btC, tm_Wo, tm_bo, ln_g, ln_b, Tn);
    spatial_kernel<<<B * T, 64, 0, stream>>>(Ebuf, WsC, bsC, sm_Wo, sm_bo, ln_g, ln_b, Sn);
    ff_kernel<<<(B * T * N + 255) / 256, 256, 0, stream>>>(Tn, Sn, ff1_W, ff1_b, ff2_W, ff2_b, ln_g, ln_b, Ebuf);
  }

  out_kernel<<<(B * T * N * M) / 256, 256, 0, stream>>>(Ebuf, op_W, op_b, X, out);
}

// Round 10
// 1313.029 us; speedup vs baseline: 2.6617x; 1.9009x over previous
//
#include <hip/hip_runtime.h>
#include <hip/hip_bf16.h>

typedef __hip_bfloat16 bf16;

constexpr int B  = 64, T = 120, N = 24, M = 3, D = 32;
constexpr int NH = 2, FD = 16, FF = 64, L = 3;
constexpr float SCALE = 0.25f;   // 1/sqrt(FD)
constexpr int ST  = 33;          // spatial LDS stride (f32)
constexpr int SK  = 40;          // attnt K/V/Q/O LDS stride (bf16, 80B rows)
constexpr int SS  = 124;         // attnt score row stride (bf16)
constexpr int CH2 = 30;          // attnt rows per chunk: 4 x 30 = 120 exactly
constexpr int RCH = 30;          // qkvt row chunks: 7680/256

__device__ __forceinline__ float b2f(bf16 x) { return __bfloat162float(x); }
__device__ __forceinline__ float blo(unsigned u) { return __uint_as_float(u << 16); }
__device__ __forceinline__ float bhi(unsigned u) { return __uint_as_float(u & 0xffff0000u); }
__device__ __forceinline__ unsigned pk2(float a, float b) {
  bf16 x = __float2bfloat16(a), y = __float2bfloat16(b);
  unsigned short ux = *reinterpret_cast<unsigned short*>(&x);
  unsigned short uy = *reinterpret_cast<unsigned short*>(&y);
  return (unsigned)ux | ((unsigned)uy << 16);
}

// ---------------------------------------------------------------------------
// Compose q/k/v chained linears: grid = 3*U blocks.  Wc = W1@W2, bc = b1@W2+b2.
// ---------------------------------------------------------------------------
__global__ __launch_bounds__(256) void compose3_kernel(
    const float* __restrict__ W1q, const float* __restrict__ b1q,
    const float* __restrict__ W2q, const float* __restrict__ b2q,
    const float* __restrict__ W1k, const float* __restrict__ b1k,
    const float* __restrict__ W2k, const float* __restrict__ b2k,
    const float* __restrict__ W1v, const float* __restrict__ b1v,
    const float* __restrict__ W2v, const float* __restrict__ b2v,
    float* __restrict__ Wc, float* __restrict__ bc, int U) {
  int fam = blockIdx.x / U;
  int n   = blockIdx.x % U;
  const float* W1 = (fam == 0) ? W1q : (fam == 1) ? W1k : W1v;
  const float* b1 = (fam == 0) ? b1q : (fam == 1) ? b1k : b1v;
  const float* W2 = (fam == 0) ? W2q : (fam == 1) ? W2k : W2v;
  const float* b2 = (fam == 0) ? b2q : (fam == 1) ? b2k : b2v;
  const float* w1 = W1 + n * D * D;
  const float* w2 = W2 + n * D * D;
  float* wc  = Wc + (size_t)(fam * U + n) * D * D;
  float* bcp = bc + (fam * U + n) * D;
  __shared__ float s1[D * D], s2[D * D];
  for (int i = threadIdx.x; i < D * D; i += 256) { s1[i] = w1[i]; s2[i] = w2[i]; }
  __syncthreads();
  for (int i = threadIdx.x; i < D * D; i += 256) {
    int d = i >> 5, f = i & 31;
    float acc = 0.f;
#pragma unroll
    for (int e = 0; e < D; ++e) acc += s1[d * D + e] * s2[e * D + f];
    wc[i] = acc;
  }
  if (threadIdx.x < D) {
    int f = threadIdx.x;
    float acc = b2[n * D + f];
#pragma unroll
    for (int e = 0; e < D; ++e) acc += b1[n * D + e] * s2[e * D + f];
    bcp[f] = acc;
  }
}

// ---------------------------------------------------------------------------
// E[b,t,n,d] = X@E_W + E_b + pe   (bf16 out)
// ---------------------------------------------------------------------------
__global__ __launch_bounds__(256) void embed_kernel(
    const float* __restrict__ X, const float* __restrict__ pe,
    const float* __restrict__ E_W, const float* __restrict__ E_b,
    bf16* __restrict__ E) {
  int idx = blockIdx.x * 256 + threadIdx.x;
  if (idx >= B * T * N * D) return;
  int d = idx & 31;
  int n = (idx >> 5) % N;
  int bt = idx / (D * N);
  int t = bt % T;
  const float* x = X + bt * (N * M) + n * M;
  float acc = E_b[n * D + d] + pe[t * D + d];
#pragma unroll
  for (int m = 0; m < M; ++m) acc += x[m] * E_W[(n * M + m) * D + d];
  E[idx] = __float2bfloat16(acc);
}

// ---------------------------------------------------------------------------
// qkvt: composed Q/K/V projections for the temporal path.
// Block = (n, chunk of 256 (b,t)-rows).  Weights in LDS (never registers).
// Writes Qt/Kt/Vt[b][n][t][32] bf16 (t-contiguous for attnt).
// ---------------------------------------------------------------------------
__global__ __launch_bounds__(256) void qkvt_kernel(
    const bf16* __restrict__ E, const float* __restrict__ WtC,
    const float* __restrict__ btC,
    bf16* __restrict__ Qt, bf16* __restrict__ Kt, bf16* __restrict__ Vt) {
  int n     = blockIdx.x / RCH;
  int chunk = blockIdx.x % RCH;
  __shared__ float wsh[3 * D * D];
  __shared__ float bsh[3 * D];
  int tid = threadIdx.x;
  for (int i = tid; i < 3 * D * D; i += 256) {
    int fam = i >> 10, idx = i & 1023;
    wsh[i] = WtC[(size_t)(fam * N + n) * D * D + idx];
  }
  if (tid < 3 * D) {
    int fam = tid >> 5, e = tid & 31;
    bsh[tid] = btC[(fam * N + n) * D + e];
  }
  __syncthreads();

  int row = chunk * 256 + tid;          // (b*T + t)
  int b = row / T, t = row % T;
  const bf16* er = E + ((size_t)row * N + n) * D;
  float x[D];
#pragma unroll
  for (int p = 0; p < 4; ++p) {
    uint4 u = *(const uint4*)&er[p * 8];
    x[p*8+0] = blo(u.x); x[p*8+1] = bhi(u.x);
    x[p*8+2] = blo(u.y); x[p*8+3] = bhi(u.y);
    x[p*8+4] = blo(u.z); x[p*8+5] = bhi(u.z);
    x[p*8+6] = blo(u.w); x[p*8+7] = bhi(u.w);
  }
  size_t dsto = (((size_t)b * N + n) * T + t) * D;
  bf16* dsts[3] = { Qt + dsto, Kt + dsto, Vt + dsto };
#pragma unroll
  for (int fam = 0; fam < 3; ++fam) {
    const float* w  = wsh + fam * D * D;
    const float* bi = bsh + fam * D;
    bf16* dst = dsts[fam];
#pragma unroll
    for (int g = 0; g < 4; ++g) {
      float a[8];
#pragma unroll
      for (int j = 0; j < 8; ++j) a[j] = bi[g * 8 + j];
#pragma unroll
      for (int d = 0; d < D; ++d) {
        float xv = x[d];
#pragma unroll
        for (int j = 0; j < 8; ++j) a[j] += xv * w[d * D + g * 8 + j];
      }
      uint4 o;
      o.x = pk2(a[0], a[1]); o.y = pk2(a[2], a[3]);
      o.z = pk2(a[4], a[5]); o.w = pk2(a[6], a[7]);
      *(uint4*)&dst[g * 8] = o;
    }
  }
}

// ---------------------------------------------------------------------------
// attnt: temporal attention + O-proj + residual + LN for a 30-row chunk.
// Block = (b, n, c), rows rg = 30c..30c+29 (4 x 30 = 120 EXACTLY — the R9
// 32-row chunking overran T and corrupted LDS/Tn).  Keys 0..rg (causal).
// Two-pass softmax: 4 lanes per (row,head); shfl max/sum; PV 4 indep chains.
// ---------------------------------------------------------------------------
__global__ __launch_bounds__(256) void attnt_kernel(
    const bf16* __restrict__ Qt, const bf16* __restrict__ Kt,
    const bf16* __restrict__ Vt, const bf16* __restrict__ E,
    const float* __restrict__ tm_Wo, const float* __restrict__ tm_bo,
    const float* __restrict__ ln_g, const float* __restrict__ ln_b,
    bf16* __restrict__ Tn) {
  int c  = blockIdx.x & 3;
  int bn = blockIdx.x >> 2;
  int n  = bn % N, b = bn / N;
  int nk = CH2 * (c + 1);               // keys staged: 30/60/90/120
  __shared__ __align__(16) bf16 Kl[T * SK], Vl[T * SK];
  __shared__ __align__(16) bf16 Ql[CH2 * SK], Ol[CH2 * SK];
  __shared__ __align__(16) bf16 Sc[2 * CH2 * SS];
  __shared__ float Wol[D * D], bol[D], gl[D], bbl[D];
  int tid = threadIdx.x;

  const bf16* Kg = Kt + (size_t)bn * T * D;
  const bf16* Vg = Vt + (size_t)bn * T * D;
  const bf16* Qg = Qt + ((size_t)bn * T + CH2 * c) * D;
  for (int i = tid; i < nk * 4; i += 256) {
    int r = i >> 2, p = i & 3;
    *(uint4*)&Kl[r * SK + p * 8] = *(const uint4*)&Kg[r * D + p * 8];
    *(uint4*)&Vl[r * SK + p * 8] = *(const uint4*)&Vg[r * D + p * 8];
  }
  if (tid < CH2 * 4) {
    int r = tid >> 2, p = tid & 3;
    *(uint4*)&Ql[r * SK + p * 8] = *(const uint4*)&Qg[r * D + p * 8];
  }
  for (int i = tid; i < D * D; i += 256) Wol[i] = tm_Wo[(size_t)n * D * D + i];
  if (tid < D) {
    bol[tid] = tm_bo[n * D + tid];
    gl[tid]  = ln_g[tid];
    bbl[tid] = ln_b[tid];
  }
  __syncthreads();

  // ---- scores + softmax + PV: task = (row, head), 4 lanes per task ----
  {
    int task = tid >> 2, sl = tid & 3;
    if (task < 2 * CH2) {
      int rl = task >> 1, h = task & 1, ho = h * FD;
      int rg = CH2 * c + rl, kend = rg + 1;
      uint4 q0 = *(const uint4*)&Ql[rl * SK + ho];
      uint4 q1 = *(const uint4*)&Ql[rl * SK + ho + 8];
      float qf[16];
      qf[0]  = blo(q0.x); qf[1]  = bhi(q0.x); qf[2]  = blo(q0.y); qf[3]  = bhi(q0.y);
      qf[4]  = blo(q0.z); qf[5]  = bhi(q0.z); qf[6]  = blo(q0.w); qf[7]  = bhi(q0.w);
      qf[8]  = blo(q1.x); qf[9]  = bhi(q1.x); qf[10] = blo(q1.y); qf[11] = bhi(q1.y);
      qf[12] = blo(q1.z); qf[13] = bhi(q1.z); qf[14] = blo(q1.w); qf[15] = bhi(q1.w);
      bf16* srow = &Sc[task * SS];
      float mx = -3e38f;
#pragma unroll 1
      for (int k = sl; k < kend; k += 4) {
        uint4 ka = *(const uint4*)&Kl[k * SK + ho];
        uint4 kb = *(const uint4*)&Kl[k * SK + ho + 8];
        float s = qf[0]*blo(ka.x)  + qf[1]*bhi(ka.x)  + qf[2]*blo(ka.y)  + qf[3]*bhi(ka.y)
                + qf[4]*blo(ka.z)  + qf[5]*bhi(ka.z)  + qf[6]*blo(ka.w)  + qf[7]*bhi(ka.w)
                + qf[8]*blo(kb.x)  + qf[9]*bhi(kb.x)  + qf[10]*blo(kb.y) + qf[11]*bhi(kb.y)
                + qf[12]*blo(kb.z) + qf[13]*bhi(kb.z) + qf[14]*blo(kb.w) + qf[15]*bhi(kb.w);
        s *= SCALE;
        srow[k] = __float2bfloat16(s);
        mx = fmaxf(mx, s);
      }
      mx = fmaxf(mx, __shfl_xor(mx, 1, 64));
      mx = fmaxf(mx, __shfl_xor(mx, 2, 64));
      float l = 0.f;
#pragma unroll 1
      for (int k = sl; k < kend; k += 4) {
        float p = __expf(b2f(srow[k]) - mx);
        srow[k] = __float2bfloat16(p);
        l += p;
      }
      l += __shfl_xor(l, 1, 64);
      l += __shfl_xor(l, 2, 64);
      float rli = 1.f / l;
      int fo = ho + sl * 4;
      float a0 = 0.f, a1 = 0.f, a2 = 0.f, a3 = 0.f;
#pragma unroll 2
      for (int k = 0; k < kend; ++k) {
        float p = b2f(srow[k]);
        uint2 v = *(const uint2*)&Vl[k * SK + fo];
        a0 += p * blo(v.x); a1 += p * bhi(v.x);
        a2 += p * blo(v.y); a3 += p * bhi(v.y);
      }
      uint2 ou;
      ou.x = pk2(a0 * rli, a1 * rli);
      ou.y = pk2(a2 * rli, a3 * rli);
      *(uint2*)&Ol[rl * SK + fo] = ou;
    }
  }
  __syncthreads();

  // ---- O-proj + residual + LN: thread = (row, e-quad), 8 lanes per row ----
  {
    int rl = tid >> 3, q = tid & 7, e0 = q * 4;
    if (rl < CH2) {
      int rg = CH2 * c + rl;
      size_t rowo = ((size_t)(b * T + rg) * N + n) * D;
      uint2 eu = *(const uint2*)&E[rowo + e0];
      float res[4] = { blo(eu.x), bhi(eu.x), blo(eu.y), bhi(eu.y) };
      float o[4], s1 = 0.f, s2 = 0.f;
#pragma unroll
      for (int j = 0; j < 4; ++j) {
        int e = e0 + j;
        float a = bol[e];
#pragma unroll
        for (int d = 0; d < D; ++d) a += b2f(Ol[rl * SK + d]) * Wol[d * D + e];
        a += res[j];
        o[j] = a; s1 += a; s2 += a * a;
      }
      s1 += __shfl_xor(s1, 1, 64); s2 += __shfl_xor(s2, 1, 64);
      s1 += __shfl_xor(s1, 2, 64); s2 += __shfl_xor(s2, 2, 64);
      s1 += __shfl_xor(s1, 4, 64); s2 += __shfl_xor(s2, 4, 64);
      float mu  = s1 * (1.f / D);
      float var = s2 * (1.f / D) - mu * mu;
      float r = rsqrtf(var + 1e-5f);
      uint2 ou;
      ou.x = pk2((o[0]-mu)*r*gl[e0]+bbl[e0],    (o[1]-mu)*r*gl[e0+1]+bbl[e0+1]);
      ou.y = pk2((o[2]-mu)*r*gl[e0+2]+bbl[e0+2],(o[3]-mu)*r*gl[e0+3]+bbl[e0+3]);
      *(uint2*)&Tn[rowo + e0] = ou;
    }
  }
}

// ---------------------------------------------------------------------------
// Spatial attention, fused per (b, t) — R6-proven form.  Grid is t-major so
// 64 consecutive blocks share one timestep's weights (L2 reuse).
// ---------------------------------------------------------------------------
__global__ __launch_bounds__(64) void spatial_kernel(
    const bf16* __restrict__ E, const float* __restrict__ WsC,
    const float* __restrict__ bsC, const float* __restrict__ sm_Wo,
    const float* __restrict__ sm_bo, const float* __restrict__ ln_g,
    const float* __restrict__ ln_b, bf16* __restrict__ Sn) {
  int t = blockIdx.x / B;
  int b = blockIdx.x % B;
  __shared__ float Es[N * ST], Ks[N * ST], Vs[N * ST], Os[N * ST];
  int tid = threadIdx.x;
  int e = tid & 31;

  for (int i = tid; i < N * D; i += 64) {
    int nn = i >> 5, d = i & 31;
    Es[nn * ST + d] = b2f(E[((size_t)(b * T + t) * N + nn) * D + d]);
  }
  __syncthreads();

  {
    const float* wqg = WsC + (0 * T + t) * D * D;
    const float* wkg = WsC + (1 * T + t) * D * D;
    float wq[D], wk[D];
#pragma unroll
    for (int d = 0; d < D; ++d) { wq[d] = wqg[d * D + e]; wk[d] = wkg[d * D + e]; }
    float bqv = bsC[(0 * T + t) * D + e];
    float bkv = bsC[(1 * T + t) * D + e];
#pragma unroll
    for (int k = 0; k < N * D / 64; ++k) {
      int nn = (tid + k * 64) >> 5;
      float aq = bqv, ak = bkv;
#pragma unroll
      for (int d = 0; d < D; ++d) {
        float x = Es[nn * ST + d];
        aq += x * wq[d];
        ak += x * wk[d];
      }
      Os[nn * ST + e] = aq;
      Ks[nn * ST + e] = ak;
    }
  }
  {
    const float* wvg = WsC + (2 * T + t) * D * D;
    float wv[D];
#pragma unroll
    for (int d = 0; d < D; ++d) wv[d] = wvg[d * D + e];
    float bvv = bsC[(2 * T + t) * D + e];
#pragma unroll
    for (int k = 0; k < N * D / 64; ++k) {
      int nn = (tid + k * 64) >> 5;
      float av = bvv;
#pragma unroll
      for (int d = 0; d < D; ++d) av += Es[nn * ST + d] * wv[d];
      Vs[nn * ST + e] = av;
    }
  }
  __syncthreads();

  if (tid < N * NH) {
    int nn = tid >> 1, h = tid & 1;
    int ho = h * FD;
    float q[FD];
#pragma unroll
    for (int f = 0; f < FD; ++f) q[f] = Os[nn * ST + ho + f];
    float sc[N];
    float m = -1e30f;
#pragma unroll
    for (int k = 0; k < N; ++k) {
      float s = 0.f;
#pragma unroll
      for (int f = 0; f < FD; ++f) s += q[f] * Ks[k * ST + ho + f];
      s *= SCALE;
      sc[k] = s;
      m = fmaxf(m, s);
    }
    float l = 0.f;
#pragma unroll
    for (int k = 0; k < N; ++k) { sc[k] = __expf(sc[k] - m); l += sc[k]; }
    float rl = 1.f / l;
#pragma unroll
    for (int f = 0; f < FD; ++f) {
      float a = 0.f;
#pragma unroll
      for (int k = 0; k < N; ++k) a += sc[k] * Vs[k * ST + ho + f];
      Os[nn * ST + ho + f] = a * rl;
    }
  }
  __syncthreads();

  {
    const float* wog = sm_Wo + t * D * D;
    float wo[D];
#pragma unroll
    for (int d = 0; d < D; ++d) wo[d] = wog[d * D + e];
    float bov = sm_bo[t * D + e];
#pragma unroll
    for (int k = 0; k < N * D / 64; ++k) {
      int nn = (tid + k * 64) >> 5;
      float a = bov;
#pragma unroll
      for (int d = 0; d < D; ++d) a += Os[nn * ST + d] * wo[d];
      Ks[nn * ST + e] = a + Es[nn * ST + e];
    }
  }
  __syncthreads();

  if (tid < N) {
    int nn = tid;
    float mu = 0.f;
#pragma unroll
    for (int d = 0; d < D; ++d) mu += Ks[nn * ST + d];
    mu *= (1.f / D);
    float var = 0.f;
#pragma unroll
    for (int d = 0; d < D; ++d) { float c = Ks[nn * ST + d] - mu; var += c * c; }
    var *= (1.f / D);
    float r = rsqrtf(var + 1e-5f);
#pragma unroll
    for (int d = 0; d < D; ++d)
      Sn[((size_t)(b * T + t) * N + nn) * D + d] =
          __float2bfloat16((Ks[nn * ST + d] - mu) * r * ln_g[d] + ln_b[d]);
  }
}

// ---------------------------------------------------------------------------
// ts = Tn + Sn; ff = relu(ts@W1+b1)@W2+b2; E = LN(ff + ts).  Row per thread.
// ---------------------------------------------------------------------------
__global__ __launch_bounds__(256) void ff_kernel(
    const bf16* __restrict__ Tn, const bf16* __restrict__ Sn,
    const float* __restrict__ W1, const float* __restrict__ b1,
    const float* __restrict__ W2, const float* __restrict__ b2,
    const float* __restrict__ ln_g, const float* __restrict__ ln_b,
    bf16* __restrict__ E) {
  __shared__ float w1[D * FF], w2[FF * D], bb1[FF], bb2[D], g[D], bbn[D];
  int tid = threadIdx.x;
  for (int i = tid; i < D * FF; i += 256) { w1[i] = W1[i]; w2[i] = W2[i]; }
  if (tid < FF) bb1[tid] = b1[tid];
  if (tid < D) { bb2[tid] = b2[tid]; g[tid] = ln_g[tid]; bbn[tid] = ln_b[tid]; }
  __syncthreads();
  int row = blockIdx.x * 256 + tid;
  if (row >= B * T * N) return;
  float ts[D];
#pragma unroll
  for (int d = 0; d < D; ++d)
    ts[d] = b2f(Tn[(size_t)row * D + d]) + b2f(Sn[(size_t)row * D + d]);
  float x[D];
#pragma unroll
  for (int d = 0; d < D; ++d) x[d] = bb2[d] + ts[d];
#pragma unroll 1
  for (int c = 0; c < 2; ++c) {
    float hh[32];
#pragma unroll
    for (int j = 0; j < 32; ++j) {
      int jj = c * 32 + j;
      float a = bb1[jj];
#pragma unroll
      for (int d = 0; d < D; ++d) a += ts[d] * w1[d * FF + jj];
      hh[j] = fmaxf(a, 0.f);
    }
#pragma unroll
    for (int e2 = 0; e2 < D; ++e2) {
      float a = 0.f;
#pragma unroll
      for (int j = 0; j < 32; ++j) a += hh[j] * w2[(c * 32 + j) * D + e2];
      x[e2] += a;
    }
  }
  float mu = 0.f;
#pragma unroll
  for (int e2 = 0; e2 < D; ++e2) mu += x[e2];
  mu *= (1.f / D);
  float var = 0.f;
#pragma unroll
  for (int e2 = 0; e2 < D; ++e2) { float c = x[e2] - mu; var += c * c; }
  var *= (1.f / D);
  float r = rsqrtf(var + 1e-5f);
#pragma unroll
  for (int e2 = 0; e2 < D; ++e2)
    E[(size_t)row * D + e2] = __float2bfloat16((x[e2] - mu) * r * g[e2] + bbn[e2]);
}

// ---------------------------------------------------------------------------
// out = E@op_W + op_b + X   (f32 out)
// ---------------------------------------------------------------------------
__global__ __launch_bounds__(256) void out_kernel(
    const bf16* __restrict__ E, const float* __restrict__ op_W,
    const float* __restrict__ op_b, const float* __restrict__ X,
    float* __restrict__ out) {
  int idx = blockIdx.x * 256 + threadIdx.x;
  if (idx >= B * T * N * M) return;
  int m  = idx % M;
  int n  = (idx / M) % N;
  int bt = idx / (M * N);
  float acc = op_b[n * M + m];
  const bf16* e = E + ((size_t)bt * N + n) * D;
#pragma unroll
  for (int d = 0; d < D; ++d) acc += b2f(e[d]) * op_W[(n * D + d) * M + m];
  acc += X[idx];
  out[idx] = acc;
}

// ---------------------------------------------------------------------------
extern "C" void kernel_launch(void* const* d_in, const int* in_sizes, int n_in,
                              void* d_out, int out_size, void* d_ws, size_t ws_size,
                              hipStream_t stream) {
  const float* X     = (const float*)d_in[0];
  const float* pe    = (const float*)d_in[1];
  const float* E_W   = (const float*)d_in[2];
  const float* E_b   = (const float*)d_in[3];
  const float* tq_W  = (const float*)d_in[4];
  const float* tq_b  = (const float*)d_in[5];
  const float* tk_W  = (const float*)d_in[6];
  const float* tk_b  = (const float*)d_in[7];
  const float* tv_W  = (const float*)d_in[8];
  const float* tv_b  = (const float*)d_in[9];
  const float* tm_Wq = (const float*)d_in[10];
  const float* tm_bq = (const float*)d_in[11];
  const float* tm_Wk = (const float*)d_in[12];
  const float* tm_bk = (const float*)d_in[13];
  const float* tm_Wv = (const float*)d_in[14];
  const float* tm_bv = (const float*)d_in[15];
  const float* tm_Wo = (const float*)d_in[16];
  const float* tm_bo = (const float*)d_in[17];
  const float* sq_W  = (const float*)d_in[18];
  const float* sq_b  = (const float*)d_in[19];
  const float* sk_W  = (const float*)d_in[20];
  const float* sk_b  = (const float*)d_in[21];
  const float* sv_W  = (const float*)d_in[22];
  const float* sv_b  = (const float*)d_in[23];
  const float* sm_Wq = (const float*)d_in[24];
  const float* sm_bq = (const float*)d_in[25];
  const float* sm_Wk = (const float*)d_in[26];
  const float* sm_bk = (const float*)d_in[27];
  const float* sm_Wv = (const float*)d_in[28];
  const float* sm_bv = (const float*)d_in[29];
  const float* sm_Wo = (const float*)d_in[30];
  const float* sm_bo = (const float*)d_in[31];
  const float* ff1_W = (const float*)d_in[32];
  const float* ff1_b = (const float*)d_in[33];
  const float* ff2_W = (const float*)d_in[34];
  const float* ff2_b = (const float*)d_in[35];
  const float* ln_g  = (const float*)d_in[36];
  const float* ln_b  = (const float*)d_in[37];
  const float* op_W  = (const float*)d_in[38];
  const float* op_b  = (const float*)d_in[39];
  float* out = (float*)d_out;

  // ws layout: composed weights (f32), then bf16 activations.
  // Sn aliases Qt (Qt dead after attnt; spatial writes it before ff reads).
  float* WtC = (float*)d_ws;                         // 3*N*D*D
  float* btC = WtC + 3 * N * D * D;                  // 3*N*D
  float* WsC = btC + 3 * N * D;                      // 3*T*D*D
  float* bsC = WsC + 3 * T * D * D;                  // 3*T*D
  size_t act = (size_t)B * T * N * D;
  bf16* Ebuf = (bf16*)(bsC + 3 * T * D);
  bf16* Tn   = Ebuf + act;
  bf16* Qt   = Tn + act;
  bf16* Kt   = Qt + act;
  bf16* Vt   = Kt + act;
  bf16* Sn   = Qt;                                   // alias
  // total ~60.8 MB

  compose3_kernel<<<3 * N, 256, 0, stream>>>(
      tq_W, tq_b, tm_Wq, tm_bq, tk_W, tk_b, tm_Wk, tm_bk,
      tv_W, tv_b, tm_Wv, tm_bv, WtC, btC, N);
  compose3_kernel<<<3 * T, 256, 0, stream>>>(
      sq_W, sq_b, sm_Wq, sm_bq, sk_W, sk_b, sm_Wk, sm_bk,
      sv_W, sv_b, sm_Wv, sm_bv, WsC, bsC, T);

  embed_kernel<<<(B * T * N * D) / 256, 256, 0, stream>>>(X, pe, E_W, E_b, Ebuf);

  for (int l = 0; l < L; ++l) {
    qkvt_kernel<<<N * RCH, 256, 0, stream>>>(Ebuf, WtC, btC, Qt, Kt, Vt);
    attnt_kernel<<<B * N * 4, 256, 0, stream>>>(Qt, Kt, Vt, Ebuf, tm_Wo, tm_bo, ln_g, ln_b, Tn);
    spatial_kernel<<<B * T, 64, 0, stream>>>(Ebuf, WsC, bsC, sm_Wo, sm_bo, ln_g, ln_b, Sn);
    ff_kernel<<<(B * T * N + 255) / 256, 256, 0, stream>>>(Tn, Sn, ff1_W, ff1_b, ff2_W, ff2_b, ln_g, ln_b, Ebuf);
  }

  out_kernel<<<(B * T * N * M + 255) / 256, 256, 0, stream>>>(Ebuf, op_W, op_b, X, out);
}

// Round 11
// 1302.904 us; speedup vs baseline: 2.6824x; 1.0078x over previous
//
#include <hip/hip_runtime.h>
#include <hip/hip_bf16.h>

typedef __hip_bfloat16 bf16;

constexpr int B  = 64, T = 120, N = 24, M = 3, D = 32;
constexpr int NH = 2, FD = 16, FF = 64, L = 3;
constexpr float SCALE = 0.25f;   // 1/sqrt(FD)
constexpr int ST  = 33;          // spatial LDS stride (f32)
constexpr int SK  = 40;          // attnt Q LDS stride (bf16, 80B rows)
constexpr int SKF = 36;          // attnt K/V/O LDS stride (f32, 144B rows; conflict-free)
constexpr int SS  = 124;         // attnt score row stride (bf16; task*248B is 8B-aligned)
constexpr int CH2 = 30;          // attnt rows per chunk: 4 x 30 = 120 exactly
constexpr int RCH = 30;          // qkvt row chunks: 7680/256

__device__ __forceinline__ float b2f(bf16 x) { return __bfloat162float(x); }
__device__ __forceinline__ float blo(unsigned u) { return __uint_as_float(u << 16); }
__device__ __forceinline__ float bhi(unsigned u) { return __uint_as_float(u & 0xffff0000u); }
__device__ __forceinline__ unsigned pk2(float a, float b) {
  bf16 x = __float2bfloat16(a), y = __float2bfloat16(b);
  unsigned short ux = *reinterpret_cast<unsigned short*>(&x);
  unsigned short uy = *reinterpret_cast<unsigned short*>(&y);
  return (unsigned)ux | ((unsigned)uy << 16);
}

// ---------------------------------------------------------------------------
// Compose q/k/v chained linears: grid = 3*U blocks.  Wc = W1@W2, bc = b1@W2+b2.
// ---------------------------------------------------------------------------
__global__ __launch_bounds__(256) void compose3_kernel(
    const float* __restrict__ W1q, const float* __restrict__ b1q,
    const float* __restrict__ W2q, const float* __restrict__ b2q,
    const float* __restrict__ W1k, const float* __restrict__ b1k,
    const float* __restrict__ W2k, const float* __restrict__ b2k,
    const float* __restrict__ W1v, const float* __restrict__ b1v,
    const float* __restrict__ W2v, const float* __restrict__ b2v,
    float* __restrict__ Wc, float* __restrict__ bc, int U) {
  int fam = blockIdx.x / U;
  int n   = blockIdx.x % U;
  const float* W1 = (fam == 0) ? W1q : (fam == 1) ? W1k : W1v;
  const float* b1 = (fam == 0) ? b1q : (fam == 1) ? b1k : b1v;
  const float* W2 = (fam == 0) ? W2q : (fam == 1) ? W2k : W2v;
  const float* b2 = (fam == 0) ? b2q : (fam == 1) ? b2k : b2v;
  const float* w1 = W1 + n * D * D;
  const float* w2 = W2 + n * D * D;
  float* wc  = Wc + (size_t)(fam * U + n) * D * D;
  float* bcp = bc + (fam * U + n) * D;
  __shared__ float s1[D * D], s2[D * D];
  for (int i = threadIdx.x; i < D * D; i += 256) { s1[i] = w1[i]; s2[i] = w2[i]; }
  __syncthreads();
  for (int i = threadIdx.x; i < D * D; i += 256) {
    int d = i >> 5, f = i & 31;
    float acc = 0.f;
#pragma unroll
    for (int e = 0; e < D; ++e) acc += s1[d * D + e] * s2[e * D + f];
    wc[i] = acc;
  }
  if (threadIdx.x < D) {
    int f = threadIdx.x;
    float acc = b2[n * D + f];
#pragma unroll
    for (int e = 0; e < D; ++e) acc += b1[n * D + e] * s2[e * D + f];
    bcp[f] = acc;
  }
}

// ---------------------------------------------------------------------------
// E[b,t,n,d] = X@E_W + E_b + pe   (bf16 out)
// ---------------------------------------------------------------------------
__global__ __launch_bounds__(256) void embed_kernel(
    const float* __restrict__ X, const float* __restrict__ pe,
    const float* __restrict__ E_W, const float* __restrict__ E_b,
    bf16* __restrict__ E) {
  int idx = blockIdx.x * 256 + threadIdx.x;
  if (idx >= B * T * N * D) return;
  int d = idx & 31;
  int n = (idx >> 5) % N;
  int bt = idx / (D * N);
  int t = bt % T;
  const float* x = X + bt * (N * M) + n * M;
  float acc = E_b[n * D + d] + pe[t * D + d];
#pragma unroll
  for (int m = 0; m < M; ++m) acc += x[m] * E_W[(n * M + m) * D + d];
  E[idx] = __float2bfloat16(acc);
}

// ---------------------------------------------------------------------------
// qkvt: composed Q/K/V projections for the temporal path.
// Block = (n, chunk of 256 (b,t)-rows).  Weights in LDS (never registers).
// Writes Qt/Kt/Vt[b][n][t][32] bf16 (t-contiguous for attnt).
// ---------------------------------------------------------------------------
__global__ __launch_bounds__(256) void qkvt_kernel(
    const bf16* __restrict__ E, const float* __restrict__ WtC,
    const float* __restrict__ btC,
    bf16* __restrict__ Qt, bf16* __restrict__ Kt, bf16* __restrict__ Vt) {
  int n     = blockIdx.x / RCH;
  int chunk = blockIdx.x % RCH;
  __shared__ float wsh[3 * D * D];
  __shared__ float bsh[3 * D];
  int tid = threadIdx.x;
  for (int i = tid; i < 3 * D * D; i += 256) {
    int fam = i >> 10, idx = i & 1023;
    wsh[i] = WtC[(size_t)(fam * N + n) * D * D + idx];
  }
  if (tid < 3 * D) {
    int fam = tid >> 5, e = tid & 31;
    bsh[tid] = btC[(fam * N + n) * D + e];
  }
  __syncthreads();

  int row = chunk * 256 + tid;          // (b*T + t)
  int b = row / T, t = row % T;
  const bf16* er = E + ((size_t)row * N + n) * D;
  float x[D];
#pragma unroll
  for (int p = 0; p < 4; ++p) {
    uint4 u = *(const uint4*)&er[p * 8];
    x[p*8+0] = blo(u.x); x[p*8+1] = bhi(u.x);
    x[p*8+2] = blo(u.y); x[p*8+3] = bhi(u.y);
    x[p*8+4] = blo(u.z); x[p*8+5] = bhi(u.z);
    x[p*8+6] = blo(u.w); x[p*8+7] = bhi(u.w);
  }
  size_t dsto = (((size_t)b * N + n) * T + t) * D;
  bf16* dsts[3] = { Qt + dsto, Kt + dsto, Vt + dsto };
#pragma unroll
  for (int fam = 0; fam < 3; ++fam) {
    const float* w  = wsh + fam * D * D;
    const float* bi = bsh + fam * D;
    bf16* dst = dsts[fam];
#pragma unroll
    for (int g = 0; g < 4; ++g) {
      float a[8];
#pragma unroll
      for (int j = 0; j < 8; ++j) a[j] = bi[g * 8 + j];
#pragma unroll
      for (int d = 0; d < D; ++d) {
        float xv = x[d];
#pragma unroll
        for (int j = 0; j < 8; ++j) a[j] += xv * w[d * D + g * 8 + j];
      }
      uint4 o;
      o.x = pk2(a[0], a[1]); o.y = pk2(a[2], a[3]);
      o.z = pk2(a[4], a[5]); o.w = pk2(a[6], a[7]);
      *(uint4*)&dst[g * 8] = o;
    }
  }
}

// ---------------------------------------------------------------------------
// attnt v2: temporal attention + O-proj + residual + LN for a 30-row chunk.
// ILP fix: K/V staged f32 (no unpacks in hot loops; stride 36 = conflict-free),
// score = 4 partial sums (chain 16 -> ~6), PV = 4-key batch with 4 independent
// accumulator sets (chain kend -> kend/4) + batched p loads.
// ---------------------------------------------------------------------------
__global__ __launch_bounds__(256) void attnt_kernel(
    const bf16* __restrict__ Qt, const bf16* __restrict__ Kt,
    const bf16* __restrict__ Vt, const bf16* __restrict__ E,
    const float* __restrict__ tm_Wo, const float* __restrict__ tm_bo,
    const float* __restrict__ ln_g, const float* __restrict__ ln_b,
    bf16* __restrict__ Tn) {
  int c  = blockIdx.x & 3;
  int bn = blockIdx.x >> 2;
  int n  = bn % N, b = bn / N;
  int nk = CH2 * (c + 1);               // keys staged: 30/60/90/120
  __shared__ __align__(16) float Kl[T * SKF], Vl[T * SKF];
  __shared__ __align__(16) bf16  Ql[CH2 * SK];
  __shared__ __align__(16) float Ol[CH2 * SKF];
  __shared__ __align__(16) bf16  Sc[2 * CH2 * SS];
  __shared__ float Wol[D * D], bol[D], gl[D], bbl[D];
  int tid = threadIdx.x;

  const bf16* Kg = Kt + (size_t)bn * T * D;
  const bf16* Vg = Vt + (size_t)bn * T * D;
  const bf16* Qg = Qt + ((size_t)bn * T + CH2 * c) * D;
  for (int i = tid; i < nk * 4; i += 256) {
    int r = i >> 2, p = i & 3;
    uint4 ku = *(const uint4*)&Kg[r * D + p * 8];
    *(float4*)&Kl[r * SKF + p * 8]     = make_float4(blo(ku.x), bhi(ku.x), blo(ku.y), bhi(ku.y));
    *(float4*)&Kl[r * SKF + p * 8 + 4] = make_float4(blo(ku.z), bhi(ku.z), blo(ku.w), bhi(ku.w));
    uint4 vu = *(const uint4*)&Vg[r * D + p * 8];
    *(float4*)&Vl[r * SKF + p * 8]     = make_float4(blo(vu.x), bhi(vu.x), blo(vu.y), bhi(vu.y));
    *(float4*)&Vl[r * SKF + p * 8 + 4] = make_float4(blo(vu.z), bhi(vu.z), blo(vu.w), bhi(vu.w));
  }
  if (tid < CH2 * 4) {
    int r = tid >> 2, p = tid & 3;
    *(uint4*)&Ql[r * SK + p * 8] = *(const uint4*)&Qg[r * D + p * 8];
  }
  for (int i = tid; i < D * D; i += 256) Wol[i] = tm_Wo[(size_t)n * D * D + i];
  if (tid < D) {
    bol[tid] = tm_bo[n * D + tid];
    gl[tid]  = ln_g[tid];
    bbl[tid] = ln_b[tid];
  }
  __syncthreads();

  // ---- scores + softmax + PV: task = (row, head), 4 lanes per task ----
  {
    int task = tid >> 2, sl = tid & 3;
    if (task < 2 * CH2) {
      int rl = task >> 1, h = task & 1, ho = h * FD;
      int rg = CH2 * c + rl, kend = rg + 1;
      uint4 q0 = *(const uint4*)&Ql[rl * SK + ho];
      uint4 q1 = *(const uint4*)&Ql[rl * SK + ho + 8];
      float qf[16];
      qf[0]  = blo(q0.x); qf[1]  = bhi(q0.x); qf[2]  = blo(q0.y); qf[3]  = bhi(q0.y);
      qf[4]  = blo(q0.z); qf[5]  = bhi(q0.z); qf[6]  = blo(q0.w); qf[7]  = bhi(q0.w);
      qf[8]  = blo(q1.x); qf[9]  = bhi(q1.x); qf[10] = blo(q1.y); qf[11] = bhi(q1.y);
      qf[12] = blo(q1.z); qf[13] = bhi(q1.z); qf[14] = blo(q1.w); qf[15] = bhi(q1.w);
      bf16* srow = &Sc[task * SS];
      float mx = -3e38f;
#pragma unroll 1
      for (int k = sl; k < kend; k += 4) {
        const float4 k0 = *(const float4*)&Kl[k * SKF + ho];
        const float4 k1 = *(const float4*)&Kl[k * SKF + ho + 4];
        const float4 k2 = *(const float4*)&Kl[k * SKF + ho + 8];
        const float4 k3 = *(const float4*)&Kl[k * SKF + ho + 12];
        float s0 = qf[0]*k0.x  + qf[1]*k0.y  + qf[2]*k0.z  + qf[3]*k0.w;
        float s1 = qf[4]*k1.x  + qf[5]*k1.y  + qf[6]*k1.z  + qf[7]*k1.w;
        float s2 = qf[8]*k2.x  + qf[9]*k2.y  + qf[10]*k2.z + qf[11]*k2.w;
        float s3 = qf[12]*k3.x + qf[13]*k3.y + qf[14]*k3.z + qf[15]*k3.w;
        float s = ((s0 + s1) + (s2 + s3)) * SCALE;
        srow[k] = __float2bfloat16(s);
        mx = fmaxf(mx, s);
      }
      mx = fmaxf(mx, __shfl_xor(mx, 1, 64));
      mx = fmaxf(mx, __shfl_xor(mx, 2, 64));
      float l = 0.f;
#pragma unroll 1
      for (int k = sl; k < kend; k += 4) {
        float p = __expf(b2f(srow[k]) - mx);
        srow[k] = __float2bfloat16(p);
        l += p;
      }
      l += __shfl_xor(l, 1, 64);
      l += __shfl_xor(l, 2, 64);
      float rli = 1.f / l;
      int fo = ho + sl * 4;
      float4 acc0 = make_float4(0.f, 0.f, 0.f, 0.f);
      float4 acc1 = make_float4(0.f, 0.f, 0.f, 0.f);
      float4 acc2 = make_float4(0.f, 0.f, 0.f, 0.f);
      float4 acc3 = make_float4(0.f, 0.f, 0.f, 0.f);
      int k4 = kend & ~3;
#pragma unroll 1
      for (int k = 0; k < k4; k += 4) {
        uint2 pu = *(const uint2*)&srow[k];   // 4 bf16 p (8B-aligned)
        float p0 = blo(pu.x), p1 = bhi(pu.x), p2 = blo(pu.y), p3 = bhi(pu.y);
        const float4 v0 = *(const float4*)&Vl[(k + 0) * SKF + fo];
        const float4 v1 = *(const float4*)&Vl[(k + 1) * SKF + fo];
        const float4 v2 = *(const float4*)&Vl[(k + 2) * SKF + fo];
        const float4 v3 = *(const float4*)&Vl[(k + 3) * SKF + fo];
        acc0.x += p0*v0.x; acc0.y += p0*v0.y; acc0.z += p0*v0.z; acc0.w += p0*v0.w;
        acc1.x += p1*v1.x; acc1.y += p1*v1.y; acc1.z += p1*v1.z; acc1.w += p1*v1.w;
        acc2.x += p2*v2.x; acc2.y += p2*v2.y; acc2.z += p2*v2.z; acc2.w += p2*v2.w;
        acc3.x += p3*v3.x; acc3.y += p3*v3.y; acc3.z += p3*v3.z; acc3.w += p3*v3.w;
      }
#pragma unroll 1
      for (int k = k4; k < kend; ++k) {
        float p = b2f(srow[k]);
        const float4 v = *(const float4*)&Vl[k * SKF + fo];
        acc0.x += p*v.x; acc0.y += p*v.y; acc0.z += p*v.z; acc0.w += p*v.w;
      }
      float4 o;
      o.x = ((acc0.x + acc1.x) + (acc2.x + acc3.x)) * rli;
      o.y = ((acc0.y + acc1.y) + (acc2.y + acc3.y)) * rli;
      o.z = ((acc0.z + acc1.z) + (acc2.z + acc3.z)) * rli;
      o.w = ((acc0.w + acc1.w) + (acc2.w + acc3.w)) * rli;
      *(float4*)&Ol[rl * SKF + fo] = o;
    }
  }
  __syncthreads();

  // ---- O-proj + residual + LN: thread = (row, e-quad), 8 lanes per row ----
  {
    int rl = tid >> 3, q = tid & 7, e0 = q * 4;
    if (rl < CH2) {
      int rg = CH2 * c + rl;
      size_t rowo = ((size_t)(b * T + rg) * N + n) * D;
      uint2 eu = *(const uint2*)&E[rowo + e0];
      float res[4] = { blo(eu.x), bhi(eu.x), blo(eu.y), bhi(eu.y) };
      float o[4], s1 = 0.f, s2 = 0.f;
#pragma unroll
      for (int j = 0; j < 4; ++j) {
        int e = e0 + j;
        float aa = 0.f, ab = 0.f;
#pragma unroll
        for (int d = 0; d < D; d += 2) {
          aa += Ol[rl * SKF + d]     * Wol[d * D + e];
          ab += Ol[rl * SKF + d + 1] * Wol[(d + 1) * D + e];
        }
        float a = bol[e] + aa + ab + res[j];
        o[j] = a; s1 += a; s2 += a * a;
      }
      s1 += __shfl_xor(s1, 1, 64); s2 += __shfl_xor(s2, 1, 64);
      s1 += __shfl_xor(s1, 2, 64); s2 += __shfl_xor(s2, 2, 64);
      s1 += __shfl_xor(s1, 4, 64); s2 += __shfl_xor(s2, 4, 64);
      float mu  = s1 * (1.f / D);
      float var = s2 * (1.f / D) - mu * mu;
      float r = rsqrtf(var + 1e-5f);
      uint2 ou;
      ou.x = pk2((o[0]-mu)*r*gl[e0]+bbl[e0],    (o[1]-mu)*r*gl[e0+1]+bbl[e0+1]);
      ou.y = pk2((o[2]-mu)*r*gl[e0+2]+bbl[e0+2],(o[3]-mu)*r*gl[e0+3]+bbl[e0+3]);
      *(uint2*)&Tn[rowo + e0] = ou;
    }
  }
}

// ---------------------------------------------------------------------------
// Spatial attention, fused per (b, t) — R6-proven form, t-major grid.
// ---------------------------------------------------------------------------
__global__ __launch_bounds__(64) void spatial_kernel(
    const bf16* __restrict__ E, const float* __restrict__ WsC,
    const float* __restrict__ bsC, const float* __restrict__ sm_Wo,
    const float* __restrict__ sm_bo, const float* __restrict__ ln_g,
    const float* __restrict__ ln_b, bf16* __restrict__ Sn) {
  int t = blockIdx.x / B;
  int b = blockIdx.x % B;
  __shared__ float Es[N * ST], Ks[N * ST], Vs[N * ST], Os[N * ST];
  int tid = threadIdx.x;
  int e = tid & 31;

  for (int i = tid; i < N * D; i += 64) {
    int nn = i >> 5, d = i & 31;
    Es[nn * ST + d] = b2f(E[((size_t)(b * T + t) * N + nn) * D + d]);
  }
  __syncthreads();

  {
    const float* wqg = WsC + (0 * T + t) * D * D;
    const float* wkg = WsC + (1 * T + t) * D * D;
    float wq[D], wk[D];
#pragma unroll
    for (int d = 0; d < D; ++d) { wq[d] = wqg[d * D + e]; wk[d] = wkg[d * D + e]; }
    float bqv = bsC[(0 * T + t) * D + e];
    float bkv = bsC[(1 * T + t) * D + e];
#pragma unroll
    for (int k = 0; k < N * D / 64; ++k) {
      int nn = (tid + k * 64) >> 5;
      float aq = bqv, ak = bkv;
#pragma unroll
      for (int d = 0; d < D; ++d) {
        float x = Es[nn * ST + d];
        aq += x * wq[d];
        ak += x * wk[d];
      }
      Os[nn * ST + e] = aq;
      Ks[nn * ST + e] = ak;
    }
  }
  {
    const float* wvg = WsC + (2 * T + t) * D * D;
    float wv[D];
#pragma unroll
    for (int d = 0; d < D; ++d) wv[d] = wvg[d * D + e];
    float bvv = bsC[(2 * T + t) * D + e];
#pragma unroll
    for (int k = 0; k < N * D / 64; ++k) {
      int nn = (tid + k * 64) >> 5;
      float av = bvv;
#pragma unroll
      for (int d = 0; d < D; ++d) av += Es[nn * ST + d] * wv[d];
      Vs[nn * ST + e] = av;
    }
  }
  __syncthreads();

  if (tid < N * NH) {
    int nn = tid >> 1, h = tid & 1;
    int ho = h * FD;
    float q[FD];
#pragma unroll
    for (int f = 0; f < FD; ++f) q[f] = Os[nn * ST + ho + f];
    float sc[N];
    float m = -1e30f;
#pragma unroll
    for (int k = 0; k < N; ++k) {
      float s = 0.f;
#pragma unroll
      for (int f = 0; f < FD; ++f) s += q[f] * Ks[k * ST + ho + f];
      s *= SCALE;
      sc[k] = s;
      m = fmaxf(m, s);
    }
    float l = 0.f;
#pragma unroll
    for (int k = 0; k < N; ++k) { sc[k] = __expf(sc[k] - m); l += sc[k]; }
    float rl = 1.f / l;
#pragma unroll
    for (int f = 0; f < FD; ++f) {
      float a = 0.f;
#pragma unroll
      for (int k = 0; k < N; ++k) a += sc[k] * Vs[k * ST + ho + f];
      Os[nn * ST + ho + f] = a * rl;
    }
  }
  __syncthreads();

  {
    const float* wog = sm_Wo + t * D * D;
    float wo[D];
#pragma unroll
    for (int d = 0; d < D; ++d) wo[d] = wog[d * D + e];
    float bov = sm_bo[t * D + e];
#pragma unroll
    for (int k = 0; k < N * D / 64; ++k) {
      int nn = (tid + k * 64) >> 5;
      float a = bov;
#pragma unroll
      for (int d = 0; d < D; ++d) a += Os[nn * ST + d] * wo[d];
      Ks[nn * ST + e] = a + Es[nn * ST + e];
    }
  }
  __syncthreads();

  if (tid < N) {
    int nn = tid;
    float mu = 0.f;
#pragma unroll
    for (int d = 0; d < D; ++d) mu += Ks[nn * ST + d];
    mu *= (1.f / D);
    float var = 0.f;
#pragma unroll
    for (int d = 0; d < D; ++d) { float c = Ks[nn * ST + d] - mu; var += c * c; }
    var *= (1.f / D);
    float r = rsqrtf(var + 1e-5f);
#pragma unroll
    for (int d = 0; d < D; ++d)
      Sn[((size_t)(b * T + t) * N + nn) * D + d] =
          __float2bfloat16((Ks[nn * ST + d] - mu) * r * ln_g[d] + ln_b[d]);
  }
}

// ---------------------------------------------------------------------------
// ts = Tn + Sn; ff = relu(ts@W1+b1)@W2+b2; E = LN(ff + ts).  Row per thread.
// ---------------------------------------------------------------------------
__global__ __launch_bounds__(256) void ff_kernel(
    const bf16* __restrict__ Tn, const bf16* __restrict__ Sn,
    const float* __restrict__ W1, const float* __restrict__ b1,
    const float* __restrict__ W2, const float* __restrict__ b2,
    const float* __restrict__ ln_g, const float* __restrict__ ln_b,
    bf16* __restrict__ E) {
  __shared__ float w1[D * FF], w2[FF * D], bb1[FF], bb2[D], g[D], bbn[D];
  int tid = threadIdx.x;
  for (int i = tid; i < D * FF; i += 256) { w1[i] = W1[i]; w2[i] = W2[i]; }
  if (tid < FF) bb1[tid] = b1[tid];
  if (tid < D) { bb2[tid] = b2[tid]; g[tid] = ln_g[tid]; bbn[tid] = ln_b[tid]; }
  __syncthreads();
  int row = blockIdx.x * 256 + tid;
  if (row >= B * T * N) return;
  float ts[D];
#pragma unroll
  for (int d = 0; d < D; ++d)
    ts[d] = b2f(Tn[(size_t)row * D + d]) + b2f(Sn[(size_t)row * D + d]);
  float x[D];
#pragma unroll
  for (int d = 0; d < D; ++d) x[d] = bb2[d] + ts[d];
#pragma unroll 1
  for (int c = 0; c < 2; ++c) {
    float hh[32];
#pragma unroll
    for (int j = 0; j < 32; ++j) {
      int jj = c * 32 + j;
      float a = bb1[jj];
#pragma unroll
      for (int d = 0; d < D; ++d) a += ts[d] * w1[d * FF + jj];
      hh[j] = fmaxf(a, 0.f);
    }
#pragma unroll
    for (int e2 = 0; e2 < D; ++e2) {
      float a = 0.f;
#pragma unroll
      for (int j = 0; j < 32; ++j) a += hh[j] * w2[(c * 32 + j) * D + e2];
      x[e2] += a;
    }
  }
  float mu = 0.f;
#pragma unroll
  for (int e2 = 0; e2 < D; ++e2) mu += x[e2];
  mu *= (1.f / D);
  float var = 0.f;
#pragma unroll
  for (int e2 = 0; e2 < D; ++e2) { float c = x[e2] - mu; var += c * c; }
  var *= (1.f / D);
  float r = rsqrtf(var + 1e-5f);
#pragma unroll
  for (int e2 = 0; e2 < D; ++e2)
    E[(size_t)row * D + e2] = __float2bfloat16((x[e2] - mu) * r * g[e2] + bbn[e2]);
}

// ---------------------------------------------------------------------------
// out = E@op_W + op_b + X   (f32 out)
// ---------------------------------------------------------------------------
__global__ __launch_bounds__(256) void out_kernel(
    const bf16* __restrict__ E, const float* __restrict__ op_W,
    const float* __restrict__ op_b, const float* __restrict__ X,
    float* __restrict__ out) {
  int idx = blockIdx.x * 256 + threadIdx.x;
  if (idx >= B * T * N * M) return;
  int m  = idx % M;
  int n  = (idx / M) % N;
  int bt = idx / (M * N);
  float acc = op_b[n * M + m];
  const bf16* e = E + ((size_t)bt * N + n) * D;
#pragma unroll
  for (int d = 0; d < D; ++d) acc += b2f(e[d]) * op_W[(n * D + d) * M + m];
  acc += X[idx];
  out[idx] = acc;
}

// ---------------------------------------------------------------------------
extern "C" void kernel_launch(void* const* d_in, const int* in_sizes, int n_in,
                              void* d_out, int out_size, void* d_ws, size_t ws_size,
                              hipStream_t stream) {
  const float* X     = (const float*)d_in[0];
  const float* pe    = (const float*)d_in[1];
  const float* E_W   = (const float*)d_in[2];
  const float* E_b   = (const float*)d_in[3];
  const float* tq_W  = (const float*)d_in[4];
  const float* tq_b  = (const float*)d_in[5];
  const float* tk_W  = (const float*)d_in[6];
  const float* tk_b  = (const float*)d_in[7];
  const float* tv_W  = (const float*)d_in[8];
  const float* tv_b  = (const float*)d_in[9];
  const float* tm_Wq = (const float*)d_in[10];
  const float* tm_bq = (const float*)d_in[11];
  const float* tm_Wk = (const float*)d_in[12];
  const float* tm_bk = (const float*)d_in[13];
  const float* tm_Wv = (const float*)d_in[14];
  const float* tm_bv = (const float*)d_in[15];
  const float* tm_Wo = (const float*)d_in[16];
  const float* tm_bo = (const float*)d_in[17];
  const float* sq_W  = (const float*)d_in[18];
  const float* sq_b  = (const float*)d_in[19];
  const float* sk_W  = (const float*)d_in[20];
  const float* sk_b  = (const float*)d_in[21];
  const float* sv_W  = (const float*)d_in[22];
  const float* sv_b  = (const float*)d_in[23];
  const float* sm_Wq = (const float*)d_in[24];
  const float* sm_bq = (const float*)d_in[25];
  const float* sm_Wk = (const float*)d_in[26];
  const float* sm_bk = (const float*)d_in[27];
  const float* sm_Wv = (const float*)d_in[28];
  const float* sm_bv = (const float*)d_in[29];
  const float* sm_Wo = (const float*)d_in[30];
  const float* sm_bo = (const float*)d_in[31];
  const float* ff1_W = (const float*)d_in[32];
  const float* ff1_b = (const float*)d_in[33];
  const float* ff2_W = (const float*)d_in[34];
  const float* ff2_b = (const float*)d_in[35];
  const float* ln_g  = (const float*)d_in[36];
  const float* ln_b  = (const float*)d_in[37];
  const float* op_W  = (const float*)d_in[38];
  const float* op_b  = (const float*)d_in[39];
  float* out = (float*)d_out;

  // ws layout: composed weights (f32), then bf16 activations.
  // Sn aliases Qt (Qt dead after attnt; spatial writes it before ff reads).
  float* WtC = (float*)d_ws;                         // 3*N*D*D
  float* btC = WtC + 3 * N * D * D;                  // 3*N*D
  float* WsC = btC + 3 * N * D;                      // 3*T*D*D
  float* bsC = WsC + 3 * T * D * D;                  // 3*T*D
  size_t act = (size_t)B * T * N * D;
  bf16* Ebuf = (bf16*)(bsC + 3 * T * D);
  bf16* Tn   = Ebuf + act;
  bf16* Qt   = Tn + act;
  bf16* Kt   = Qt + act;
  bf16* Vt   = Kt + act;
  bf16* Sn   = Qt;                                   // alias
  // total ~60.8 MB

  compose3_kernel<<<3 * N, 256, 0, stream>>>(
      tq_W, tq_b, tm_Wq, tm_bq, tk_W, tk_b, tm_Wk, tm_bk,
      tv_W, tv_b, tm_Wv, tm_bv, WtC, btC, N);
  compose3_kernel<<<3 * T, 256, 0, stream>>>(
      sq_W, sq_b, sm_Wq, sm_bq, sk_W, sk_b, sm_Wk, sm_bk,
      sv_W, sv_b, sm_Wv, sm_bv, WsC, bsC, T);

  embed_kernel<<<(B * T * N * D) / 256, 256, 0, stream>>>(X, pe, E_W, E_b, Ebuf);

  for (int l = 0; l < L; ++l) {
    qkvt_kernel<<<N * RCH, 256, 0, stream>>>(Ebuf, WtC, btC, Qt, Kt, Vt);
    attnt_kernel<<<B * N * 4, 256, 0, stream>>>(Qt, Kt, Vt, Ebuf, tm_Wo, tm_bo, ln_g, ln_b, Tn);
    spatial_kernel<<<B * T, 64, 0, stream>>>(Ebuf, WsC, bsC, sm_Wo, sm_bo, ln_g, ln_b, Sn);
    ff_kernel<<<(B * T * N + 255) / 256, 256, 0, stream>>>(Tn, Sn, ff1_W, ff1_b, ff2_W, ff2_b, ln_g, ln_b, Ebuf);
  }

  out_kernel<<<(B * T * N * M + 255) / 256, 256, 0, stream>>>(Ebuf, op_W, op_b, X, out);
}

// Round 12
// 1202.744 us; speedup vs baseline: 2.9058x; 1.0833x over previous
//
#include <hip/hip_runtime.h>
#include <hip/hip_bf16.h>

typedef __hip_bfloat16 bf16;

constexpr int B  = 64, T = 120, N = 24, M = 3, D = 32;
constexpr int NH = 2, FD = 16, FF = 64, L = 3;
constexpr float SCALE = 0.25f;   // 1/sqrt(FD)
constexpr int SK  = 40;          // attnt Q/V LDS stride (bf16, 80B rows)
constexpr int SKF = 36;          // attnt K/O LDS stride (f32, 144B rows)
constexpr int SS  = 124;         // attnt score row stride (bf16)
constexpr int CH2 = 30;          // attnt rows per chunk: 4 x 30 = 120 exactly
constexpr int RCH = 30;          // qkvt row chunks: 7680/256
constexpr int BG  = 2;           // spatial batches per block
constexpr int SR  = N * BG;      // spatial rows per block = 48
constexpr int SES = 40;          // spatial Es bf16 stride (80B, 16B-aligned)
constexpr int SQS = 32;          // spatial Q/K/V f32 stride

__device__ __forceinline__ float b2f(bf16 x) { return __bfloat162float(x); }
__device__ __forceinline__ float blo(unsigned u) { return __uint_as_float(u << 16); }
__device__ __forceinline__ float bhi(unsigned u) { return __uint_as_float(u & 0xffff0000u); }
__device__ __forceinline__ unsigned pk2(float a, float b) {
  bf16 x = __float2bfloat16(a), y = __float2bfloat16(b);
  unsigned short ux = *reinterpret_cast<unsigned short*>(&x);
  unsigned short uy = *reinterpret_cast<unsigned short*>(&y);
  return (unsigned)ux | ((unsigned)uy << 16);
}

// ---------------------------------------------------------------------------
// Compose q/k/v chained linears: grid = 3*U blocks.  Wc = W1@W2, bc = b1@W2+b2.
// ---------------------------------------------------------------------------
__global__ __launch_bounds__(256) void compose3_kernel(
    const float* __restrict__ W1q, const float* __restrict__ b1q,
    const float* __restrict__ W2q, const float* __restrict__ b2q,
    const float* __restrict__ W1k, const float* __restrict__ b1k,
    const float* __restrict__ W2k, const float* __restrict__ b2k,
    const float* __restrict__ W1v, const float* __restrict__ b1v,
    const float* __restrict__ W2v, const float* __restrict__ b2v,
    float* __restrict__ Wc, float* __restrict__ bc, int U) {
  int fam = blockIdx.x / U;
  int n   = blockIdx.x % U;
  const float* W1 = (fam == 0) ? W1q : (fam == 1) ? W1k : W1v;
  const float* b1 = (fam == 0) ? b1q : (fam == 1) ? b1k : b1v;
  const float* W2 = (fam == 0) ? W2q : (fam == 1) ? W2k : W2v;
  const float* b2 = (fam == 0) ? b2q : (fam == 1) ? b2k : b2v;
  const float* w1 = W1 + n * D * D;
  const float* w2 = W2 + n * D * D;
  float* wc  = Wc + (size_t)(fam * U + n) * D * D;
  float* bcp = bc + (fam * U + n) * D;
  __shared__ float s1[D * D], s2[D * D];
  for (int i = threadIdx.x; i < D * D; i += 256) { s1[i] = w1[i]; s2[i] = w2[i]; }
  __syncthreads();
  for (int i = threadIdx.x; i < D * D; i += 256) {
    int d = i >> 5, f = i & 31;
    float acc = 0.f;
#pragma unroll
    for (int e = 0; e < D; ++e) acc += s1[d * D + e] * s2[e * D + f];
    wc[i] = acc;
  }
  if (threadIdx.x < D) {
    int f = threadIdx.x;
    float acc = b2[n * D + f];
#pragma unroll
    for (int e = 0; e < D; ++e) acc += b1[n * D + e] * s2[e * D + f];
    bcp[f] = acc;
  }
}

// ---------------------------------------------------------------------------
// E[b,t,n,d] = X@E_W + E_b + pe   (bf16 out)
// ---------------------------------------------------------------------------
__global__ __launch_bounds__(256) void embed_kernel(
    const float* __restrict__ X, const float* __restrict__ pe,
    const float* __restrict__ E_W, const float* __restrict__ E_b,
    bf16* __restrict__ E) {
  int idx = blockIdx.x * 256 + threadIdx.x;
  if (idx >= B * T * N * D) return;
  int d = idx & 31;
  int n = (idx >> 5) % N;
  int bt = idx / (D * N);
  int t = bt % T;
  const float* x = X + bt * (N * M) + n * M;
  float acc = E_b[n * D + d] + pe[t * D + d];
#pragma unroll
  for (int m = 0; m < M; ++m) acc += x[m] * E_W[(n * M + m) * D + d];
  E[idx] = __float2bfloat16(acc);
}

// ---------------------------------------------------------------------------
// qkvt: composed Q/K/V projections for the temporal path.
// Weights in LDS.  Writes Qt/Kt/Vt[b][n][t][32] bf16 (t-contiguous).
// ---------------------------------------------------------------------------
__global__ __launch_bounds__(256) void qkvt_kernel(
    const bf16* __restrict__ E, const float* __restrict__ WtC,
    const float* __restrict__ btC,
    bf16* __restrict__ Qt, bf16* __restrict__ Kt, bf16* __restrict__ Vt) {
  int n     = blockIdx.x / RCH;
  int chunk = blockIdx.x % RCH;
  __shared__ float wsh[3 * D * D];
  __shared__ float bsh[3 * D];
  int tid = threadIdx.x;
  for (int i = tid; i < 3 * D * D; i += 256) {
    int fam = i >> 10, idx = i & 1023;
    wsh[i] = WtC[(size_t)(fam * N + n) * D * D + idx];
  }
  if (tid < 3 * D) {
    int fam = tid >> 5, e = tid & 31;
    bsh[tid] = btC[(fam * N + n) * D + e];
  }
  __syncthreads();

  int row = chunk * 256 + tid;          // (b*T + t)
  int b = row / T, t = row % T;
  const bf16* er = E + ((size_t)row * N + n) * D;
  float x[D];
#pragma unroll
  for (int p = 0; p < 4; ++p) {
    uint4 u = *(const uint4*)&er[p * 8];
    x[p*8+0] = blo(u.x); x[p*8+1] = bhi(u.x);
    x[p*8+2] = blo(u.y); x[p*8+3] = bhi(u.y);
    x[p*8+4] = blo(u.z); x[p*8+5] = bhi(u.z);
    x[p*8+6] = blo(u.w); x[p*8+7] = bhi(u.w);
  }
  size_t dsto = (((size_t)b * N + n) * T + t) * D;
  bf16* dsts[3] = { Qt + dsto, Kt + dsto, Vt + dsto };
#pragma unroll
  for (int fam = 0; fam < 3; ++fam) {
    const float* w  = wsh + fam * D * D;
    const float* bi = bsh + fam * D;
    bf16* dst = dsts[fam];
#pragma unroll
    for (int g = 0; g < 4; ++g) {
      float a[8];
#pragma unroll
      for (int j = 0; j < 8; ++j) a[j] = bi[g * 8 + j];
#pragma unroll
      for (int d = 0; d < D; ++d) {
        float xv = x[d];
#pragma unroll
        for (int j = 0; j < 8; ++j) a[j] += xv * w[d * D + g * 8 + j];
      }
      uint4 o;
      o.x = pk2(a[0], a[1]); o.y = pk2(a[2], a[3]);
      o.z = pk2(a[4], a[5]); o.w = pk2(a[6], a[7]);
      *(uint4*)&dst[g * 8] = o;
    }
  }
}

// ---------------------------------------------------------------------------
// attnt v3: R11's ILP structure with LDS trimmed back to 3 blocks/CU:
// K f32 (unpack off the serial score chain), V/Q bf16 (unpacks hide in the
// 4-way-independent PV chains), O f32.  Total 52.9 KB <= 54.6 KB.
// ---------------------------------------------------------------------------
__global__ __launch_bounds__(256) void attnt_kernel(
    const bf16* __restrict__ Qt, const bf16* __restrict__ Kt,
    const bf16* __restrict__ Vt, const bf16* __restrict__ E,
    const float* __restrict__ tm_Wo, const float* __restrict__ tm_bo,
    const float* __restrict__ ln_g, const float* __restrict__ ln_b,
    bf16* __restrict__ Tn) {
  int c  = blockIdx.x & 3;
  int bn = blockIdx.x >> 2;
  int n  = bn % N, b = bn / N;
  int nk = CH2 * (c + 1);               // keys staged: 30/60/90/120
  __shared__ __align__(16) float Kl[T * SKF];
  __shared__ __align__(16) bf16  Vl[T * SK];
  __shared__ __align__(16) bf16  Ql[CH2 * SK];
  __shared__ __align__(16) float Ol[CH2 * SKF];
  __shared__ __align__(16) bf16  Sc[2 * CH2 * SS];
  __shared__ float Wol[D * D], bol[D], gl[D], bbl[D];
  int tid = threadIdx.x;

  const bf16* Kg = Kt + (size_t)bn * T * D;
  const bf16* Vg = Vt + (size_t)bn * T * D;
  const bf16* Qg = Qt + ((size_t)bn * T + CH2 * c) * D;
  for (int i = tid; i < nk * 4; i += 256) {
    int r = i >> 2, p = i & 3;
    uint4 ku = *(const uint4*)&Kg[r * D + p * 8];
    *(float4*)&Kl[r * SKF + p * 8]     = make_float4(blo(ku.x), bhi(ku.x), blo(ku.y), bhi(ku.y));
    *(float4*)&Kl[r * SKF + p * 8 + 4] = make_float4(blo(ku.z), bhi(ku.z), blo(ku.w), bhi(ku.w));
    *(uint4*)&Vl[r * SK + p * 8]       = *(const uint4*)&Vg[r * D + p * 8];
  }
  if (tid < CH2 * 4) {
    int r = tid >> 2, p = tid & 3;
    *(uint4*)&Ql[r * SK + p * 8] = *(const uint4*)&Qg[r * D + p * 8];
  }
  for (int i = tid; i < D * D; i += 256) Wol[i] = tm_Wo[(size_t)n * D * D + i];
  if (tid < D) {
    bol[tid] = tm_bo[n * D + tid];
    gl[tid]  = ln_g[tid];
    bbl[tid] = ln_b[tid];
  }
  __syncthreads();

  // ---- scores + softmax + PV: task = (row, head), 4 lanes per task ----
  {
    int task = tid >> 2, sl = tid & 3;
    if (task < 2 * CH2) {
      int rl = task >> 1, h = task & 1, ho = h * FD;
      int rg = CH2 * c + rl, kend = rg + 1;
      uint4 q0 = *(const uint4*)&Ql[rl * SK + ho];
      uint4 q1 = *(const uint4*)&Ql[rl * SK + ho + 8];
      float qf[16];
      qf[0]  = blo(q0.x); qf[1]  = bhi(q0.x); qf[2]  = blo(q0.y); qf[3]  = bhi(q0.y);
      qf[4]  = blo(q0.z); qf[5]  = bhi(q0.z); qf[6]  = blo(q0.w); qf[7]  = bhi(q0.w);
      qf[8]  = blo(q1.x); qf[9]  = bhi(q1.x); qf[10] = blo(q1.y); qf[11] = bhi(q1.y);
      qf[12] = blo(q1.z); qf[13] = bhi(q1.z); qf[14] = blo(q1.w); qf[15] = bhi(q1.w);
      bf16* srow = &Sc[task * SS];
      float mx = -3e38f;
#pragma unroll 1
      for (int k = sl; k < kend; k += 4) {
        const float4 k0 = *(const float4*)&Kl[k * SKF + ho];
        const float4 k1 = *(const float4*)&Kl[k * SKF + ho + 4];
        const float4 k2 = *(const float4*)&Kl[k * SKF + ho + 8];
        const float4 k3 = *(const float4*)&Kl[k * SKF + ho + 12];
        float s0 = qf[0]*k0.x  + qf[1]*k0.y  + qf[2]*k0.z  + qf[3]*k0.w;
        float s1 = qf[4]*k1.x  + qf[5]*k1.y  + qf[6]*k1.z  + qf[7]*k1.w;
        float s2 = qf[8]*k2.x  + qf[9]*k2.y  + qf[10]*k2.z + qf[11]*k2.w;
        float s3 = qf[12]*k3.x + qf[13]*k3.y + qf[14]*k3.z + qf[15]*k3.w;
        float s = ((s0 + s1) + (s2 + s3)) * SCALE;
        srow[k] = __float2bfloat16(s);
        mx = fmaxf(mx, s);
      }
      mx = fmaxf(mx, __shfl_xor(mx, 1, 64));
      mx = fmaxf(mx, __shfl_xor(mx, 2, 64));
      float l = 0.f;
#pragma unroll 1
      for (int k = sl; k < kend; k += 4) {
        float p = __expf(b2f(srow[k]) - mx);
        srow[k] = __float2bfloat16(p);
        l += p;
      }
      l += __shfl_xor(l, 1, 64);
      l += __shfl_xor(l, 2, 64);
      float rli = 1.f / l;
      int fo = ho + sl * 4;
      float4 acc0 = make_float4(0.f, 0.f, 0.f, 0.f);
      float4 acc1 = make_float4(0.f, 0.f, 0.f, 0.f);
      float4 acc2 = make_float4(0.f, 0.f, 0.f, 0.f);
      float4 acc3 = make_float4(0.f, 0.f, 0.f, 0.f);
      int k4 = kend & ~3;
#pragma unroll 1
      for (int k = 0; k < k4; k += 4) {
        uint2 pu = *(const uint2*)&srow[k];   // 4 bf16 p
        float p0 = blo(pu.x), p1 = bhi(pu.x), p2 = blo(pu.y), p3 = bhi(pu.y);
        uint2 v0u = *(const uint2*)&Vl[(k + 0) * SK + fo];
        uint2 v1u = *(const uint2*)&Vl[(k + 1) * SK + fo];
        uint2 v2u = *(const uint2*)&Vl[(k + 2) * SK + fo];
        uint2 v3u = *(const uint2*)&Vl[(k + 3) * SK + fo];
        acc0.x += p0*blo(v0u.x); acc0.y += p0*bhi(v0u.x);
        acc0.z += p0*blo(v0u.y); acc0.w += p0*bhi(v0u.y);
        acc1.x += p1*blo(v1u.x); acc1.y += p1*bhi(v1u.x);
        acc1.z += p1*blo(v1u.y); acc1.w += p1*bhi(v1u.y);
        acc2.x += p2*blo(v2u.x); acc2.y += p2*bhi(v2u.x);
        acc2.z += p2*blo(v2u.y); acc2.w += p2*bhi(v2u.y);
        acc3.x += p3*blo(v3u.x); acc3.y += p3*bhi(v3u.x);
        acc3.z += p3*blo(v3u.y); acc3.w += p3*bhi(v3u.y);
      }
#pragma unroll 1
      for (int k = k4; k < kend; ++k) {
        float p = b2f(srow[k]);
        uint2 vu = *(const uint2*)&Vl[k * SK + fo];
        acc0.x += p*blo(vu.x); acc0.y += p*bhi(vu.x);
        acc0.z += p*blo(vu.y); acc0.w += p*bhi(vu.y);
      }
      float4 o;
      o.x = ((acc0.x + acc1.x) + (acc2.x + acc3.x)) * rli;
      o.y = ((acc0.y + acc1.y) + (acc2.y + acc3.y)) * rli;
      o.z = ((acc0.z + acc1.z) + (acc2.z + acc3.z)) * rli;
      o.w = ((acc0.w + acc1.w) + (acc2.w + acc3.w)) * rli;
      *(float4*)&Ol[rl * SKF + fo] = o;
    }
  }
  __syncthreads();

  // ---- O-proj + residual + LN: thread = (row, e-quad), 8 lanes per row ----
  {
    int rl = tid >> 3, q = tid & 7, e0 = q * 4;
    if (rl < CH2) {
      int rg = CH2 * c + rl;
      size_t rowo = ((size_t)(b * T + rg) * N + n) * D;
      uint2 eu = *(const uint2*)&E[rowo + e0];
      float res[4] = { blo(eu.x), bhi(eu.x), blo(eu.y), bhi(eu.y) };
      float o[4], s1 = 0.f, s2 = 0.f;
#pragma unroll
      for (int j = 0; j < 4; ++j) {
        int e = e0 + j;
        float aa = 0.f, ab = 0.f;
#pragma unroll
        for (int d = 0; d < D; d += 2) {
          aa += Ol[rl * SKF + d]     * Wol[d * D + e];
          ab += Ol[rl * SKF + d + 1] * Wol[(d + 1) * D + e];
        }
        float a = bol[e] + aa + ab + res[j];
        o[j] = a; s1 += a; s2 += a * a;
      }
      s1 += __shfl_xor(s1, 1, 64); s2 += __shfl_xor(s2, 1, 64);
      s1 += __shfl_xor(s1, 2, 64); s2 += __shfl_xor(s2, 2, 64);
      s1 += __shfl_xor(s1, 4, 64); s2 += __shfl_xor(s2, 4, 64);
      float mu  = s1 * (1.f / D);
      float var = s2 * (1.f / D) - mu * mu;
      float r = rsqrtf(var + 1e-5f);
      uint2 ou;
      ou.x = pk2((o[0]-mu)*r*gl[e0]+bbl[e0],    (o[1]-mu)*r*gl[e0+1]+bbl[e0+1]);
      ou.y = pk2((o[2]-mu)*r*gl[e0+2]+bbl[e0+2],(o[3]-mu)*r*gl[e0+3]+bbl[e0+3]);
      *(uint2*)&Tn[rowo + e0] = ou;
    }
  }
}

// ---------------------------------------------------------------------------
// spatial v2: block = (t, 2 batches), 256 threads.  All 4 weight mats in LDS
// (16 KB, L2-shared across the 32 same-t blocks).  Gemv thread=(row,e);
// attention task-per-thread (N=24 keys, registers); O-proj+LN via 32-lane
// shfl row-reduce.  LDS ~39.4 KB -> 4 blocks/CU.
// ---------------------------------------------------------------------------
__global__ __launch_bounds__(256) void spatial_kernel(
    const bf16* __restrict__ E, const float* __restrict__ WsC,
    const float* __restrict__ bsC, const float* __restrict__ sm_Wo,
    const float* __restrict__ sm_bo, const float* __restrict__ ln_g,
    const float* __restrict__ ln_b, bf16* __restrict__ Sn) {
  int t  = blockIdx.x >> 5;          // B/BG = 32 groups per t
  int bg = blockIdx.x & 31;
  int b0 = bg * BG;
  __shared__ float Wq[D * D], Wk[D * D], Wv[D * D], Wo[D * D];
  __shared__ float bqs[D], bks[D], bvs[D], bos[D], gs[D], bbs[D];
  __shared__ __align__(16) bf16  Es[SR * SES];
  __shared__ float Qs[SR * SQS], Ks[SR * SQS], Vs[SR * SQS];
  int tid = threadIdx.x;

  for (int i = tid; i < D * D; i += 256) {
    Wq[i] = WsC[(size_t)(0 * T + t) * D * D + i];
    Wk[i] = WsC[(size_t)(1 * T + t) * D * D + i];
    Wv[i] = WsC[(size_t)(2 * T + t) * D * D + i];
    Wo[i] = sm_Wo[(size_t)t * D * D + i];
  }
  if (tid < D) {
    bqs[tid] = bsC[(0 * T + t) * D + tid];
    bks[tid] = bsC[(1 * T + t) * D + tid];
    bvs[tid] = bsC[(2 * T + t) * D + tid];
    bos[tid] = sm_bo[t * D + tid];
    gs[tid]  = ln_g[tid];
    bbs[tid] = ln_b[tid];
  }
  if (tid < SR * 4) {
    int r = tid >> 2, p = tid & 3;
    int b = b0 + r / N, n = r % N;
    *(uint4*)&Es[r * SES + p * 8] =
        *(const uint4*)&E[(((size_t)b * T + t) * N + n) * D + p * 8];
  }
  __syncthreads();

  // ---- QKV gemv: thread = (row, e), 6 iterations ----
#pragma unroll 1
  for (int i = tid; i < SR * D; i += 256) {
    int r = i >> 5, e = i & 31;
    float aq = bqs[e], ak = bks[e], av = bvs[e];
#pragma unroll
    for (int d = 0; d < D; ++d) {
      float x = b2f(Es[r * SES + d]);
      aq += x * Wq[d * D + e];
      ak += x * Wk[d * D + e];
      av += x * Wv[d * D + e];
    }
    Qs[r * SQS + e] = aq;
    Ks[r * SQS + e] = ak;
    Vs[r * SQS + e] = av;
  }
  __syncthreads();

  // ---- attention: task = (row, head) per thread; O overwrites Q slots ----
  if (tid < SR * NH) {
    int r = tid >> 1, h = tid & 1, ho = h * FD;
    int kb = (r >= N) ? N : 0;       // key-row base of this row's batch
    float q[FD];
#pragma unroll
    for (int f = 0; f < FD; ++f) q[f] = Qs[r * SQS + ho + f];
    float sc[N];
    float m = -1e30f;
#pragma unroll
    for (int k = 0; k < N; ++k) {
      float sa = 0.f, sb = 0.f;
#pragma unroll
      for (int f = 0; f < FD; f += 2) {
        sa += q[f]     * Ks[(kb + k) * SQS + ho + f];
        sb += q[f + 1] * Ks[(kb + k) * SQS + ho + f + 1];
      }
      float s = (sa + sb) * SCALE;
      sc[k] = s;
      m = fmaxf(m, s);
    }
    float l = 0.f;
#pragma unroll
    for (int k = 0; k < N; ++k) { sc[k] = __expf(sc[k] - m); l += sc[k]; }
    float rl = 1.f / l;
#pragma unroll
    for (int f = 0; f < FD; ++f) {
      float a = 0.f;
#pragma unroll
      for (int k = 0; k < N; ++k) a += sc[k] * Vs[(kb + k) * SQS + ho + f];
      Qs[r * SQS + ho + f] = a * rl;
    }
  }
  __syncthreads();

  // ---- O-proj + residual + LN: thread = (row, e); shfl row-reduce ----
#pragma unroll 1
  for (int it = 0; it < SR * D / 256; ++it) {
    int i = it * 256 + tid;
    int r = i >> 5, e = i & 31;
    float aa = 0.f, ab = 0.f;
#pragma unroll
    for (int d = 0; d < D; d += 2) {
      aa += Qs[r * SQS + d]     * Wo[d * D + e];
      ab += Qs[r * SQS + d + 1] * Wo[(d + 1) * D + e];
    }
    float o = bos[e] + aa + ab + b2f(Es[r * SES + e]);
    float s1 = o, s2 = o * o;
    s1 += __shfl_xor(s1, 1, 64);  s2 += __shfl_xor(s2, 1, 64);
    s1 += __shfl_xor(s1, 2, 64);  s2 += __shfl_xor(s2, 2, 64);
    s1 += __shfl_xor(s1, 4, 64);  s2 += __shfl_xor(s2, 4, 64);
    s1 += __shfl_xor(s1, 8, 64);  s2 += __shfl_xor(s2, 8, 64);
    s1 += __shfl_xor(s1, 16, 64); s2 += __shfl_xor(s2, 16, 64);
    float mu  = s1 * (1.f / D);
    float var = s2 * (1.f / D) - mu * mu;
    float rr = rsqrtf(var + 1e-5f);
    int b = b0 + r / N, n = r % N;
    Sn[(((size_t)b * T + t) * N + n) * D + e] =
        __float2bfloat16((o - mu) * rr * gs[e] + bbs[e]);
  }
}

// ---------------------------------------------------------------------------
// ts = Tn + Sn; ff = relu(ts@W1+b1)@W2+b2; E = LN(ff + ts).  Row per thread.
// ---------------------------------------------------------------------------
__global__ __launch_bounds__(256) void ff_kernel(
    const bf16* __restrict__ Tn, const bf16* __restrict__ Sn,
    const float* __restrict__ W1, const float* __restrict__ b1,
    const float* __restrict__ W2, const float* __restrict__ b2,
    const float* __restrict__ ln_g, const float* __restrict__ ln_b,
    bf16* __restrict__ E) {
  __shared__ float w1[D * FF], w2[FF * D], bb1[FF], bb2[D], g[D], bbn[D];
  int tid = threadIdx.x;
  for (int i = tid; i < D * FF; i += 256) { w1[i] = W1[i]; w2[i] = W2[i]; }
  if (tid < FF) bb1[tid] = b1[tid];
  if (tid < D) { bb2[tid] = b2[tid]; g[tid] = ln_g[tid]; bbn[tid] = ln_b[tid]; }
  __syncthreads();
  int row = blockIdx.x * 256 + tid;
  if (row >= B * T * N) return;
  float ts[D];
#pragma unroll
  for (int d = 0; d < D; ++d)
    ts[d] = b2f(Tn[(size_t)row * D + d]) + b2f(Sn[(size_t)row * D + d]);
  float x[D];
#pragma unroll
  for (int d = 0; d < D; ++d) x[d] = bb2[d] + ts[d];
#pragma unroll 1
  for (int c = 0; c < 2; ++c) {
    float hh[32];
#pragma unroll
    for (int j = 0; j < 32; ++j) {
      int jj = c * 32 + j;
      float a = bb1[jj];
#pragma unroll
      for (int d = 0; d < D; ++d) a += ts[d] * w1[d * FF + jj];
      hh[j] = fmaxf(a, 0.f);
    }
#pragma unroll
    for (int e2 = 0; e2 < D; ++e2) {
      float a = 0.f;
#pragma unroll
      for (int j = 0; j < 32; ++j) a += hh[j] * w2[(c * 32 + j) * D + e2];
      x[e2] += a;
    }
  }
  float mu = 0.f;
#pragma unroll
  for (int e2 = 0; e2 < D; ++e2) mu += x[e2];
  mu *= (1.f / D);
  float var = 0.f;
#pragma unroll
  for (int e2 = 0; e2 < D; ++e2) { float c = x[e2] - mu; var += c * c; }
  var *= (1.f / D);
  float r = rsqrtf(var + 1e-5f);
#pragma unroll
  for (int e2 = 0; e2 < D; ++e2)
    E[(size_t)row * D + e2] = __float2bfloat16((x[e2] - mu) * r * g[e2] + bbn[e2]);
}

// ---------------------------------------------------------------------------
// out = E@op_W + op_b + X   (f32 out)
// ---------------------------------------------------------------------------
__global__ __launch_bounds__(256) void out_kernel(
    const bf16* __restrict__ E, const float* __restrict__ op_W,
    const float* __restrict__ op_b, const float* __restrict__ X,
    float* __restrict__ out) {
  int idx = blockIdx.x * 256 + threadIdx.x;
  if (idx >= B * T * N * M) return;
  int m  = idx % M;
  int n  = (idx / M) % N;
  int bt = idx / (M * N);
  float acc = op_b[n * M + m];
  const bf16* e = E + ((size_t)bt * N + n) * D;
#pragma unroll
  for (int d = 0; d < D; ++d) acc += b2f(e[d]) * op_W[(n * D + d) * M + m];
  acc += X[idx];
  out[idx] = acc;
}

// ---------------------------------------------------------------------------
extern "C" void kernel_launch(void* const* d_in, const int* in_sizes, int n_in,
                              void* d_out, int out_size, void* d_ws, size_t ws_size,
                              hipStream_t stream) {
  const float* X     = (const float*)d_in[0];
  const float* pe    = (const float*)d_in[1];
  const float* E_W   = (const float*)d_in[2];
  const float* E_b   = (const float*)d_in[3];
  const float* tq_W  = (const float*)d_in[4];
  const float* tq_b  = (const float*)d_in[5];
  const float* tk_W  = (const float*)d_in[6];
  const float* tk_b  = (const float*)d_in[7];
  const float* tv_W  = (const float*)d_in[8];
  const float* tv_b  = (const float*)d_in[9];
  const float* tm_Wq = (const float*)d_in[10];
  const float* tm_bq = (const float*)d_in[11];
  const float* tm_Wk = (const float*)d_in[12];
  const float* tm_bk = (const float*)d_in[13];
  const float* tm_Wv = (const float*)d_in[14];
  const float* tm_bv = (const float*)d_in[15];
  const float* tm_Wo = (const float*)d_in[16];
  const float* tm_bo = (const float*)d_in[17];
  const float* sq_W  = (const float*)d_in[18];
  const float* sq_b  = (const float*)d_in[19];
  const float* sk_W  = (const float*)d_in[20];
  const float* sk_b  = (const float*)d_in[21];
  const float* sv_W  = (const float*)d_in[22];
  const float* sv_b  = (const float*)d_in[23];
  const float* sm_Wq = (const float*)d_in[24];
  const float* sm_bq = (const float*)d_in[25];
  const float* sm_Wk = (const float*)d_in[26];
  const float* sm_bk = (const float*)d_in[27];
  const float* sm_Wv = (const float*)d_in[28];
  const float* sm_bv = (const float*)d_in[29];
  const float* sm_Wo = (const float*)d_in[30];
  const float* sm_bo = (const float*)d_in[31];
  const float* ff1_W = (const float*)d_in[32];
  const float* ff1_b = (const float*)d_in[33];
  const float* ff2_W = (const float*)d_in[34];
  const float* ff2_b = (const float*)d_in[35];
  const float* ln_g  = (const float*)d_in[36];
  const float* ln_b  = (const float*)d_in[37];
  const float* op_W  = (const float*)d_in[38];
  const float* op_b  = (const float*)d_in[39];
  float* out = (float*)d_out;

  // ws layout: composed weights (f32), then bf16 activations.
  // Sn aliases Qt (Qt dead after attnt; spatial writes it before ff reads).
  float* WtC = (float*)d_ws;                         // 3*N*D*D
  float* btC = WtC + 3 * N * D * D;                  // 3*N*D
  float* WsC = btC + 3 * N * D;                      // 3*T*D*D
  float* bsC = WsC + 3 * T * D * D;                  // 3*T*D
  size_t act = (size_t)B * T * N * D;
  bf16* Ebuf = (bf16*)(bsC + 3 * T * D);
  bf16* Tn   = Ebuf + act;
  bf16* Qt   = Tn + act;
  bf16* Kt   = Qt + act;
  bf16* Vt   = Kt + act;
  bf16* Sn   = Qt;                                   // alias
  // total ~60.8 MB

  compose3_kernel<<<3 * N, 256, 0, stream>>>(
      tq_W, tq_b, tm_Wq, tm_bq, tk_W, tk_b, tm_Wk, tm_bk,
      tv_W, tv_b, tm_Wv, tm_bv, WtC, btC, N);
  compose3_kernel<<<3 * T, 256, 0, stream>>>(
      sq_W, sq_b, sm_Wq, sm_bq, sk_W, sk_b, sm_Wk, sm_bk,
      sv_W, sv_b, sm_Wv, sm_bv, WsC, bsC, T);

  embed_kernel<<<(B * T * N * D) / 256, 256, 0, stream>>>(X, pe, E_W, E_b, Ebuf);

  for (int l = 0; l < L; ++l) {
    qkvt_kernel<<<N * RCH, 256, 0, stream>>>(Ebuf, WtC, btC, Qt, Kt, Vt);
    attnt_kernel<<<B * N * 4, 256, 0, stream>>>(Qt, Kt, Vt, Ebuf, tm_Wo, tm_bo, ln_g, ln_b, Tn);
    spatial_kernel<<<T * (B / BG), 256, 0, stream>>>(Ebuf, WsC, bsC, sm_Wo, sm_bo, ln_g, ln_b, Sn);
    ff_kernel<<<(B * T * N + 255) / 256, 256, 0, stream>>>(Tn, Sn, ff1_W, ff1_b, ff2_W, ff2_b, ln_g, ln_b, Ebuf);
  }

  out_kernel<<<(B * T * N * M + 255) / 256, 256, 0, stream>>>(Ebuf, op_W, op_b, X, out);
}

// Round 13
// 1118.115 us; speedup vs baseline: 3.1257x; 1.0757x over previous
//
#include <hip/hip_runtime.h>
#include <hip/hip_bf16.h>

typedef __hip_bfloat16 bf16;

constexpr int B  = 64, T = 120, N = 24, M = 3, D = 32;
constexpr int NH = 2, FD = 16, FF = 64, L = 3;
constexpr float SCALE = 0.25f;   // 1/sqrt(FD)
constexpr int SK  = 40;          // attnt Q/V LDS stride (bf16, 80B rows)
constexpr int SKF = 36;          // attnt K/O LDS stride (f32, 144B rows)
constexpr int CH2 = 30;          // attnt rows per chunk: 4 x 30 = 120 exactly
constexpr int NJ  = 30;          // max keys per lane slice (120/4)
constexpr int RCH = 30;          // qkvt row chunks: 7680/256
constexpr int BG  = 2;           // spatial batches per block
constexpr int SR  = N * BG;      // spatial rows per block = 48
constexpr int SES = 40;          // spatial Es bf16 stride
constexpr int SQS = 32;          // spatial Q/K/V f32 stride

__device__ __forceinline__ float b2f(bf16 x) { return __bfloat162float(x); }
__device__ __forceinline__ float blo(unsigned u) { return __uint_as_float(u << 16); }
__device__ __forceinline__ float bhi(unsigned u) { return __uint_as_float(u & 0xffff0000u); }
__device__ __forceinline__ unsigned pk2(float a, float b) {
  bf16 x = __float2bfloat16(a), y = __float2bfloat16(b);
  unsigned short ux = *reinterpret_cast<unsigned short*>(&x);
  unsigned short uy = *reinterpret_cast<unsigned short*>(&y);
  return (unsigned)ux | ((unsigned)uy << 16);
}

// ---------------------------------------------------------------------------
// Compose q/k/v chained linears: grid = 3*U blocks.  Wc = W1@W2, bc = b1@W2+b2.
// ---------------------------------------------------------------------------
__global__ __launch_bounds__(256) void compose3_kernel(
    const float* __restrict__ W1q, const float* __restrict__ b1q,
    const float* __restrict__ W2q, const float* __restrict__ b2q,
    const float* __restrict__ W1k, const float* __restrict__ b1k,
    const float* __restrict__ W2k, const float* __restrict__ b2k,
    const float* __restrict__ W1v, const float* __restrict__ b1v,
    const float* __restrict__ W2v, const float* __restrict__ b2v,
    float* __restrict__ Wc, float* __restrict__ bc, int U) {
  int fam = blockIdx.x / U;
  int n   = blockIdx.x % U;
  const float* W1 = (fam == 0) ? W1q : (fam == 1) ? W1k : W1v;
  const float* b1 = (fam == 0) ? b1q : (fam == 1) ? b1k : b1v;
  const float* W2 = (fam == 0) ? W2q : (fam == 1) ? W2k : W2v;
  const float* b2 = (fam == 0) ? b2q : (fam == 1) ? b2k : b2v;
  const float* w1 = W1 + n * D * D;
  const float* w2 = W2 + n * D * D;
  float* wc  = Wc + (size_t)(fam * U + n) * D * D;
  float* bcp = bc + (fam * U + n) * D;
  __shared__ float s1[D * D], s2[D * D];
  for (int i = threadIdx.x; i < D * D; i += 256) { s1[i] = w1[i]; s2[i] = w2[i]; }
  __syncthreads();
  for (int i = threadIdx.x; i < D * D; i += 256) {
    int d = i >> 5, f = i & 31;
    float acc = 0.f;
#pragma unroll
    for (int e = 0; e < D; ++e) acc += s1[d * D + e] * s2[e * D + f];
    wc[i] = acc;
  }
  if (threadIdx.x < D) {
    int f = threadIdx.x;
    float acc = b2[n * D + f];
#pragma unroll
    for (int e = 0; e < D; ++e) acc += b1[n * D + e] * s2[e * D + f];
    bcp[f] = acc;
  }
}

// ---------------------------------------------------------------------------
// E[b,t,n,d] = X@E_W + E_b + pe   (bf16 out)
// ---------------------------------------------------------------------------
__global__ __launch_bounds__(256) void embed_kernel(
    const float* __restrict__ X, const float* __restrict__ pe,
    const float* __restrict__ E_W, const float* __restrict__ E_b,
    bf16* __restrict__ E) {
  int idx = blockIdx.x * 256 + threadIdx.x;
  if (idx >= B * T * N * D) return;
  int d = idx & 31;
  int n = (idx >> 5) % N;
  int bt = idx / (D * N);
  int t = bt % T;
  const float* x = X + bt * (N * M) + n * M;
  float acc = E_b[n * D + d] + pe[t * D + d];
#pragma unroll
  for (int m = 0; m < M; ++m) acc += x[m] * E_W[(n * M + m) * D + d];
  E[idx] = __float2bfloat16(acc);
}

// ---------------------------------------------------------------------------
// qkvt: composed Q/K/V projections for the temporal path.
// Weights in LDS.  Writes Qt/Kt/Vt[b][n][t][32] bf16 (t-contiguous).
// ---------------------------------------------------------------------------
__global__ __launch_bounds__(256) void qkvt_kernel(
    const bf16* __restrict__ E, const float* __restrict__ WtC,
    const float* __restrict__ btC,
    bf16* __restrict__ Qt, bf16* __restrict__ Kt, bf16* __restrict__ Vt) {
  int n     = blockIdx.x / RCH;
  int chunk = blockIdx.x % RCH;
  __shared__ float wsh[3 * D * D];
  __shared__ float bsh[3 * D];
  int tid = threadIdx.x;
  for (int i = tid; i < 3 * D * D; i += 256) {
    int fam = i >> 10, idx = i & 1023;
    wsh[i] = WtC[(size_t)(fam * N + n) * D * D + idx];
  }
  if (tid < 3 * D) {
    int fam = tid >> 5, e = tid & 31;
    bsh[tid] = btC[(fam * N + n) * D + e];
  }
  __syncthreads();

  int row = chunk * 256 + tid;          // (b*T + t)
  int b = row / T, t = row % T;
  const bf16* er = E + ((size_t)row * N + n) * D;
  float x[D];
#pragma unroll
  for (int p = 0; p < 4; ++p) {
    uint4 u = *(const uint4*)&er[p * 8];
    x[p*8+0] = blo(u.x); x[p*8+1] = bhi(u.x);
    x[p*8+2] = blo(u.y); x[p*8+3] = bhi(u.y);
    x[p*8+4] = blo(u.z); x[p*8+5] = bhi(u.z);
    x[p*8+6] = blo(u.w); x[p*8+7] = bhi(u.w);
  }
  size_t dsto = (((size_t)b * N + n) * T + t) * D;
  bf16* dsts[3] = { Qt + dsto, Kt + dsto, Vt + dsto };
#pragma unroll
  for (int fam = 0; fam < 3; ++fam) {
    const float* w  = wsh + fam * D * D;
    const float* bi = bsh + fam * D;
    bf16* dst = dsts[fam];
#pragma unroll
    for (int g = 0; g < 4; ++g) {
      float a[8];
#pragma unroll
      for (int j = 0; j < 8; ++j) a[j] = bi[g * 8 + j];
#pragma unroll
      for (int d = 0; d < D; ++d) {
        float xv = x[d];
#pragma unroll
        for (int j = 0; j < 8; ++j) a[j] += xv * w[d * D + g * 8 + j];
      }
      uint4 o;
      o.x = pk2(a[0], a[1]); o.y = pk2(a[2], a[3]);
      o.z = pk2(a[4], a[5]); o.w = pk2(a[6], a[7]);
      *(uint4*)&dst[g * 8] = o;
    }
  }
}

// ---------------------------------------------------------------------------
// attnt v4: scores live in REGISTERS (sc[30] per lane, compile-time indexed).
// No Sc LDS array -> 37.2 KB LDS -> 4 blocks/CU (R12's 52KB gave only 2).
// Pass1 guarded scores + shfl max; pass2 independent exps; pass3 per-lane PV
// slice into acc[16], shfl-merged.  K/V rows >= nk zero-filled (NaN-proof).
// ---------------------------------------------------------------------------
__global__ __launch_bounds__(256) void attnt_kernel(
    const bf16* __restrict__ Qt, const bf16* __restrict__ Kt,
    const bf16* __restrict__ Vt, const bf16* __restrict__ E,
    const float* __restrict__ tm_Wo, const float* __restrict__ tm_bo,
    const float* __restrict__ ln_g, const float* __restrict__ ln_b,
    bf16* __restrict__ Tn) {
  int c  = blockIdx.x & 3;
  int bn = blockIdx.x >> 2;
  int n  = bn % N, b = bn / N;
  int nk = CH2 * (c + 1);               // keys staged: 30/60/90/120
  __shared__ __align__(16) float Kl[T * SKF];
  __shared__ __align__(16) bf16  Vl[T * SK];
  __shared__ __align__(16) bf16  Ql[CH2 * SK];
  __shared__ __align__(16) float Ol[CH2 * SKF];
  __shared__ float Wol[D * D], bol[D], gl[D], bbl[D];
  int tid = threadIdx.x;

  const bf16* Kg = Kt + (size_t)bn * T * D;
  const bf16* Vg = Vt + (size_t)bn * T * D;
  const bf16* Qg = Qt + ((size_t)bn * T + CH2 * c) * D;
  for (int i = tid; i < T * 4; i += 256) {
    int r = i >> 2, p = i & 3;
    if (r < nk) {
      uint4 ku = *(const uint4*)&Kg[r * D + p * 8];
      *(float4*)&Kl[r * SKF + p * 8]     = make_float4(blo(ku.x), bhi(ku.x), blo(ku.y), bhi(ku.y));
      *(float4*)&Kl[r * SKF + p * 8 + 4] = make_float4(blo(ku.z), bhi(ku.z), blo(ku.w), bhi(ku.w));
      *(uint4*)&Vl[r * SK + p * 8]       = *(const uint4*)&Vg[r * D + p * 8];
    } else {
      *(float4*)&Kl[r * SKF + p * 8]     = make_float4(0.f, 0.f, 0.f, 0.f);
      *(float4*)&Kl[r * SKF + p * 8 + 4] = make_float4(0.f, 0.f, 0.f, 0.f);
      *(uint4*)&Vl[r * SK + p * 8]       = make_uint4(0u, 0u, 0u, 0u);
    }
  }
  if (tid < CH2 * 4) {
    int r = tid >> 2, p = tid & 3;
    *(uint4*)&Ql[r * SK + p * 8] = *(const uint4*)&Qg[r * D + p * 8];
  }
  for (int i = tid; i < D * D; i += 256) Wol[i] = tm_Wo[(size_t)n * D * D + i];
  if (tid < D) {
    bol[tid] = tm_bo[n * D + tid];
    gl[tid]  = ln_g[tid];
    bbl[tid] = ln_b[tid];
  }
  __syncthreads();

  // ---- attention: task = (row, head), 4 lanes per task ----
  {
    int task = tid >> 2, sl = tid & 3;
    if (task < 2 * CH2) {
      int rl = task >> 1, h = task & 1, ho = h * FD;
      int rg = CH2 * c + rl;
      uint4 q0 = *(const uint4*)&Ql[rl * SK + ho];
      uint4 q1 = *(const uint4*)&Ql[rl * SK + ho + 8];
      float qf[16];
      qf[0]  = blo(q0.x); qf[1]  = bhi(q0.x); qf[2]  = blo(q0.y); qf[3]  = bhi(q0.y);
      qf[4]  = blo(q0.z); qf[5]  = bhi(q0.z); qf[6]  = blo(q0.w); qf[7]  = bhi(q0.w);
      qf[8]  = blo(q1.x); qf[9]  = bhi(q1.x); qf[10] = blo(q1.y); qf[11] = bhi(q1.y);
      qf[12] = blo(q1.z); qf[13] = bhi(q1.z); qf[14] = blo(q1.w); qf[15] = bhi(q1.w);

      float sc[NJ];
      float mx = -3e38f;
#pragma unroll
      for (int j = 0; j < NJ; ++j) {
        int k = 4 * j + sl;
        sc[j] = -3e38f;
        if (k <= rg) {
          const float4 k0 = *(const float4*)&Kl[k * SKF + ho];
          const float4 k1 = *(const float4*)&Kl[k * SKF + ho + 4];
          const float4 k2 = *(const float4*)&Kl[k * SKF + ho + 8];
          const float4 k3 = *(const float4*)&Kl[k * SKF + ho + 12];
          float s0 = qf[0]*k0.x  + qf[1]*k0.y  + qf[2]*k0.z  + qf[3]*k0.w;
          float s1 = qf[4]*k1.x  + qf[5]*k1.y  + qf[6]*k1.z  + qf[7]*k1.w;
          float s2 = qf[8]*k2.x  + qf[9]*k2.y  + qf[10]*k2.z + qf[11]*k2.w;
          float s3 = qf[12]*k3.x + qf[13]*k3.y + qf[14]*k3.z + qf[15]*k3.w;
          float s = ((s0 + s1) + (s2 + s3)) * SCALE;
          sc[j] = s;
          mx = fmaxf(mx, s);
        }
      }
      mx = fmaxf(mx, __shfl_xor(mx, 1, 64));
      mx = fmaxf(mx, __shfl_xor(mx, 2, 64));
      float l = 0.f;
#pragma unroll
      for (int j = 0; j < NJ; ++j) {
        sc[j] = __expf(sc[j] - mx);   // invalid slots: exp(-inf) = 0
        l += sc[j];
      }
      l += __shfl_xor(l, 1, 64);
      l += __shfl_xor(l, 2, 64);
      float rli = 1.f / l;

      float acc[16];
#pragma unroll
      for (int f = 0; f < 16; ++f) acc[f] = 0.f;
#pragma unroll
      for (int j = 0; j < NJ; ++j) {
        int k = 4 * j + sl;
        if (k <= rg) {
          float p = sc[j];
          uint2 va = *(const uint2*)&Vl[k * SK + ho];
          uint2 vb = *(const uint2*)&Vl[k * SK + ho + 4];
          uint2 vc = *(const uint2*)&Vl[k * SK + ho + 8];
          uint2 vd = *(const uint2*)&Vl[k * SK + ho + 12];
          acc[0]  += p * blo(va.x); acc[1]  += p * bhi(va.x);
          acc[2]  += p * blo(va.y); acc[3]  += p * bhi(va.y);
          acc[4]  += p * blo(vb.x); acc[5]  += p * bhi(vb.x);
          acc[6]  += p * blo(vb.y); acc[7]  += p * bhi(vb.y);
          acc[8]  += p * blo(vc.x); acc[9]  += p * bhi(vc.x);
          acc[10] += p * blo(vc.y); acc[11] += p * bhi(vc.y);
          acc[12] += p * blo(vd.x); acc[13] += p * bhi(vd.x);
          acc[14] += p * blo(vd.y); acc[15] += p * bhi(vd.y);
        }
      }
#pragma unroll
      for (int f = 0; f < 16; ++f) {
        acc[f] += __shfl_xor(acc[f], 1, 64);
        acc[f] += __shfl_xor(acc[f], 2, 64);
      }
      if (sl == 0) {
#pragma unroll
        for (int f = 0; f < 16; ++f) Ol[rl * SKF + ho + f] = acc[f] * rli;
      }
    }
  }
  __syncthreads();

  // ---- O-proj + residual + LN: thread = (row, e-quad), 8 lanes per row ----
  {
    int rl = tid >> 3, q = tid & 7, e0 = q * 4;
    if (rl < CH2) {
      int rg = CH2 * c + rl;
      size_t rowo = ((size_t)(b * T + rg) * N + n) * D;
      uint2 eu = *(const uint2*)&E[rowo + e0];
      float res[4] = { blo(eu.x), bhi(eu.x), blo(eu.y), bhi(eu.y) };
      float o[4], s1 = 0.f, s2 = 0.f;
#pragma unroll
      for (int j = 0; j < 4; ++j) {
        int e = e0 + j;
        float aa = 0.f, ab = 0.f;
#pragma unroll
        for (int d = 0; d < D; d += 2) {
          aa += Ol[rl * SKF + d]     * Wol[d * D + e];
          ab += Ol[rl * SKF + d + 1] * Wol[(d + 1) * D + e];
        }
        float a = bol[e] + aa + ab + res[j];
        o[j] = a; s1 += a; s2 += a * a;
      }
      s1 += __shfl_xor(s1, 1, 64); s2 += __shfl_xor(s2, 1, 64);
      s1 += __shfl_xor(s1, 2, 64); s2 += __shfl_xor(s2, 2, 64);
      s1 += __shfl_xor(s1, 4, 64); s2 += __shfl_xor(s2, 4, 64);
      float mu  = s1 * (1.f / D);
      float var = s2 * (1.f / D) - mu * mu;
      float r = rsqrtf(var + 1e-5f);
      uint2 ou;
      ou.x = pk2((o[0]-mu)*r*gl[e0]+bbl[e0],    (o[1]-mu)*r*gl[e0+1]+bbl[e0+1]);
      ou.y = pk2((o[2]-mu)*r*gl[e0+2]+bbl[e0+2],(o[3]-mu)*r*gl[e0+3]+bbl[e0+3]);
      *(uint2*)&Tn[rowo + e0] = ou;
    }
  }
}

// ---------------------------------------------------------------------------
// spatial v2: block = (t, 2 batches), 256 threads.  Weights in LDS.
// ---------------------------------------------------------------------------
__global__ __launch_bounds__(256) void spatial_kernel(
    const bf16* __restrict__ E, const float* __restrict__ WsC,
    const float* __restrict__ bsC, const float* __restrict__ sm_Wo,
    const float* __restrict__ sm_bo, const float* __restrict__ ln_g,
    const float* __restrict__ ln_b, bf16* __restrict__ Sn) {
  int t  = blockIdx.x >> 5;          // B/BG = 32 groups per t
  int bg = blockIdx.x & 31;
  int b0 = bg * BG;
  __shared__ float Wq[D * D], Wk[D * D], Wv[D * D], Wo[D * D];
  __shared__ float bqs[D], bks[D], bvs[D], bos[D], gs[D], bbs[D];
  __shared__ __align__(16) bf16  Es[SR * SES];
  __shared__ float Qs[SR * SQS], Ks[SR * SQS], Vs[SR * SQS];
  int tid = threadIdx.x;

  for (int i = tid; i < D * D; i += 256) {
    Wq[i] = WsC[(size_t)(0 * T + t) * D * D + i];
    Wk[i] = WsC[(size_t)(1 * T + t) * D * D + i];
    Wv[i] = WsC[(size_t)(2 * T + t) * D * D + i];
    Wo[i] = sm_Wo[(size_t)t * D * D + i];
  }
  if (tid < D) {
    bqs[tid] = bsC[(0 * T + t) * D + tid];
    bks[tid] = bsC[(1 * T + t) * D + tid];
    bvs[tid] = bsC[(2 * T + t) * D + tid];
    bos[tid] = sm_bo[t * D + tid];
    gs[tid]  = ln_g[tid];
    bbs[tid] = ln_b[tid];
  }
  if (tid < SR * 4) {
    int r = tid >> 2, p = tid & 3;
    int b = b0 + r / N, n = r % N;
    *(uint4*)&Es[r * SES + p * 8] =
        *(const uint4*)&E[(((size_t)b * T + t) * N + n) * D + p * 8];
  }
  __syncthreads();

#pragma unroll 1
  for (int i = tid; i < SR * D; i += 256) {
    int r = i >> 5, e = i & 31;
    float aq = bqs[e], ak = bks[e], av = bvs[e];
#pragma unroll
    for (int d = 0; d < D; ++d) {
      float x = b2f(Es[r * SES + d]);
      aq += x * Wq[d * D + e];
      ak += x * Wk[d * D + e];
      av += x * Wv[d * D + e];
    }
    Qs[r * SQS + e] = aq;
    Ks[r * SQS + e] = ak;
    Vs[r * SQS + e] = av;
  }
  __syncthreads();

  if (tid < SR * NH) {
    int r = tid >> 1, h = tid & 1, ho = h * FD;
    int kb = (r >= N) ? N : 0;
    float q[FD];
#pragma unroll
    for (int f = 0; f < FD; ++f) q[f] = Qs[r * SQS + ho + f];
    float sc[N];
    float m = -1e30f;
#pragma unroll
    for (int k = 0; k < N; ++k) {
      float sa = 0.f, sb = 0.f;
#pragma unroll
      for (int f = 0; f < FD; f += 2) {
        sa += q[f]     * Ks[(kb + k) * SQS + ho + f];
        sb += q[f + 1] * Ks[(kb + k) * SQS + ho + f + 1];
      }
      float s = (sa + sb) * SCALE;
      sc[k] = s;
      m = fmaxf(m, s);
    }
    float l = 0.f;
#pragma unroll
    for (int k = 0; k < N; ++k) { sc[k] = __expf(sc[k] - m); l += sc[k]; }
    float rl = 1.f / l;
#pragma unroll
    for (int f = 0; f < FD; ++f) {
      float a = 0.f;
#pragma unroll
      for (int k = 0; k < N; ++k) a += sc[k] * Vs[(kb + k) * SQS + ho + f];
      Qs[r * SQS + ho + f] = a * rl;
    }
  }
  __syncthreads();

#pragma unroll 1
  for (int it = 0; it < SR * D / 256; ++it) {
    int i = it * 256 + tid;
    int r = i >> 5, e = i & 31;
    float aa = 0.f, ab = 0.f;
#pragma unroll
    for (int d = 0; d < D; d += 2) {
      aa += Qs[r * SQS + d]     * Wo[d * D + e];
      ab += Qs[r * SQS + d + 1] * Wo[(d + 1) * D + e];
    }
    float o = bos[e] + aa + ab + b2f(Es[r * SES + e]);
    float s1 = o, s2 = o * o;
    s1 += __shfl_xor(s1, 1, 64);  s2 += __shfl_xor(s2, 1, 64);
    s1 += __shfl_xor(s1, 2, 64);  s2 += __shfl_xor(s2, 2, 64);
    s1 += __shfl_xor(s1, 4, 64);  s2 += __shfl_xor(s2, 4, 64);
    s1 += __shfl_xor(s1, 8, 64);  s2 += __shfl_xor(s2, 8, 64);
    s1 += __shfl_xor(s1, 16, 64); s2 += __shfl_xor(s2, 16, 64);
    float mu  = s1 * (1.f / D);
    float var = s2 * (1.f / D) - mu * mu;
    float rr = rsqrtf(var + 1e-5f);
    int b = b0 + r / N, n = r % N;
    Sn[(((size_t)b * T + t) * N + n) * D + e] =
        __float2bfloat16((o - mu) * rr * gs[e] + bbs[e]);
  }
}

// ---------------------------------------------------------------------------
// ts = Tn + Sn; ff = relu(ts@W1+b1)@W2+b2; E = LN(ff + ts).  Row per thread.
// ---------------------------------------------------------------------------
__global__ __launch_bounds__(256) void ff_kernel(
    const bf16* __restrict__ Tn, const bf16* __restrict__ Sn,
    const float* __restrict__ W1, const float* __restrict__ b1,
    const float* __restrict__ W2, const float* __restrict__ b2,
    const float* __restrict__ ln_g, const float* __restrict__ ln_b,
    bf16* __restrict__ E) {
  __shared__ float w1[D * FF], w2[FF * D], bb1[FF], bb2[D], g[D], bbn[D];
  int tid = threadIdx.x;
  for (int i = tid; i < D * FF; i += 256) { w1[i] = W1[i]; w2[i] = W2[i]; }
  if (tid < FF) bb1[tid] = b1[tid];
  if (tid < D) { bb2[tid] = b2[tid]; g[tid] = ln_g[tid]; bbn[tid] = ln_b[tid]; }
  __syncthreads();
  int row = blockIdx.x * 256 + tid;
  if (row >= B * T * N) return;
  float ts[D];
#pragma unroll
  for (int d = 0; d < D; ++d)
    ts[d] = b2f(Tn[(size_t)row * D + d]) + b2f(Sn[(size_t)row * D + d]);
  float x[D];
#pragma unroll
  for (int d = 0; d < D; ++d) x[d] = bb2[d] + ts[d];
#pragma unroll 1
  for (int c = 0; c < 2; ++c) {
    float hh[32];
#pragma unroll
    for (int j = 0; j < 32; ++j) {
      int jj = c * 32 + j;
      float a = bb1[jj];
#pragma unroll
      for (int d = 0; d < D; ++d) a += ts[d] * w1[d * FF + jj];
      hh[j] = fmaxf(a, 0.f);
    }
#pragma unroll
    for (int e2 = 0; e2 < D; ++e2) {
      float a = 0.f;
#pragma unroll
      for (int j = 0; j < 32; ++j) a += hh[j] * w2[(c * 32 + j) * D + e2];
      x[e2] += a;
    }
  }
  float mu = 0.f;
#pragma unroll
  for (int e2 = 0; e2 < D; ++e2) mu += x[e2];
  mu *= (1.f / D);
  float var = 0.f;
#pragma unroll
  for (int e2 = 0; e2 < D; ++e2) { float c = x[e2] - mu; var += c * c; }
  var *= (1.f / D);
  float r = rsqrtf(var + 1e-5f);
#pragma unroll
  for (int e2 = 0; e2 < D; ++e2)
    E[(size_t)row * D + e2] = __float2bfloat16((x[e2] - mu) * r * g[e2] + bbn[e2]);
}

// ---------------------------------------------------------------------------
// out = E@op_W + op_b + X   (f32 out)
// ---------------------------------------------------------------------------
__global__ __launch_bounds__(256) void out_kernel(
    const bf16* __restrict__ E, const float* __restrict__ op_W,
    const float* __restrict__ op_b, const float* __restrict__ X,
    float* __restrict__ out) {
  int idx = blockIdx.x * 256 + threadIdx.x;
  if (idx >= B * T * N * M) return;
  int m  = idx % M;
  int n  = (idx / M) % N;
  int bt = idx / (M * N);
  float acc = op_b[n * M + m];
  const bf16* e = E + ((size_t)bt * N + n) * D;
#pragma unroll
  for (int d = 0; d < D; ++d) acc += b2f(e[d]) * op_W[(n * D + d) * M + m];
  acc += X[idx];
  out[idx] = acc;
}

// ---------------------------------------------------------------------------
extern "C" void kernel_launch(void* const* d_in, const int* in_sizes, int n_in,
                              void* d_out, int out_size, void* d_ws, size_t ws_size,
                              hipStream_t stream) {
  const float* X     = (const float*)d_in[0];
  const float* pe    = (const float*)d_in[1];
  const float* E_W   = (const float*)d_in[2];
  const float* E_b   = (const float*)d_in[3];
  const float* tq_W  = (const float*)d_in[4];
  const float* tq_b  = (const float*)d_in[5];
  const float* tk_W  = (const float*)d_in[6];
  const float* tk_b  = (const float*)d_in[7];
  const float* tv_W  = (const float*)d_in[8];
  const float* tv_b  = (const float*)d_in[9];
  const float* tm_Wq = (const float*)d_in[10];
  const float* tm_bq = (const float*)d_in[11];
  const float* tm_Wk = (const float*)d_in[12];
  const float* tm_bk = (const float*)d_in[13];
  const float* tm_Wv = (const float*)d_in[14];
  const float* tm_bv = (const float*)d_in[15];
  const float* tm_Wo = (const float*)d_in[16];
  const float* tm_bo = (const float*)d_in[17];
  const float* sq_W  = (const float*)d_in[18];
  const float* sq_b  = (const float*)d_in[19];
  const float* sk_W  = (const float*)d_in[20];
  const float* sk_b  = (const float*)d_in[21];
  const float* sv_W  = (const float*)d_in[22];
  const float* sv_b  = (const float*)d_in[23];
  const float* sm_Wq = (const float*)d_in[24];
  const float* sm_bq = (const float*)d_in[25];
  const float* sm_Wk = (const float*)d_in[26];
  const float* sm_bk = (const float*)d_in[27];
  const float* sm_Wv = (const float*)d_in[28];
  const float* sm_bv = (const float*)d_in[29];
  const float* sm_Wo = (const float*)d_in[30];
  const float* sm_bo = (const float*)d_in[31];
  const float* ff1_W = (const float*)d_in[32];
  const float* ff1_b = (const float*)d_in[33];
  const float* ff2_W = (const float*)d_in[34];
  const float* ff2_b = (const float*)d_in[35];
  const float* ln_g  = (const float*)d_in[36];
  const float* ln_b  = (const float*)d_in[37];
  const float* op_W  = (const float*)d_in[38];
  const float* op_b  = (const float*)d_in[39];
  float* out = (float*)d_out;

  float* WtC = (float*)d_ws;                         // 3*N*D*D
  float* btC = WtC + 3 * N * D * D;                  // 3*N*D
  float* WsC = btC + 3 * N * D;                      // 3*T*D*D
  float* bsC = WsC + 3 * T * D * D;                  // 3*T*D
  size_t act = (size_t)B * T * N * D;
  bf16* Ebuf = (bf16*)(bsC + 3 * T * D);
  bf16* Tn   = Ebuf + act;
  bf16* Qt   = Tn + act;
  bf16* Kt   = Qt + act;
  bf16* Vt   = Kt + act;
  bf16* Sn   = Qt;                                   // alias

  compose3_kernel<<<3 * N, 256, 0, stream>>>(
      tq_W, tq_b, tm_Wq, tm_bq, tk_W, tk_b, tm_Wk, tm_bk,
      tv_W, tv_b, tm_Wv, tm_bv, WtC, btC, N);
  compose3_kernel<<<3 * T, 256, 0, stream>>>(
      sq_W, sq_b, sm_Wq, sm_bq, sk_W, sk_b, sm_Wk, sm_bk,
      sv_W, sv_b, sm_Wv, sm_bv, WsC, bsC, T);

  embed_kernel<<<(B * T * N * D) / 256, 256, 0, stream>>>(X, pe, E_W, E_b, Ebuf);

  for (int l = 0; l < L; ++l) {
    qkvt_kernel<<<N * RCH, 256, 0, stream>>>(Ebuf, WtC, btC, Qt, Kt, Vt);
    attnt_kernel<<<B * N * 4, 256, 0, stream>>>(Qt, Kt, Vt, Ebuf, tm_Wo, tm_bo, ln_g, ln_b, Tn);
    spatial_kernel<<<T * (B / BG), 256, 0, stream>>>(Ebuf, WsC, bsC, sm_Wo, sm_bo, ln_g, ln_b, Sn);
    ff_kernel<<<(B * T * N + 255) / 256, 256, 0, stream>>>(Tn, Sn, ff1_W, ff1_b, ff2_W, ff2_b, ln_g, ln_b, Ebuf);
  }

  out_kernel<<<(B * T * N * M + 255) / 256, 256, 0, stream>>>(Ebuf, op_W, op_b, X, out);
}

// Round 14
// 1114.008 us; speedup vs baseline: 3.1372x; 1.0037x over previous
//
#include <hip/hip_runtime.h>
#include <hip/hip_bf16.h>

typedef __hip_bfloat16 bf16;

constexpr int B  = 64, T = 120, N = 24, M = 3, D = 32;
constexpr int NH = 2, FD = 16, FF = 64, L = 3;
constexpr float SCALE = 0.25f;   // 1/sqrt(FD)
constexpr int SK  = 40;          // attnt Q/V LDS stride (bf16, 80B rows)
constexpr int SKF = 36;          // attnt K/O LDS stride (f32, 144B rows)
constexpr int CH2 = 30;          // attnt rows per chunk: 4 x 30 = 120 exactly
constexpr int NJ  = 30;          // max keys per lane slice (120/4)
constexpr int RCH = 30;          // qkvt row chunks: 7680/256
constexpr int BG  = 2;           // spatial batches per block
constexpr int SR  = N * BG;      // spatial rows per block = 48
constexpr int SES = 40;          // spatial Es bf16 stride
constexpr int SQS = 32;          // spatial Q/K/V f32 stride
constexpr int FR  = 32;          // ff rows per block (8 lanes/row)

__device__ __forceinline__ float b2f(bf16 x) { return __bfloat162float(x); }
__device__ __forceinline__ float blo(unsigned u) { return __uint_as_float(u << 16); }
__device__ __forceinline__ float bhi(unsigned u) { return __uint_as_float(u & 0xffff0000u); }
__device__ __forceinline__ unsigned pk2(float a, float b) {
  bf16 x = __float2bfloat16(a), y = __float2bfloat16(b);
  unsigned short ux = *reinterpret_cast<unsigned short*>(&x);
  unsigned short uy = *reinterpret_cast<unsigned short*>(&y);
  return (unsigned)ux | ((unsigned)uy << 16);
}

// ---------------------------------------------------------------------------
// Compose q/k/v chained linears: grid = 3*U blocks.  Wc = W1@W2, bc = b1@W2+b2.
// ---------------------------------------------------------------------------
__global__ __launch_bounds__(256) void compose3_kernel(
    const float* __restrict__ W1q, const float* __restrict__ b1q,
    const float* __restrict__ W2q, const float* __restrict__ b2q,
    const float* __restrict__ W1k, const float* __restrict__ b1k,
    const float* __restrict__ W2k, const float* __restrict__ b2k,
    const float* __restrict__ W1v, const float* __restrict__ b1v,
    const float* __restrict__ W2v, const float* __restrict__ b2v,
    float* __restrict__ Wc, float* __restrict__ bc, int U) {
  int fam = blockIdx.x / U;
  int n   = blockIdx.x % U;
  const float* W1 = (fam == 0) ? W1q : (fam == 1) ? W1k : W1v;
  const float* b1 = (fam == 0) ? b1q : (fam == 1) ? b1k : b1v;
  const float* W2 = (fam == 0) ? W2q : (fam == 1) ? W2k : W2v;
  const float* b2 = (fam == 0) ? b2q : (fam == 1) ? b2k : b2v;
  const float* w1 = W1 + n * D * D;
  const float* w2 = W2 + n * D * D;
  float* wc  = Wc + (size_t)(fam * U + n) * D * D;
  float* bcp = bc + (fam * U + n) * D;
  __shared__ float s1[D * D], s2[D * D];
  for (int i = threadIdx.x; i < D * D; i += 256) { s1[i] = w1[i]; s2[i] = w2[i]; }
  __syncthreads();
  for (int i = threadIdx.x; i < D * D; i += 256) {
    int d = i >> 5, f = i & 31;
    float acc = 0.f;
#pragma unroll
    for (int e = 0; e < D; ++e) acc += s1[d * D + e] * s2[e * D + f];
    wc[i] = acc;
  }
  if (threadIdx.x < D) {
    int f = threadIdx.x;
    float acc = b2[n * D + f];
#pragma unroll
    for (int e = 0; e < D; ++e) acc += b1[n * D + e] * s2[e * D + f];
    bcp[f] = acc;
  }
}

// ---------------------------------------------------------------------------
// E[b,t,n,d] = X@E_W + E_b + pe   (bf16 out)
// ---------------------------------------------------------------------------
__global__ __launch_bounds__(256) void embed_kernel(
    const float* __restrict__ X, const float* __restrict__ pe,
    const float* __restrict__ E_W, const float* __restrict__ E_b,
    bf16* __restrict__ E) {
  int idx = blockIdx.x * 256 + threadIdx.x;
  if (idx >= B * T * N * D) return;
  int d = idx & 31;
  int n = (idx >> 5) % N;
  int bt = idx / (D * N);
  int t = bt % T;
  const float* x = X + bt * (N * M) + n * M;
  float acc = E_b[n * D + d] + pe[t * D + d];
#pragma unroll
  for (int m = 0; m < M; ++m) acc += x[m] * E_W[(n * M + m) * D + d];
  E[idx] = __float2bfloat16(acc);
}

// ---------------------------------------------------------------------------
// qkvt: composed Q/K/V projections for the temporal path.
// Weights in LDS.  Writes Qt/Kt/Vt[b][n][t][32] bf16 (t-contiguous).
// ---------------------------------------------------------------------------
__global__ __launch_bounds__(256) void qkvt_kernel(
    const bf16* __restrict__ E, const float* __restrict__ WtC,
    const float* __restrict__ btC,
    bf16* __restrict__ Qt, bf16* __restrict__ Kt, bf16* __restrict__ Vt) {
  int n     = blockIdx.x / RCH;
  int chunk = blockIdx.x % RCH;
  __shared__ float wsh[3 * D * D];
  __shared__ float bsh[3 * D];
  int tid = threadIdx.x;
  for (int i = tid; i < 3 * D * D; i += 256) {
    int fam = i >> 10, idx = i & 1023;
    wsh[i] = WtC[(size_t)(fam * N + n) * D * D + idx];
  }
  if (tid < 3 * D) {
    int fam = tid >> 5, e = tid & 31;
    bsh[tid] = btC[(fam * N + n) * D + e];
  }
  __syncthreads();

  int row = chunk * 256 + tid;          // (b*T + t)
  int b = row / T, t = row % T;
  const bf16* er = E + ((size_t)row * N + n) * D;
  float x[D];
#pragma unroll
  for (int p = 0; p < 4; ++p) {
    uint4 u = *(const uint4*)&er[p * 8];
    x[p*8+0] = blo(u.x); x[p*8+1] = bhi(u.x);
    x[p*8+2] = blo(u.y); x[p*8+3] = bhi(u.y);
    x[p*8+4] = blo(u.z); x[p*8+5] = bhi(u.z);
    x[p*8+6] = blo(u.w); x[p*8+7] = bhi(u.w);
  }
  size_t dsto = (((size_t)b * N + n) * T + t) * D;
  bf16* dsts[3] = { Qt + dsto, Kt + dsto, Vt + dsto };
#pragma unroll
  for (int fam = 0; fam < 3; ++fam) {
    const float* w  = wsh + fam * D * D;
    const float* bi = bsh + fam * D;
    bf16* dst = dsts[fam];
#pragma unroll
    for (int g = 0; g < 4; ++g) {
      float a[8];
#pragma unroll
      for (int j = 0; j < 8; ++j) a[j] = bi[g * 8 + j];
#pragma unroll
      for (int d = 0; d < D; ++d) {
        float xv = x[d];
#pragma unroll
        for (int j = 0; j < 8; ++j) a[j] += xv * w[d * D + g * 8 + j];
      }
      uint4 o;
      o.x = pk2(a[0], a[1]); o.y = pk2(a[2], a[3]);
      o.z = pk2(a[4], a[5]); o.w = pk2(a[6], a[7]);
      *(uint4*)&dst[g * 8] = o;
    }
  }
}

// ---------------------------------------------------------------------------
// attnt v5: v4 + EARLY EXIT.  v4 ran a fixed 30 unrolled iterations per lane
// with per-key masking — c=0 blocks wasted 73% of issue slots on fully-masked
// iterations.  jend = (rg>>2)+1 is task-uniform; `break` keeps sc[] statically
// indexed (rule #20) while cutting executed iterations to 8/15/23/30.
// ---------------------------------------------------------------------------
__global__ __launch_bounds__(256) void attnt_kernel(
    const bf16* __restrict__ Qt, const bf16* __restrict__ Kt,
    const bf16* __restrict__ Vt, const bf16* __restrict__ E,
    const float* __restrict__ tm_Wo, const float* __restrict__ tm_bo,
    const float* __restrict__ ln_g, const float* __restrict__ ln_b,
    bf16* __restrict__ Tn) {
  int c  = blockIdx.x & 3;
  int bn = blockIdx.x >> 2;
  int n  = bn % N, b = bn / N;
  int nk = CH2 * (c + 1);               // keys used: 30/60/90/120
  int nk4 = (nk + 4 > T) ? T : nk + 4;  // stage a zero-filled guard tail
  __shared__ __align__(16) float Kl[T * SKF];
  __shared__ __align__(16) bf16  Vl[T * SK];
  __shared__ __align__(16) bf16  Ql[CH2 * SK];
  __shared__ __align__(16) float Ol[CH2 * SKF];
  __shared__ float Wol[D * D], bol[D], gl[D], bbl[D];
  int tid = threadIdx.x;

  const bf16* Kg = Kt + (size_t)bn * T * D;
  const bf16* Vg = Vt + (size_t)bn * T * D;
  const bf16* Qg = Qt + ((size_t)bn * T + CH2 * c) * D;
  for (int i = tid; i < nk4 * 4; i += 256) {
    int r = i >> 2, p = i & 3;
    if (r < nk) {
      uint4 ku = *(const uint4*)&Kg[r * D + p * 8];
      *(float4*)&Kl[r * SKF + p * 8]     = make_float4(blo(ku.x), bhi(ku.x), blo(ku.y), bhi(ku.y));
      *(float4*)&Kl[r * SKF + p * 8 + 4] = make_float4(blo(ku.z), bhi(ku.z), blo(ku.w), bhi(ku.w));
      *(uint4*)&Vl[r * SK + p * 8]       = *(const uint4*)&Vg[r * D + p * 8];
    } else {
      *(float4*)&Kl[r * SKF + p * 8]     = make_float4(0.f, 0.f, 0.f, 0.f);
      *(float4*)&Kl[r * SKF + p * 8 + 4] = make_float4(0.f, 0.f, 0.f, 0.f);
      *(uint4*)&Vl[r * SK + p * 8]       = make_uint4(0u, 0u, 0u, 0u);
    }
  }
  if (tid < CH2 * 4) {
    int r = tid >> 2, p = tid & 3;
    *(uint4*)&Ql[r * SK + p * 8] = *(const uint4*)&Qg[r * D + p * 8];
  }
  for (int i = tid; i < D * D; i += 256) Wol[i] = tm_Wo[(size_t)n * D * D + i];
  if (tid < D) {
    bol[tid] = tm_bo[n * D + tid];
    gl[tid]  = ln_g[tid];
    bbl[tid] = ln_b[tid];
  }
  __syncthreads();

  // ---- attention: task = (row, head), 4 lanes per task ----
  {
    int task = tid >> 2, sl = tid & 3;
    if (task < 2 * CH2) {
      int rl = task >> 1, h = task & 1, ho = h * FD;
      int rg = CH2 * c + rl;
      int jend = (rg >> 2) + 1;        // task-uniform early-exit bound
      uint4 q0 = *(const uint4*)&Ql[rl * SK + ho];
      uint4 q1 = *(const uint4*)&Ql[rl * SK + ho + 8];
      float qf[16];
      qf[0]  = blo(q0.x); qf[1]  = bhi(q0.x); qf[2]  = blo(q0.y); qf[3]  = bhi(q0.y);
      qf[4]  = blo(q0.z); qf[5]  = bhi(q0.z); qf[6]  = blo(q0.w); qf[7]  = bhi(q0.w);
      qf[8]  = blo(q1.x); qf[9]  = bhi(q1.x); qf[10] = blo(q1.y); qf[11] = bhi(q1.y);
      qf[12] = blo(q1.z); qf[13] = bhi(q1.z); qf[14] = blo(q1.w); qf[15] = bhi(q1.w);

      float sc[NJ];
      float mx = -3e38f;
#pragma unroll
      for (int j = 0; j < NJ; ++j) {
        if (j >= jend) break;
        int k = 4 * j + sl;
        sc[j] = -3e38f;
        if (k <= rg) {
          const float4 k0 = *(const float4*)&Kl[k * SKF + ho];
          const float4 k1 = *(const float4*)&Kl[k * SKF + ho + 4];
          const float4 k2 = *(const float4*)&Kl[k * SKF + ho + 8];
          const float4 k3 = *(const float4*)&Kl[k * SKF + ho + 12];
          float s0 = qf[0]*k0.x  + qf[1]*k0.y  + qf[2]*k0.z  + qf[3]*k0.w;
          float s1 = qf[4]*k1.x  + qf[5]*k1.y  + qf[6]*k1.z  + qf[7]*k1.w;
          float s2 = qf[8]*k2.x  + qf[9]*k2.y  + qf[10]*k2.z + qf[11]*k2.w;
          float s3 = qf[12]*k3.x + qf[13]*k3.y + qf[14]*k3.z + qf[15]*k3.w;
          float s = ((s0 + s1) + (s2 + s3)) * SCALE;
          sc[j] = s;
          mx = fmaxf(mx, s);
        }
      }
      mx = fmaxf(mx, __shfl_xor(mx, 1, 64));
      mx = fmaxf(mx, __shfl_xor(mx, 2, 64));
      float l = 0.f;
#pragma unroll
      for (int j = 0; j < NJ; ++j) {
        if (j >= jend) break;
        sc[j] = __expf(sc[j] - mx);   // invalid slots: exp(-inf) = 0
        l += sc[j];
      }
      l += __shfl_xor(l, 1, 64);
      l += __shfl_xor(l, 2, 64);
      float rli = 1.f / l;

      float acc[16];
#pragma unroll
      for (int f = 0; f < 16; ++f) acc[f] = 0.f;
#pragma unroll
      for (int j = 0; j < NJ; ++j) {
        if (j >= jend) break;
        int k = 4 * j + sl;
        if (k <= rg) {
          float p = sc[j];
          uint2 va = *(const uint2*)&Vl[k * SK + ho];
          uint2 vb = *(const uint2*)&Vl[k * SK + ho + 4];
          uint2 vc = *(const uint2*)&Vl[k * SK + ho + 8];
          uint2 vd = *(const uint2*)&Vl[k * SK + ho + 12];
          acc[0]  += p * blo(va.x); acc[1]  += p * bhi(va.x);
          acc[2]  += p * blo(va.y); acc[3]  += p * bhi(va.y);
          acc[4]  += p * blo(vb.x); acc[5]  += p * bhi(vb.x);
          acc[6]  += p * blo(vb.y); acc[7]  += p * bhi(vb.y);
          acc[8]  += p * blo(vc.x); acc[9]  += p * bhi(vc.x);
          acc[10] += p * blo(vc.y); acc[11] += p * bhi(vc.y);
          acc[12] += p * blo(vd.x); acc[13] += p * bhi(vd.x);
          acc[14] += p * blo(vd.y); acc[15] += p * bhi(vd.y);
        }
      }
#pragma unroll
      for (int f = 0; f < 16; ++f) {
        acc[f] += __shfl_xor(acc[f], 1, 64);
        acc[f] += __shfl_xor(acc[f], 2, 64);
      }
      if (sl == 0) {
#pragma unroll
        for (int f = 0; f < 16; ++f) Ol[rl * SKF + ho + f] = acc[f] * rli;
      }
    }
  }
  __syncthreads();

  // ---- O-proj + residual + LN: thread = (row, e-quad), 8 lanes per row ----
  {
    int rl = tid >> 3, q = tid & 7, e0 = q * 4;
    if (rl < CH2) {
      int rg = CH2 * c + rl;
      size_t rowo = ((size_t)(b * T + rg) * N + n) * D;
      uint2 eu = *(const uint2*)&E[rowo + e0];
      float res[4] = { blo(eu.x), bhi(eu.x), blo(eu.y), bhi(eu.y) };
      float o[4], s1 = 0.f, s2 = 0.f;
#pragma unroll
      for (int j = 0; j < 4; ++j) {
        int e = e0 + j;
        float aa = 0.f, ab = 0.f;
#pragma unroll
        for (int d = 0; d < D; d += 2) {
          aa += Ol[rl * SKF + d]     * Wol[d * D + e];
          ab += Ol[rl * SKF + d + 1] * Wol[(d + 1) * D + e];
        }
        float a = bol[e] + aa + ab + res[j];
        o[j] = a; s1 += a; s2 += a * a;
      }
      s1 += __shfl_xor(s1, 1, 64); s2 += __shfl_xor(s2, 1, 64);
      s1 += __shfl_xor(s1, 2, 64); s2 += __shfl_xor(s2, 2, 64);
      s1 += __shfl_xor(s1, 4, 64); s2 += __shfl_xor(s2, 4, 64);
      float mu  = s1 * (1.f / D);
      float var = s2 * (1.f / D) - mu * mu;
      float r = rsqrtf(var + 1e-5f);
      uint2 ou;
      ou.x = pk2((o[0]-mu)*r*gl[e0]+bbl[e0],    (o[1]-mu)*r*gl[e0+1]+bbl[e0+1]);
      ou.y = pk2((o[2]-mu)*r*gl[e0+2]+bbl[e0+2],(o[3]-mu)*r*gl[e0+3]+bbl[e0+3]);
      *(uint2*)&Tn[rowo + e0] = ou;
    }
  }
}

// ---------------------------------------------------------------------------
// spatial v2: block = (t, 2 batches), 256 threads.  Weights in LDS.
// ---------------------------------------------------------------------------
__global__ __launch_bounds__(256) void spatial_kernel(
    const bf16* __restrict__ E, const float* __restrict__ WsC,
    const float* __restrict__ bsC, const float* __restrict__ sm_Wo,
    const float* __restrict__ sm_bo, const float* __restrict__ ln_g,
    const float* __restrict__ ln_b, bf16* __restrict__ Sn) {
  int t  = blockIdx.x >> 5;          // B/BG = 32 groups per t
  int bg = blockIdx.x & 31;
  int b0 = bg * BG;
  __shared__ float Wq[D * D], Wk[D * D], Wv[D * D], Wo[D * D];
  __shared__ float bqs[D], bks[D], bvs[D], bos[D], gs[D], bbs[D];
  __shared__ __align__(16) bf16  Es[SR * SES];
  __shared__ float Qs[SR * SQS], Ks[SR * SQS], Vs[SR * SQS];
  int tid = threadIdx.x;

  for (int i = tid; i < D * D; i += 256) {
    Wq[i] = WsC[(size_t)(0 * T + t) * D * D + i];
    Wk[i] = WsC[(size_t)(1 * T + t) * D * D + i];
    Wv[i] = WsC[(size_t)(2 * T + t) * D * D + i];
    Wo[i] = sm_Wo[(size_t)t * D * D + i];
  }
  if (tid < D) {
    bqs[tid] = bsC[(0 * T + t) * D + tid];
    bks[tid] = bsC[(1 * T + t) * D + tid];
    bvs[tid] = bsC[(2 * T + t) * D + tid];
    bos[tid] = sm_bo[t * D + tid];
    gs[tid]  = ln_g[tid];
    bbs[tid] = ln_b[tid];
  }
  if (tid < SR * 4) {
    int r = tid >> 2, p = tid & 3;
    int b = b0 + r / N, n = r % N;
    *(uint4*)&Es[r * SES + p * 8] =
        *(const uint4*)&E[(((size_t)b * T + t) * N + n) * D + p * 8];
  }
  __syncthreads();

#pragma unroll 1
  for (int i = tid; i < SR * D; i += 256) {
    int r = i >> 5, e = i & 31;
    float aq = bqs[e], ak = bks[e], av = bvs[e];
#pragma unroll
    for (int d = 0; d < D; ++d) {
      float x = b2f(Es[r * SES + d]);
      aq += x * Wq[d * D + e];
      ak += x * Wk[d * D + e];
      av += x * Wv[d * D + e];
    }
    Qs[r * SQS + e] = aq;
    Ks[r * SQS + e] = ak;
    Vs[r * SQS + e] = av;
  }
  __syncthreads();

  if (tid < SR * NH) {
    int r = tid >> 1, h = tid & 1, ho = h * FD;
    int kb = (r >= N) ? N : 0;
    float q[FD];
#pragma unroll
    for (int f = 0; f < FD; ++f) q[f] = Qs[r * SQS + ho + f];
    float sc[N];
    float m = -1e30f;
#pragma unroll
    for (int k = 0; k < N; ++k) {
      float sa = 0.f, sb = 0.f;
#pragma unroll
      for (int f = 0; f < FD; f += 2) {
        sa += q[f]     * Ks[(kb + k) * SQS + ho + f];
        sb += q[f + 1] * Ks[(kb + k) * SQS + ho + f + 1];
      }
      float s = (sa + sb) * SCALE;
      sc[k] = s;
      m = fmaxf(m, s);
    }
    float l = 0.f;
#pragma unroll
    for (int k = 0; k < N; ++k) { sc[k] = __expf(sc[k] - m); l += sc[k]; }
    float rl = 1.f / l;
#pragma unroll
    for (int f = 0; f < FD; ++f) {
      float a = 0.f;
#pragma unroll
      for (int k = 0; k < N; ++k) a += sc[k] * Vs[(kb + k) * SQS + ho + f];
      Qs[r * SQS + ho + f] = a * rl;
    }
  }
  __syncthreads();

#pragma unroll 1
  for (int it = 0; it < SR * D / 256; ++it) {
    int i = it * 256 + tid;
    int r = i >> 5, e = i & 31;
    float aa = 0.f, ab = 0.f;
#pragma unroll
    for (int d = 0; d < D; d += 2) {
      aa += Qs[r * SQS + d]     * Wo[d * D + e];
      ab += Qs[r * SQS + d + 1] * Wo[(d + 1) * D + e];
    }
    float o = bos[e] + aa + ab + b2f(Es[r * SES + e]);
    float s1 = o, s2 = o * o;
    s1 += __shfl_xor(s1, 1, 64);  s2 += __shfl_xor(s2, 1, 64);
    s1 += __shfl_xor(s1, 2, 64);  s2 += __shfl_xor(s2, 2, 64);
    s1 += __shfl_xor(s1, 4, 64);  s2 += __shfl_xor(s2, 4, 64);
    s1 += __shfl_xor(s1, 8, 64);  s2 += __shfl_xor(s2, 8, 64);
    s1 += __shfl_xor(s1, 16, 64); s2 += __shfl_xor(s2, 16, 64);
    float mu  = s1 * (1.f / D);
    float var = s2 * (1.f / D) - mu * mu;
    float rr = rsqrtf(var + 1e-5f);
    int b = b0 + r / N, n = r % N;
    Sn[(((size_t)b * T + t) * N + n) * D + e] =
        __float2bfloat16((o - mu) * rr * gs[e] + bbs[e]);
  }
}

// ---------------------------------------------------------------------------
// ff v2: block = 32 rows x 8 lanes/row (grid 240, was 30 — 4x parallelism).
// Pass1: lane computes 8 hidden units -> hl LDS (65-stride, conflict-free).
// Pass2: lane computes 4 outputs over 64 hidden + LN via 3 shfl-xor.
// ---------------------------------------------------------------------------
__global__ __launch_bounds__(256) void ff_kernel(
    const bf16* __restrict__ Tn, const bf16* __restrict__ Sn,
    const float* __restrict__ W1, const float* __restrict__ b1,
    const float* __restrict__ W2, const float* __restrict__ b2,
    const float* __restrict__ ln_g, const float* __restrict__ ln_b,
    bf16* __restrict__ E) {
  __shared__ float w1s[D * FF], w2s[FF * D];
  __shared__ float bb1[FF], bb2[D], gs[D], bbs[D];
  __shared__ float tsl[FR][D + 1];
  __shared__ float hl[FR][FF + 1];
  int tid = threadIdx.x;
  int r0 = blockIdx.x * FR;
  for (int i = tid; i < D * FF; i += 256) { w1s[i] = W1[i]; w2s[i] = W2[i]; }
  if (tid < FF) bb1[tid] = b1[tid];
  if (tid < D) { bb2[tid] = b2[tid]; gs[tid] = ln_g[tid]; bbs[tid] = ln_b[tid]; }
  int r = tid >> 3, s = tid & 7;
  {
    const bf16* tp = Tn + ((size_t)(r0 + r)) * D + s * 4;
    const bf16* sp = Sn + ((size_t)(r0 + r)) * D + s * 4;
    uint2 tu = *(const uint2*)tp;
    uint2 su = *(const uint2*)sp;
    tsl[r][s*4+0] = blo(tu.x) + blo(su.x);
    tsl[r][s*4+1] = bhi(tu.x) + bhi(su.x);
    tsl[r][s*4+2] = blo(tu.y) + blo(su.y);
    tsl[r][s*4+3] = bhi(tu.y) + bhi(su.y);
  }
  __syncthreads();
  // pass1: 8 hidden units per lane
  {
    float hh[8];
#pragma unroll
    for (int j = 0; j < 8; ++j) {
      int jj = s * 8 + j;
      float aa = bb1[jj], ab = 0.f;
#pragma unroll
      for (int d = 0; d < D; d += 2) {
        aa += tsl[r][d]     * w1s[d * FF + jj];
        ab += tsl[r][d + 1] * w1s[(d + 1) * FF + jj];
      }
      hh[j] = fmaxf(aa + ab, 0.f);
    }
#pragma unroll
    for (int j = 0; j < 8; ++j) hl[r][s * 8 + j] = hh[j];
  }
  __syncthreads();
  // pass2: 4 outputs per lane + LN (8-lane shfl reduce)
  {
    float x[4];
    float s1 = 0.f, s2 = 0.f;
#pragma unroll
    for (int j4 = 0; j4 < 4; ++j4) {
      int e = s * 4 + j4;
      float aa = 0.f, ab = 0.f;
#pragma unroll
      for (int k = 0; k < FF; k += 2) {
        aa += hl[r][k]     * w2s[k * D + e];
        ab += hl[r][k + 1] * w2s[(k + 1) * D + e];
      }
      float a = bb2[e] + tsl[r][e] + aa + ab;
      x[j4] = a; s1 += a; s2 += a * a;
    }
    s1 += __shfl_xor(s1, 1, 64); s2 += __shfl_xor(s2, 1, 64);
    s1 += __shfl_xor(s1, 2, 64); s2 += __shfl_xor(s2, 2, 64);
    s1 += __shfl_xor(s1, 4, 64); s2 += __shfl_xor(s2, 4, 64);
    float mu  = s1 * (1.f / D);
    float var = s2 * (1.f / D) - mu * mu;
    float rr = rsqrtf(var + 1e-5f);
    int e0 = s * 4;
    uint2 ou;
    ou.x = pk2((x[0]-mu)*rr*gs[e0]+bbs[e0],    (x[1]-mu)*rr*gs[e0+1]+bbs[e0+1]);
    ou.y = pk2((x[2]-mu)*rr*gs[e0+2]+bbs[e0+2],(x[3]-mu)*rr*gs[e0+3]+bbs[e0+3]);
    *(uint2*)&E[((size_t)(r0 + r)) * D + e0] = ou;
  }
}

// ---------------------------------------------------------------------------
// out = E@op_W + op_b + X   (f32 out)
// ---------------------------------------------------------------------------
__global__ __launch_bounds__(256) void out_kernel(
    const bf16* __restrict__ E, const float* __restrict__ op_W,
    const float* __restrict__ op_b, const float* __restrict__ X,
    float* __restrict__ out) {
  int idx = blockIdx.x * 256 + threadIdx.x;
  if (idx >= B * T * N * M) return;
  int m  = idx % M;
  int n  = (idx / M) % N;
  int bt = idx / (M * N);
  float acc = op_b[n * M + m];
  const bf16* e = E + ((size_t)bt * N + n) * D;
#pragma unroll
  for (int d = 0; d < D; ++d) acc += b2f(e[d]) * op_W[(n * D + d) * M + m];
  acc += X[idx];
  out[idx] = acc;
}

// ---------------------------------------------------------------------------
extern "C" void kernel_launch(void* const* d_in, const int* in_sizes, int n_in,
                              void* d_out, int out_size, void* d_ws, size_t ws_size,
                              hipStream_t stream) {
  const float* X     = (const float*)d_in[0];
  const float* pe    = (const float*)d_in[1];
  const float* E_W   = (const float*)d_in[2];
  const float* E_b   = (const float*)d_in[3];
  const float* tq_W  = (const float*)d_in[4];
  const float* tq_b  = (const float*)d_in[5];
  const float* tk_W  = (const float*)d_in[6];
  const float* tk_b  = (const float*)d_in[7];
  const float* tv_W  = (const float*)d_in[8];
  const float* tv_b  = (const float*)d_in[9];
  const float* tm_Wq = (const float*)d_in[10];
  const float* tm_bq = (const float*)d_in[11];
  const float* tm_Wk = (const float*)d_in[12];
  const float* tm_bk = (const float*)d_in[13];
  const float* tm_Wv = (const float*)d_in[14];
  const float* tm_bv = (const float*)d_in[15];
  const float* tm_Wo = (const float*)d_in[16];
  const float* tm_bo = (const float*)d_in[17];
  const float* sq_W  = (const float*)d_in[18];
  const float* sq_b  = (const float*)d_in[19];
  const float* sk_W  = (const float*)d_in[20];
  const float* sk_b  = (const float*)d_in[21];
  const float* sv_W  = (const float*)d_in[22];
  const float* sv_b  = (const float*)d_in[23];
  const float* sm_Wq = (const float*)d_in[24];
  const float* sm_bq = (const float*)d_in[25];
  const float* sm_Wk = (const float*)d_in[26];
  const float* sm_bk = (const float*)d_in[27];
  const float* sm_Wv = (const float*)d_in[28];
  const float* sm_bv = (const float*)d_in[29];
  const float* sm_Wo = (const float*)d_in[30];
  const float* sm_bo = (const float*)d_in[31];
  const float* ff1_W = (const float*)d_in[32];
  const float* ff1_b = (const float*)d_in[33];
  const float* ff2_W = (const float*)d_in[34];
  const float* ff2_b = (const float*)d_in[35];
  const float* ln_g  = (const float*)d_in[36];
  const float* ln_b  = (const float*)d_in[37];
  const float* op_W  = (const float*)d_in[38];
  const float* op_b  = (const float*)d_in[39];
  float* out = (float*)d_out;

  float* WtC = (float*)d_ws;                         // 3*N*D*D
  float* btC = WtC + 3 * N * D * D;                  // 3*N*D
  float* WsC = btC + 3 * N * D;                      // 3*T*D*D
  float* bsC = WsC + 3 * T * D * D;                  // 3*T*D
  size_t act = (size_t)B * T * N * D;
  bf16* Ebuf = (bf16*)(bsC + 3 * T * D);
  bf16* Tn   = Ebuf + act;
  bf16* Qt   = Tn + act;
  bf16* Kt   = Qt + act;
  bf16* Vt   = Kt + act;
  bf16* Sn   = Qt;                                   // alias

  compose3_kernel<<<3 * N, 256, 0, stream>>>(
      tq_W, tq_b, tm_Wq, tm_bq, tk_W, tk_b, tm_Wk, tm_bk,
      tv_W, tv_b, tm_Wv, tm_bv, WtC, btC, N);
  compose3_kernel<<<3 * T, 256, 0, stream>>>(
      sq_W, sq_b, sm_Wq, sm_bq, sk_W, sk_b, sm_Wk, sm_bk,
      sv_W, sv_b, sm_Wv, sm_bv, WsC, bsC, T);

  embed_kernel<<<(B * T * N * D) / 256, 256, 0, stream>>>(X, pe, E_W, E_b, Ebuf);

  for (int l = 0; l < L; ++l) {
    qkvt_kernel<<<N * RCH, 256, 0, stream>>>(Ebuf, WtC, btC, Qt, Kt, Vt);
    attnt_kernel<<<B * N * 4, 256, 0, stream>>>(Qt, Kt, Vt, Ebuf, tm_Wo, tm_bo, ln_g, ln_b, Tn);
    spatial_kernel<<<T * (B / BG), 256, 0, stream>>>(Ebuf, WsC, bsC, sm_Wo, sm_bo, ln_g, ln_b, Sn);
    ff_kernel<<<(B * T * N) / FR, 256, 0, stream>>>(Tn, Sn, ff1_W, ff1_b, ff2_W, ff2_b, ln_g, ln_b, Ebuf);
  }

  out_kernel<<<(B * T * N * M + 255) / 256, 256, 0, stream>>>(Ebuf, op_W, op_b, X, out);
}

// Round 15
// 1069.606 us; speedup vs baseline: 3.2675x; 1.0415x over previous
//
#include <hip/hip_runtime.h>
#include <hip/hip_bf16.h>

typedef __hip_bfloat16 bf16;

constexpr int B  = 64, T = 120, N = 24, M = 3, D = 32;
constexpr int NH = 2, FD = 16, FF = 64, L = 3;
constexpr float SCALE = 0.25f;   // 1/sqrt(FD)
constexpr int SK  = 40;          // attnt Q/V LDS stride (bf16, 80B rows)
constexpr int SKF = 36;          // attnt K/O LDS stride (f32, 144B rows)
constexpr int CH2 = 30;          // attnt rows per chunk: 4 x 30 = 120 exactly
constexpr int RCH = 30;          // qkvt row chunks: 7680/256
constexpr int BG  = 2;           // spatial batches per block
constexpr int SR  = N * BG;      // spatial rows per block = 48
constexpr int SES = 40;          // spatial Es bf16 stride
constexpr int SQS = 32;          // spatial Q/K/V f32 stride
constexpr int FR  = 32;          // ff rows per block (8 lanes/row)

__device__ __forceinline__ float b2f(bf16 x) { return __bfloat162float(x); }
__device__ __forceinline__ float blo(unsigned u) { return __uint_as_float(u << 16); }
__device__ __forceinline__ float bhi(unsigned u) { return __uint_as_float(u & 0xffff0000u); }
__device__ __forceinline__ unsigned pk2(float a, float b) {
  bf16 x = __float2bfloat16(a), y = __float2bfloat16(b);
  unsigned short ux = *reinterpret_cast<unsigned short*>(&x);
  unsigned short uy = *reinterpret_cast<unsigned short*>(&y);
  return (unsigned)ux | ((unsigned)uy << 16);
}

// ---------------------------------------------------------------------------
// Compose q/k/v chained linears: grid = 3*U blocks.  Wc = W1@W2, bc = b1@W2+b2.
// ---------------------------------------------------------------------------
__global__ __launch_bounds__(256) void compose3_kernel(
    const float* __restrict__ W1q, const float* __restrict__ b1q,
    const float* __restrict__ W2q, const float* __restrict__ b2q,
    const float* __restrict__ W1k, const float* __restrict__ b1k,
    const float* __restrict__ W2k, const float* __restrict__ b2k,
    const float* __restrict__ W1v, const float* __restrict__ b1v,
    const float* __restrict__ W2v, const float* __restrict__ b2v,
    float* __restrict__ Wc, float* __restrict__ bc, int U) {
  int fam = blockIdx.x / U;
  int n   = blockIdx.x % U;
  const float* W1 = (fam == 0) ? W1q : (fam == 1) ? W1k : W1v;
  const float* b1 = (fam == 0) ? b1q : (fam == 1) ? b1k : b1v;
  const float* W2 = (fam == 0) ? W2q : (fam == 1) ? W2k : W2v;
  const float* b2 = (fam == 0) ? b2q : (fam == 1) ? b2k : b2v;
  const float* w1 = W1 + n * D * D;
  const float* w2 = W2 + n * D * D;
  float* wc  = Wc + (size_t)(fam * U + n) * D * D;
  float* bcp = bc + (fam * U + n) * D;
  __shared__ float s1[D * D], s2[D * D];
  for (int i = threadIdx.x; i < D * D; i += 256) { s1[i] = w1[i]; s2[i] = w2[i]; }
  __syncthreads();
  for (int i = threadIdx.x; i < D * D; i += 256) {
    int d = i >> 5, f = i & 31;
    float acc = 0.f;
#pragma unroll
    for (int e = 0; e < D; ++e) acc += s1[d * D + e] * s2[e * D + f];
    wc[i] = acc;
  }
  if (threadIdx.x < D) {
    int f = threadIdx.x;
    float acc = b2[n * D + f];
#pragma unroll
    for (int e = 0; e < D; ++e) acc += b1[n * D + e] * s2[e * D + f];
    bcp[f] = acc;
  }
}

// ---------------------------------------------------------------------------
// E[b,t,n,d] = X@E_W + E_b + pe   (bf16 out)
// ---------------------------------------------------------------------------
__global__ __launch_bounds__(256) void embed_kernel(
    const float* __restrict__ X, const float* __restrict__ pe,
    const float* __restrict__ E_W, const float* __restrict__ E_b,
    bf16* __restrict__ E) {
  int idx = blockIdx.x * 256 + threadIdx.x;
  if (idx >= B * T * N * D) return;
  int d = idx & 31;
  int n = (idx >> 5) % N;
  int bt = idx / (D * N);
  int t = bt % T;
  const float* x = X + bt * (N * M) + n * M;
  float acc = E_b[n * D + d] + pe[t * D + d];
#pragma unroll
  for (int m = 0; m < M; ++m) acc += x[m] * E_W[(n * M + m) * D + d];
  E[idx] = __float2bfloat16(acc);
}

// ---------------------------------------------------------------------------
// qkvt: composed Q/K/V projections for the temporal path.
// Weights in LDS.  Writes Qt/Kt/Vt[b][n][t][32] bf16 (t-contiguous).
// ---------------------------------------------------------------------------
__global__ __launch_bounds__(256) void qkvt_kernel(
    const bf16* __restrict__ E, const float* __restrict__ WtC,
    const float* __restrict__ btC,
    bf16* __restrict__ Qt, bf16* __restrict__ Kt, bf16* __restrict__ Vt) {
  int n     = blockIdx.x / RCH;
  int chunk = blockIdx.x % RCH;
  __shared__ float wsh[3 * D * D];
  __shared__ float bsh[3 * D];
  int tid = threadIdx.x;
  for (int i = tid; i < 3 * D * D; i += 256) {
    int fam = i >> 10, idx = i & 1023;
    wsh[i] = WtC[(size_t)(fam * N + n) * D * D + idx];
  }
  if (tid < 3 * D) {
    int fam = tid >> 5, e = tid & 31;
    bsh[tid] = btC[(fam * N + n) * D + e];
  }
  __syncthreads();

  int row = chunk * 256 + tid;          // (b*T + t)
  int b = row / T, t = row % T;
  const bf16* er = E + ((size_t)row * N + n) * D;
  float x[D];
#pragma unroll
  for (int p = 0; p < 4; ++p) {
    uint4 u = *(const uint4*)&er[p * 8];
    x[p*8+0] = blo(u.x); x[p*8+1] = bhi(u.x);
    x[p*8+2] = blo(u.y); x[p*8+3] = bhi(u.y);
    x[p*8+4] = blo(u.z); x[p*8+5] = bhi(u.z);
    x[p*8+6] = blo(u.w); x[p*8+7] = bhi(u.w);
  }
  size_t dsto = (((size_t)b * N + n) * T + t) * D;
  bf16* dsts[3] = { Qt + dsto, Kt + dsto, Vt + dsto };
#pragma unroll
  for (int fam = 0; fam < 3; ++fam) {
    const float* w  = wsh + fam * D * D;
    const float* bi = bsh + fam * D;
    bf16* dst = dsts[fam];
#pragma unroll
    for (int g = 0; g < 4; ++g) {
      float a[8];
#pragma unroll
      for (int j = 0; j < 8; ++j) a[j] = bi[g * 8 + j];
#pragma unroll
      for (int d = 0; d < D; ++d) {
        float xv = x[d];
#pragma unroll
        for (int j = 0; j < 8; ++j) a[j] += xv * w[d * D + g * 8 + j];
      }
      uint4 o;
      o.x = pk2(a[0], a[1]); o.y = pk2(a[2], a[3]);
      o.z = pk2(a[4], a[5]); o.w = pk2(a[6], a[7]);
      *(uint4*)&dst[g * 8] = o;
    }
  }
}

// ---------------------------------------------------------------------------
// attnt v6: compile-time trip counts per chunk.  R14's `break` in unrolled
// loops forced rolled loops + v_cndmask cascades over the sc[] register array
// (VALU 47->61%, dur +25%).  Templating on chunk CC makes the bound NJC a
// constant {8,15,23,30} -> full unroll, static indices, no wasted iterations.
// ---------------------------------------------------------------------------
template<int CC>
__device__ __forceinline__ void attnt_attention(
    int task, int sl, const bf16* Ql, const float* Kl, const bf16* Vl,
    float* Ol) {
  constexpr int NJC = ((CH2 * (CC + 1) - 1) >> 2) + 1;   // 8,15,23,30
  int rl = task >> 1, h = task & 1, ho = h * FD;
  int rg = CH2 * CC + rl;
  uint4 q0 = *(const uint4*)&Ql[rl * SK + ho];
  uint4 q1 = *(const uint4*)&Ql[rl * SK + ho + 8];
  float qf[16];
  qf[0]  = blo(q0.x); qf[1]  = bhi(q0.x); qf[2]  = blo(q0.y); qf[3]  = bhi(q0.y);
  qf[4]  = blo(q0.z); qf[5]  = bhi(q0.z); qf[6]  = blo(q0.w); qf[7]  = bhi(q0.w);
  qf[8]  = blo(q1.x); qf[9]  = bhi(q1.x); qf[10] = blo(q1.y); qf[11] = bhi(q1.y);
  qf[12] = blo(q1.z); qf[13] = bhi(q1.z); qf[14] = blo(q1.w); qf[15] = bhi(q1.w);

  float sc[NJC];
  float mx = -3e38f;
#pragma unroll
  for (int j = 0; j < NJC; ++j) {
    int k = 4 * j + sl;
    sc[j] = -3e38f;
    if (k <= rg) {
      const float4 k0 = *(const float4*)&Kl[k * SKF + ho];
      const float4 k1 = *(const float4*)&Kl[k * SKF + ho + 4];
      const float4 k2 = *(const float4*)&Kl[k * SKF + ho + 8];
      const float4 k3 = *(const float4*)&Kl[k * SKF + ho + 12];
      float s0 = qf[0]*k0.x  + qf[1]*k0.y  + qf[2]*k0.z  + qf[3]*k0.w;
      float s1 = qf[4]*k1.x  + qf[5]*k1.y  + qf[6]*k1.z  + qf[7]*k1.w;
      float s2 = qf[8]*k2.x  + qf[9]*k2.y  + qf[10]*k2.z + qf[11]*k2.w;
      float s3 = qf[12]*k3.x + qf[13]*k3.y + qf[14]*k3.z + qf[15]*k3.w;
      float s = ((s0 + s1) + (s2 + s3)) * SCALE;
      sc[j] = s;
      mx = fmaxf(mx, s);
    }
  }
  mx = fmaxf(mx, __shfl_xor(mx, 1, 64));
  mx = fmaxf(mx, __shfl_xor(mx, 2, 64));
  float l = 0.f;
#pragma unroll
  for (int j = 0; j < NJC; ++j) {
    sc[j] = __expf(sc[j] - mx);   // invalid slots: exp(-inf) = 0
    l += sc[j];
  }
  l += __shfl_xor(l, 1, 64);
  l += __shfl_xor(l, 2, 64);
  float rli = 1.f / l;

  float acc[16];
#pragma unroll
  for (int f = 0; f < 16; ++f) acc[f] = 0.f;
#pragma unroll
  for (int j = 0; j < NJC; ++j) {
    int k = 4 * j + sl;
    if (k <= rg) {
      float p = sc[j];
      uint2 va = *(const uint2*)&Vl[k * SK + ho];
      uint2 vb = *(const uint2*)&Vl[k * SK + ho + 4];
      uint2 vc = *(const uint2*)&Vl[k * SK + ho + 8];
      uint2 vd = *(const uint2*)&Vl[k * SK + ho + 12];
      acc[0]  += p * blo(va.x); acc[1]  += p * bhi(va.x);
      acc[2]  += p * blo(va.y); acc[3]  += p * bhi(va.y);
      acc[4]  += p * blo(vb.x); acc[5]  += p * bhi(vb.x);
      acc[6]  += p * blo(vb.y); acc[7]  += p * bhi(vb.y);
      acc[8]  += p * blo(vc.x); acc[9]  += p * bhi(vc.x);
      acc[10] += p * blo(vc.y); acc[11] += p * bhi(vc.y);
      acc[12] += p * blo(vd.x); acc[13] += p * bhi(vd.x);
      acc[14] += p * blo(vd.y); acc[15] += p * bhi(vd.y);
    }
  }
#pragma unroll
  for (int f = 0; f < 16; ++f) {
    acc[f] += __shfl_xor(acc[f], 1, 64);
    acc[f] += __shfl_xor(acc[f], 2, 64);
  }
  if (sl == 0) {
#pragma unroll
    for (int f = 0; f < 16; ++f) Ol[rl * SKF + ho + f] = acc[f] * rli;
  }
}

__global__ __launch_bounds__(256) void attnt_kernel(
    const bf16* __restrict__ Qt, const bf16* __restrict__ Kt,
    const bf16* __restrict__ Vt, const bf16* __restrict__ E,
    const float* __restrict__ tm_Wo, const float* __restrict__ tm_bo,
    const float* __restrict__ ln_g, const float* __restrict__ ln_b,
    bf16* __restrict__ Tn) {
  int c  = blockIdx.x & 3;
  int bn = blockIdx.x >> 2;
  int n  = bn % N, b = bn / N;
  int nk = CH2 * (c + 1);               // keys used: 30/60/90/120
  int nk4 = (nk + 4 > T) ? T : nk + 4;  // stage a zero-filled guard tail
  __shared__ __align__(16) float Kl[T * SKF];
  __shared__ __align__(16) bf16  Vl[T * SK];
  __shared__ __align__(16) bf16  Ql[CH2 * SK];
  __shared__ __align__(16) float Ol[CH2 * SKF];
  __shared__ float Wol[D * D], bol[D], gl[D], bbl[D];
  int tid = threadIdx.x;

  const bf16* Kg = Kt + (size_t)bn * T * D;
  const bf16* Vg = Vt + (size_t)bn * T * D;
  const bf16* Qg = Qt + ((size_t)bn * T + CH2 * c) * D;
  for (int i = tid; i < nk4 * 4; i += 256) {
    int r = i >> 2, p = i & 3;
    if (r < nk) {
      uint4 ku = *(const uint4*)&Kg[r * D + p * 8];
      *(float4*)&Kl[r * SKF + p * 8]     = make_float4(blo(ku.x), bhi(ku.x), blo(ku.y), bhi(ku.y));
      *(float4*)&Kl[r * SKF + p * 8 + 4] = make_float4(blo(ku.z), bhi(ku.z), blo(ku.w), bhi(ku.w));
      *(uint4*)&Vl[r * SK + p * 8]       = *(const uint4*)&Vg[r * D + p * 8];
    } else {
      *(float4*)&Kl[r * SKF + p * 8]     = make_float4(0.f, 0.f, 0.f, 0.f);
      *(float4*)&Kl[r * SKF + p * 8 + 4] = make_float4(0.f, 0.f, 0.f, 0.f);
      *(uint4*)&Vl[r * SK + p * 8]       = make_uint4(0u, 0u, 0u, 0u);
    }
  }
  if (tid < CH2 * 4) {
    int r = tid >> 2, p = tid & 3;
    *(uint4*)&Ql[r * SK + p * 8] = *(const uint4*)&Qg[r * D + p * 8];
  }
  for (int i = tid; i < D * D; i += 256) Wol[i] = tm_Wo[(size_t)n * D * D + i];
  if (tid < D) {
    bol[tid] = tm_bo[n * D + tid];
    gl[tid]  = ln_g[tid];
    bbl[tid] = ln_b[tid];
  }
  __syncthreads();

  {
    int task = tid >> 2, sl = tid & 3;
    if (task < 2 * CH2) {
      switch (c) {
        case 0: attnt_attention<0>(task, sl, Ql, Kl, Vl, Ol); break;
        case 1: attnt_attention<1>(task, sl, Ql, Kl, Vl, Ol); break;
        case 2: attnt_attention<2>(task, sl, Ql, Kl, Vl, Ol); break;
        default: attnt_attention<3>(task, sl, Ql, Kl, Vl, Ol); break;
      }
    }
  }
  __syncthreads();

  // ---- O-proj + residual + LN: thread = (row, e-quad), 8 lanes per row ----
  {
    int rl = tid >> 3, q = tid & 7, e0 = q * 4;
    if (rl < CH2) {
      int rg = CH2 * c + rl;
      size_t rowo = ((size_t)(b * T + rg) * N + n) * D;
      uint2 eu = *(const uint2*)&E[rowo + e0];
      float res[4] = { blo(eu.x), bhi(eu.x), blo(eu.y), bhi(eu.y) };
      float o[4], s1 = 0.f, s2 = 0.f;
#pragma unroll
      for (int j = 0; j < 4; ++j) {
        int e = e0 + j;
        float aa = 0.f, ab = 0.f;
#pragma unroll
        for (int d = 0; d < D; d += 2) {
          aa += Ol[rl * SKF + d]     * Wol[d * D + e];
          ab += Ol[rl * SKF + d + 1] * Wol[(d + 1) * D + e];
        }
        float a = bol[e] + aa + ab + res[j];
        o[j] = a; s1 += a; s2 += a * a;
      }
      s1 += __shfl_xor(s1, 1, 64); s2 += __shfl_xor(s2, 1, 64);
      s1 += __shfl_xor(s1, 2, 64); s2 += __shfl_xor(s2, 2, 64);
      s1 += __shfl_xor(s1, 4, 64); s2 += __shfl_xor(s2, 4, 64);
      float mu  = s1 * (1.f / D);
      float var = s2 * (1.f / D) - mu * mu;
      float r = rsqrtf(var + 1e-5f);
      uint2 ou;
      ou.x = pk2((o[0]-mu)*r*gl[e0]+bbl[e0],    (o[1]-mu)*r*gl[e0+1]+bbl[e0+1]);
      ou.y = pk2((o[2]-mu)*r*gl[e0+2]+bbl[e0+2],(o[3]-mu)*r*gl[e0+3]+bbl[e0+3]);
      *(uint2*)&Tn[rowo + e0] = ou;
    }
  }
}

// ---------------------------------------------------------------------------
// spatial v2: block = (t, 2 batches), 256 threads.  Weights in LDS.
// ---------------------------------------------------------------------------
__global__ __launch_bounds__(256) void spatial_kernel(
    const bf16* __restrict__ E, const float* __restrict__ WsC,
    const float* __restrict__ bsC, const float* __restrict__ sm_Wo,
    const float* __restrict__ sm_bo, const float* __restrict__ ln_g,
    const float* __restrict__ ln_b, bf16* __restrict__ Sn) {
  int t  = blockIdx.x >> 5;          // B/BG = 32 groups per t
  int bg = blockIdx.x & 31;
  int b0 = bg * BG;
  __shared__ float Wq[D * D], Wk[D * D], Wv[D * D], Wo[D * D];
  __shared__ float bqs[D], bks[D], bvs[D], bos[D], gs[D], bbs[D];
  __shared__ __align__(16) bf16  Es[SR * SES];
  __shared__ float Qs[SR * SQS], Ks[SR * SQS], Vs[SR * SQS];
  int tid = threadIdx.x;

  for (int i = tid; i < D * D; i += 256) {
    Wq[i] = WsC[(size_t)(0 * T + t) * D * D + i];
    Wk[i] = WsC[(size_t)(1 * T + t) * D * D + i];
    Wv[i] = WsC[(size_t)(2 * T + t) * D * D + i];
    Wo[i] = sm_Wo[(size_t)t * D * D + i];
  }
  if (tid < D) {
    bqs[tid] = bsC[(0 * T + t) * D + tid];
    bks[tid] = bsC[(1 * T + t) * D + tid];
    bvs[tid] = bsC[(2 * T + t) * D + tid];
    bos[tid] = sm_bo[t * D + tid];
    gs[tid]  = ln_g[tid];
    bbs[tid] = ln_b[tid];
  }
  if (tid < SR * 4) {
    int r = tid >> 2, p = tid & 3;
    int b = b0 + r / N, n = r % N;
    *(uint4*)&Es[r * SES + p * 8] =
        *(const uint4*)&E[(((size_t)b * T + t) * N + n) * D + p * 8];
  }
  __syncthreads();

#pragma unroll 1
  for (int i = tid; i < SR * D; i += 256) {
    int r = i >> 5, e = i & 31;
    float aq = bqs[e], ak = bks[e], av = bvs[e];
#pragma unroll
    for (int d = 0; d < D; ++d) {
      float x = b2f(Es[r * SES + d]);
      aq += x * Wq[d * D + e];
      ak += x * Wk[d * D + e];
      av += x * Wv[d * D + e];
    }
    Qs[r * SQS + e] = aq;
    Ks[r * SQS + e] = ak;
    Vs[r * SQS + e] = av;
  }
  __syncthreads();

  if (tid < SR * NH) {
    int r = tid >> 1, h = tid & 1, ho = h * FD;
    int kb = (r >= N) ? N : 0;
    float q[FD];
#pragma unroll
    for (int f = 0; f < FD; ++f) q[f] = Qs[r * SQS + ho + f];
    float sc[N];
    float m = -1e30f;
#pragma unroll
    for (int k = 0; k < N; ++k) {
      float sa = 0.f, sb = 0.f;
#pragma unroll
      for (int f = 0; f < FD; f += 2) {
        sa += q[f]     * Ks[(kb + k) * SQS + ho + f];
        sb += q[f + 1] * Ks[(kb + k) * SQS + ho + f + 1];
      }
      float s = (sa + sb) * SCALE;
      sc[k] = s;
      m = fmaxf(m, s);
    }
    float l = 0.f;
#pragma unroll
    for (int k = 0; k < N; ++k) { sc[k] = __expf(sc[k] - m); l += sc[k]; }
    float rl = 1.f / l;
#pragma unroll
    for (int f = 0; f < FD; ++f) {
      float a = 0.f;
#pragma unroll
      for (int k = 0; k < N; ++k) a += sc[k] * Vs[(kb + k) * SQS + ho + f];
      Qs[r * SQS + ho + f] = a * rl;
    }
  }
  __syncthreads();

#pragma unroll 1
  for (int it = 0; it < SR * D / 256; ++it) {
    int i = it * 256 + tid;
    int r = i >> 5, e = i & 31;
    float aa = 0.f, ab = 0.f;
#pragma unroll
    for (int d = 0; d < D; d += 2) {
      aa += Qs[r * SQS + d]     * Wo[d * D + e];
      ab += Qs[r * SQS + d + 1] * Wo[(d + 1) * D + e];
    }
    float o = bos[e] + aa + ab + b2f(Es[r * SES + e]);
    float s1 = o, s2 = o * o;
    s1 += __shfl_xor(s1, 1, 64);  s2 += __shfl_xor(s2, 1, 64);
    s1 += __shfl_xor(s1, 2, 64);  s2 += __shfl_xor(s2, 2, 64);
    s1 += __shfl_xor(s1, 4, 64);  s2 += __shfl_xor(s2, 4, 64);
    s1 += __shfl_xor(s1, 8, 64);  s2 += __shfl_xor(s2, 8, 64);
    s1 += __shfl_xor(s1, 16, 64); s2 += __shfl_xor(s2, 16, 64);
    float mu  = s1 * (1.f / D);
    float var = s2 * (1.f / D) - mu * mu;
    float rr = rsqrtf(var + 1e-5f);
    int b = b0 + r / N, n = r % N;
    Sn[(((size_t)b * T + t) * N + n) * D + e] =
        __float2bfloat16((o - mu) * rr * gs[e] + bbs[e]);
  }
}

// ---------------------------------------------------------------------------
// ff v2: block = 32 rows x 8 lanes/row (grid 240).
// ---------------------------------------------------------------------------
__global__ __launch_bounds__(256) void ff_kernel(
    const bf16* __restrict__ Tn, const bf16* __restrict__ Sn,
    const float* __restrict__ W1, const float* __restrict__ b1,
    const float* __restrict__ W2, const float* __restrict__ b2,
    const float* __restrict__ ln_g, const float* __restrict__ ln_b,
    bf16* __restrict__ E) {
  __shared__ float w1s[D * FF], w2s[FF * D];
  __shared__ float bb1[FF], bb2[D], gs[D], bbs[D];
  __shared__ float tsl[FR][D + 1];
  __shared__ float hl[FR][FF + 1];
  int tid = threadIdx.x;
  int r0 = blockIdx.x * FR;
  for (int i = tid; i < D * FF; i += 256) { w1s[i] = W1[i]; w2s[i] = W2[i]; }
  if (tid < FF) bb1[tid] = b1[tid];
  if (tid < D) { bb2[tid] = b2[tid]; gs[tid] = ln_g[tid]; bbs[tid] = ln_b[tid]; }
  int r = tid >> 3, s = tid & 7;
  {
    const bf16* tp = Tn + ((size_t)(r0 + r)) * D + s * 4;
    const bf16* sp = Sn + ((size_t)(r0 + r)) * D + s * 4;
    uint2 tu = *(const uint2*)tp;
    uint2 su = *(const uint2*)sp;
    tsl[r][s*4+0] = blo(tu.x) + blo(su.x);
    tsl[r][s*4+1] = bhi(tu.x) + bhi(su.x);
    tsl[r][s*4+2] = blo(tu.y) + blo(su.y);
    tsl[r][s*4+3] = bhi(tu.y) + bhi(su.y);
  }
  __syncthreads();
  {
    float hh[8];
#pragma unroll
    for (int j = 0; j < 8; ++j) {
      int jj = s * 8 + j;
      float aa = bb1[jj], ab = 0.f;
#pragma unroll
      for (int d = 0; d < D; d += 2) {
        aa += tsl[r][d]     * w1s[d * FF + jj];
        ab += tsl[r][d + 1] * w1s[(d + 1) * FF + jj];
      }
      hh[j] = fmaxf(aa + ab, 0.f);
    }
#pragma unroll
    for (int j = 0; j < 8; ++j) hl[r][s * 8 + j] = hh[j];
  }
  __syncthreads();
  {
    float x[4];
    float s1 = 0.f, s2 = 0.f;
#pragma unroll
    for (int j4 = 0; j4 < 4; ++j4) {
      int e = s * 4 + j4;
      float aa = 0.f, ab = 0.f;
#pragma unroll
      for (int k = 0; k < FF; k += 2) {
        aa += hl[r][k]     * w2s[k * D + e];
        ab += hl[r][k + 1] * w2s[(k + 1) * D + e];
      }
      float a = bb2[e] + tsl[r][e] + aa + ab;
      x[j4] = a; s1 += a; s2 += a * a;
    }
    s1 += __shfl_xor(s1, 1, 64); s2 += __shfl_xor(s2, 1, 64);
    s1 += __shfl_xor(s1, 2, 64); s2 += __shfl_xor(s2, 2, 64);
    s1 += __shfl_xor(s1, 4, 64); s2 += __shfl_xor(s2, 4, 64);
    float mu  = s1 * (1.f / D);
    float var = s2 * (1.f / D) - mu * mu;
    float rr = rsqrtf(var + 1e-5f);
    int e0 = s * 4;
    uint2 ou;
    ou.x = pk2((x[0]-mu)*rr*gs[e0]+bbs[e0],    (x[1]-mu)*rr*gs[e0+1]+bbs[e0+1]);
    ou.y = pk2((x[2]-mu)*rr*gs[e0+2]+bbs[e0+2],(x[3]-mu)*rr*gs[e0+3]+bbs[e0+3]);
    *(uint2*)&E[((size_t)(r0 + r)) * D + e0] = ou;
  }
}

// ---------------------------------------------------------------------------
// out = E@op_W + op_b + X   (f32 out)
// ---------------------------------------------------------------------------
__global__ __launch_bounds__(256) void out_kernel(
    const bf16* __restrict__ E, const float* __restrict__ op_W,
    const float* __restrict__ op_b, const float* __restrict__ X,
    float* __restrict__ out) {
  int idx = blockIdx.x * 256 + threadIdx.x;
  if (idx >= B * T * N * M) return;
  int m  = idx % M;
  int n  = (idx / M) % N;
  int bt = idx / (M * N);
  float acc = op_b[n * M + m];
  const bf16* e = E + ((size_t)bt * N + n) * D;
#pragma unroll
  for (int d = 0; d < D; ++d) acc += b2f(e[d]) * op_W[(n * D + d) * M + m];
  acc += X[idx];
  out[idx] = acc;
}

// ---------------------------------------------------------------------------
extern "C" void kernel_launch(void* const* d_in, const int* in_sizes, int n_in,
                              void* d_out, int out_size, void* d_ws, size_t ws_size,
                              hipStream_t stream) {
  const float* X     = (const float*)d_in[0];
  const float* pe    = (const float*)d_in[1];
  const float* E_W   = (const float*)d_in[2];
  const float* E_b   = (const float*)d_in[3];
  const float* tq_W  = (const float*)d_in[4];
  const float* tq_b  = (const float*)d_in[5];
  const float* tk_W  = (const float*)d_in[6];
  const float* tk_b  = (const float*)d_in[7];
  const float* tv_W  = (const float*)d_in[8];
  const float* tv_b  = (const float*)d_in[9];
  const float* tm_Wq = (const float*)d_in[10];
  const float* tm_bq = (const float*)d_in[11];
  const float* tm_Wk = (const float*)d_in[12];
  const float* tm_bk = (const float*)d_in[13];
  const float* tm_Wv = (const float*)d_in[14];
  const float* tm_bv = (const float*)d_in[15];
  const float* tm_Wo = (const float*)d_in[16];
  const float* tm_bo = (const float*)d_in[17];
  const float* sq_W  = (const float*)d_in[18];
  const float* sq_b  = (const float*)d_in[19];
  const float* sk_W  = (const float*)d_in[20];
  const float* sk_b  = (const float*)d_in[21];
  const float* sv_W  = (const float*)d_in[22];
  const float* sv_b  = (const float*)d_in[23];
  const float* sm_Wq = (const float*)d_in[24];
  const float* sm_bq = (const float*)d_in[25];
  const float* sm_Wk = (const float*)d_in[26];
  const float* sm_bk = (const float*)d_in[27];
  const float* sm_Wv = (const float*)d_in[28];
  const float* sm_bv = (const float*)d_in[29];
  const float* sm_Wo = (const float*)d_in[30];
  const float* sm_bo = (const float*)d_in[31];
  const float* ff1_W = (const float*)d_in[32];
  const float* ff1_b = (const float*)d_in[33];
  const float* ff2_W = (const float*)d_in[34];
  const float* ff2_b = (const float*)d_in[35];
  const float* ln_g  = (const float*)d_in[36];
  const float* ln_b  = (const float*)d_in[37];
  const float* op_W  = (const float*)d_in[38];
  const float* op_b  = (const float*)d_in[39];
  float* out = (float*)d_out;

  float* WtC = (float*)d_ws;                         // 3*N*D*D
  float* btC = WtC + 3 * N * D * D;                  // 3*N*D
  float* WsC = btC + 3 * N * D;                      // 3*T*D*D
  float* bsC = WsC + 3 * T * D * D;                  // 3*T*D
  size_t act = (size_t)B * T * N * D;
  bf16* Ebuf = (bf16*)(bsC + 3 * T * D);
  bf16* Tn   = Ebuf + act;
  bf16* Qt   = Tn + act;
  bf16* Kt   = Qt + act;
  bf16* Vt   = Kt + act;
  bf16* Sn   = Qt;                                   // alias

  compose3_kernel<<<3 * N, 256, 0, stream>>>(
      tq_W, tq_b, tm_Wq, tm_bq, tk_W, tk_b, tm_Wk, tm_bk,
      tv_W, tv_b, tm_Wv, tm_bv, WtC, btC, N);
  compose3_kernel<<<3 * T, 256, 0, stream>>>(
      sq_W, sq_b, sm_Wq, sm_bq, sk_W, sk_b, sm_Wk, sm_bk,
      sv_W, sv_b, sm_Wv, sm_bv, WsC, bsC, T);

  embed_kernel<<<(B * T * N * D) / 256, 256, 0, stream>>>(X, pe, E_W, E_b, Ebuf);

  for (int l = 0; l < L; ++l) {
    qkvt_kernel<<<N * RCH, 256, 0, stream>>>(Ebuf, WtC, btC, Qt, Kt, Vt);
    attnt_kernel<<<B * N * 4, 256, 0, stream>>>(Qt, Kt, Vt, Ebuf, tm_Wo, tm_bo, ln_g, ln_b, Tn);
    spatial_kernel<<<T * (B / BG), 256, 0, stream>>>(Ebuf, WsC, bsC, sm_Wo, sm_bo, ln_g, ln_b, Sn);
    ff_kernel<<<(B * T * N) / FR, 256, 0, stream>>>(Tn, Sn, ff1_W, ff1_b, ff2_W, ff2_b, ln_g, ln_b, Ebuf);
  }

  out_kernel<<<(B * T * N * M + 255) / 256, 256, 0, stream>>>(Ebuf, op_W, op_b, X, out);
}